// Round 1
// baseline (2973.347 us; speedup 1.0000x reference)
//
#include <hip/hip_runtime.h>
#include <cstdint>
#include <cstddef>

#define HIDC 128
#define NHEAD 8
#define NLAY 3
#define NGRAPH 64
#define NCLS 3

// ---------------------------------------------------------------------------
// C[M,Nc] = act(A[M,128] @ B[128,Nc] + bias)   (K fixed = 128)
// grid: (ceil(M/32), ceil(Nc/256)), block: 128 threads. Each thread: 2 cols x 32 rows.
// ---------------------------------------------------------------------------
__global__ __launch_bounds__(128) void mm_k128(
    const float* __restrict__ A, const float* __restrict__ B,
    const float* __restrict__ bias, float* __restrict__ C,
    int M, int Nc, int relu)
{
  __shared__ float4 As4[32 * 32];   // As4[r*32 + k4] = A[r0+r][4k4..4k4+3]
  const int tid = threadIdx.x;
  const int r0 = blockIdx.x * 32;
  const int c0 = blockIdx.y * 256;
  const float4* A4 = (const float4*)A;
#pragma unroll
  for (int it = 0; it < 8; ++it) {
    int idx = tid + it * 128;
    int r = idx >> 5, k4 = idx & 31;
    int row = r0 + r; if (row >= M) row = M - 1;
    As4[r * 32 + k4] = A4[(size_t)row * 32 + k4];
  }
  __syncthreads();
  int c1 = c0 + tid;
  int c2 = c0 + tid + 128;
  int c1c = c1 < Nc ? c1 : Nc - 1;
  int c2c = c2 < Nc ? c2 : Nc - 1;
  float acc1[32], acc2[32];
#pragma unroll
  for (int r = 0; r < 32; ++r) { acc1[r] = 0.f; acc2[r] = 0.f; }
  for (int kk = 0; kk < 32; ++kk) {
    float w1[4], w2[4];
#pragma unroll
    for (int j = 0; j < 4; ++j) {
      w1[j] = B[(size_t)(4 * kk + j) * Nc + c1c];
      w2[j] = B[(size_t)(4 * kk + j) * Nc + c2c];
    }
#pragma unroll
    for (int r = 0; r < 32; ++r) {
      float4 a = As4[r * 32 + kk];   // broadcast ds_read_b128
      acc1[r] += a.x * w1[0] + a.y * w1[1] + a.z * w1[2] + a.w * w1[3];
      acc2[r] += a.x * w2[0] + a.y * w2[1] + a.z * w2[2] + a.w * w2[3];
    }
  }
  float b1 = bias ? bias[c1c] : 0.f;
  float b2 = bias ? bias[c2c] : 0.f;
#pragma unroll
  for (int r = 0; r < 32; ++r) {
    int row = r0 + r;
    if (row < M) {
      float v1 = acc1[r] + b1; if (relu) v1 = fmaxf(v1, 0.f);
      float v2 = acc2[r] + b2; if (relu) v2 = fmaxf(v2, 0.f);
      if (c1 < Nc) C[(size_t)row * Nc + c1] = v1;
      if (c2 < Nc) C[(size_t)row * Nc + c2] = v2;
    }
  }
}

// ---------------------------------------------------------------------------
// alpha_s[n,h] = sum_c xl[n,h,c]*a_src[h,c] ; same for alpha_d. 8 nodes/block.
// ---------------------------------------------------------------------------
__global__ __launch_bounds__(256) void alpha_kernel(
    const float* __restrict__ xl, const float* __restrict__ a_src,
    const float* __restrict__ a_dst, float* __restrict__ alpha_s,
    float* __restrict__ alpha_d, int N)
{
  __shared__ float s_as[1024], s_ad[1024];
  const int tid = threadIdx.x;
  for (int i = tid; i < 1024; i += 256) { s_as[i] = a_src[i]; s_ad[i] = a_dst[i]; }
  __syncthreads();
  float4 av = ((const float4*)s_as)[tid];
  float4 dv = ((const float4*)s_ad)[tid];
  int head = tid >> 5;
  int n0 = blockIdx.x * 8;
  int n1 = n0 + 8; if (n1 > N) n1 = N;
  for (int n = n0; n < n1; ++n) {
    float4 v = ((const float4*)xl)[(size_t)n * 256 + tid];
    float ps = v.x * av.x + v.y * av.y + v.z * av.z + v.w * av.w;
    float pd = v.x * dv.x + v.y * dv.y + v.z * dv.z + v.w * dv.w;
    for (int off = 16; off; off >>= 1) {
      ps += __shfl_xor(ps, off, 32);
      pd += __shfl_xor(pd, off, 32);
    }
    if ((tid & 31) == 0) {
      alpha_s[(size_t)n * NHEAD + head] = ps;
      alpha_d[(size_t)n * NHEAD + head] = pd;
    }
  }
}

// ---------------------------------------------------------------------------
// CSR build (counting sort by dst). Edge list is int32 (JAX x64 disabled).
// ---------------------------------------------------------------------------
__global__ void hist_kernel(const int* __restrict__ ei, int* __restrict__ deg, int E, int N)
{
  int i = blockIdx.x * 256 + threadIdx.x;
  if (i >= E + N) return;
  int dst = (i < E) ? ei[E + i] : (i - E);
  atomicAdd(&deg[dst], 1);
}

__global__ __launch_bounds__(1024) void scan_kernel(const int* __restrict__ deg,
                                                    int* __restrict__ rowptr, int N)
{
  __shared__ int sd[1024];
  __shared__ int s_carry;
  if (threadIdx.x == 0) s_carry = 0;
  __syncthreads();
  for (int base = 0; base < N; base += 1024) {
    int i = base + threadIdx.x;
    int v = (i < N) ? deg[i] : 0;
    sd[threadIdx.x] = v;
    __syncthreads();
    for (int off = 1; off < 1024; off <<= 1) {
      int t = (threadIdx.x >= off) ? sd[threadIdx.x - off] : 0;
      __syncthreads();
      sd[threadIdx.x] += t;
      __syncthreads();
    }
    int incl = sd[threadIdx.x];
    int carry = s_carry;
    if (i < N) rowptr[i] = carry + incl - v;   // exclusive prefix
    __syncthreads();
    if (threadIdx.x == 1023) s_carry = carry + sd[1023];
    __syncthreads();
  }
  if (threadIdx.x == 0) rowptr[N] = s_carry;
}

__global__ void scatter_kernel(const int* __restrict__ ei, const int* __restrict__ rowptr,
                               int* __restrict__ cursor, int* __restrict__ csr_src,
                               int E, int N)
{
  int i = blockIdx.x * 256 + threadIdx.x;
  if (i >= E + N) return;
  int src, dst;
  if (i < E) { src = ei[i]; dst = ei[E + i]; }
  else { src = i - E; dst = i - E; }
  int pos = rowptr[dst] + atomicAdd(&cursor[dst], 1);
  csr_src[pos] = src;
}

// ---------------------------------------------------------------------------
// GAT aggregation: one block per dst node; 8 groups of 32 lanes (one head each).
// Edge softmax (leaky_relu 0.2) + weighted gather of xl[src,h,:], head mean.
// ---------------------------------------------------------------------------
#define MAXC 8
__global__ __launch_bounds__(256) void gat_aggregate(
    const float* __restrict__ xl, const int* __restrict__ rowptr,
    const int* __restrict__ csr_src, const float* __restrict__ alpha_s,
    const float* __restrict__ alpha_d, const float* __restrict__ bias,
    float* __restrict__ out, int N, int do_relu)
{
  const int dst = blockIdx.x;
  const int tid = threadIdx.x;
  const int h = tid >> 5, lane = tid & 31;
  __shared__ float sh[NHEAD * HIDC];
  const int start = rowptr[dst];
  const int deg = rowptr[dst + 1] - start;
  const float ad = alpha_d[(size_t)dst * NHEAD + h];
  const int nch = (deg + 31) >> 5;

  float s_arr[MAXC]; int src_arr[MAXC];
  float m = -1e30f;
  for (int c = 0; c < nch; ++c) {
    int e = c * 32 + lane;
    float s = -1e30f; int src = 0;
    if (e < deg) {
      src = csr_src[start + e];
      s = alpha_s[(size_t)src * NHEAD + h] + ad;
      s = (s > 0.f) ? s : 0.2f * s;
    }
    if (c < MAXC) { s_arr[c] = s; src_arr[c] = src; }
    m = fmaxf(m, s);
  }
  for (int off = 16; off; off >>= 1) m = fmaxf(m, __shfl_xor(m, off, 32));

  float denom = 0.f;
  float4 acc = make_float4(0.f, 0.f, 0.f, 0.f);
  for (int c = 0; c < nch; ++c) {
    int e0 = c * 32;
    float s; int src;
    if (c < MAXC) { s = s_arr[c]; src = src_arr[c]; }
    else {
      int e = e0 + lane; s = -1e30f; src = 0;
      if (e < deg) {
        src = csr_src[start + e];
        s = alpha_s[(size_t)src * NHEAD + h] + ad;
        s = (s > 0.f) ? s : 0.2f * s;
      }
    }
    float p = (e0 + lane < deg) ? __expf(s - m) : 0.f;
    denom += p;
    int cnt_e = deg - e0; if (cnt_e > 32) cnt_e = 32;
    for (int e = 0; e < cnt_e; ++e) {
      float w = __shfl(p, e, 32);
      int se = __shfl(src, e, 32);
      float4 v = ((const float4*)xl)[(size_t)se * 256 + h * 32 + lane];
      acc.x += w * v.x; acc.y += w * v.y; acc.z += w * v.z; acc.w += w * v.w;
    }
  }
  for (int off = 16; off; off >>= 1) denom += __shfl_xor(denom, off, 32);
  float inv = 1.f / (denom + 1e-16f);
  float4 r;
  r.x = acc.x * inv; r.y = acc.y * inv; r.z = acc.z * inv; r.w = acc.w * inv;
  ((float4*)sh)[h * 32 + lane] = r;
  __syncthreads();
  if (tid < HIDC) {
    float sum = 0.f;
#pragma unroll
    for (int hh = 0; hh < NHEAD; ++hh) sum += sh[hh * HIDC + tid];
    float val = sum * 0.125f + bias[tid];
    if (do_relu) val = fmaxf(val, 0.f);
    out[(size_t)dst * HIDC + tid] = val;
  }
}

// ---------------------------------------------------------------------------
// W [rows,128] -> Wt [128,rows]
// ---------------------------------------------------------------------------
__global__ void transpose_w(const float* __restrict__ W, float* __restrict__ Wt,
                            int rows)
{
  int i = blockIdx.x * 256 + threadIdx.x;
  if (i >= rows * 128) return;
  int j = i >> 7;          // row in W (output feature)
  int k = i & 127;         // col in W (input feature)
  Wt[(size_t)k * rows + j] = W[i];
}

// ---------------------------------------------------------------------------
// GRU gates (torch order r,z,n)
// ---------------------------------------------------------------------------
__global__ __launch_bounds__(256) void gru_gate_kernel(
    const float* __restrict__ gi, const float* __restrict__ gh,
    const float* __restrict__ mem, float* __restrict__ hout, int N)
{
  int idx = blockIdx.x * 256 + threadIdx.x;
  if (idx >= N * HIDC) return;
  int n = idx >> 7, c = idx & 127;
  size_t b = (size_t)n * 384;
  float gir = gi[b + c], giz = gi[b + 128 + c], gin = gi[b + 256 + c];
  float ghr = gh[b + c], ghz = gh[b + 128 + c], ghn = gh[b + 256 + c];
  float rg = 1.f / (1.f + __expf(-(gir + ghr)));
  float zg = 1.f / (1.f + __expf(-(giz + ghz)));
  float ncand = tanhf(gin + rg * ghn);
  hout[idx] = (1.f - zg) * ncand + zg * mem[idx];
}

// ---------------------------------------------------------------------------
// global_mean_pool (batch ids sorted): run-length accumulate + atomic flush.
// ---------------------------------------------------------------------------
__global__ __launch_bounds__(128) void pool_kernel(
    const float* __restrict__ h, const int* __restrict__ batch,
    float* __restrict__ pooled_sums, float* __restrict__ cnt, int N)
{
  int n0 = blockIdx.x * 128;
  int c = threadIdx.x;
  int end = n0 + 128; if (end > N) end = N;
  if (n0 >= N) return;
  int cur = batch[n0];
  float acc = 0.f; float count = 0.f;
  for (int n = n0; n < end; ++n) {
    int b = batch[n];
    if (b != cur) {
      atomicAdd(&pooled_sums[(size_t)cur * HIDC + c], acc);
      if (c == 0) atomicAdd(&cnt[cur], count);
      acc = 0.f; count = 0.f; cur = b;
    }
    acc += h[(size_t)n * HIDC + c];
    count += 1.f;
  }
  atomicAdd(&pooled_sums[(size_t)cur * HIDC + c], acc);
  if (c == 0) atomicAdd(&cnt[cur], count);
}

// ---------------------------------------------------------------------------
// finalize pooled (divide by count), classifier MLP, softmax
// grid = NGRAPH blocks, 64 threads
// ---------------------------------------------------------------------------
__global__ __launch_bounds__(64) void classifier_kernel(
    float* __restrict__ pooled, const float* __restrict__ cnt,
    const float* __restrict__ c1W, const float* __restrict__ c1b,
    const float* __restrict__ c2W, const float* __restrict__ c2b,
    float* __restrict__ logits, float* __restrict__ preds)
{
  int g = blockIdx.x, j = threadIdx.x;
  __shared__ float sp[128];
  __shared__ float hid[64];
  __shared__ float lg[3];
  float invc = 1.f / fmaxf(cnt[g], 1.f);
  float p0 = pooled[(size_t)g * 128 + j] * invc;
  float p1 = pooled[(size_t)g * 128 + 64 + j] * invc;
  pooled[(size_t)g * 128 + j] = p0;
  pooled[(size_t)g * 128 + 64 + j] = p1;
  sp[j] = p0; sp[j + 64] = p1;
  __syncthreads();
  float a = c1b[j];
#pragma unroll
  for (int k = 0; k < 128; ++k) a = fmaf(sp[k], c1W[k * 64 + j], a);
  hid[j] = fmaxf(a, 0.f);
  __syncthreads();
  if (j < NCLS) {
    float t = c2b[j];
#pragma unroll
    for (int k = 0; k < 64; ++k) t = fmaf(hid[k], c2W[k * NCLS + j], t);
    logits[(size_t)g * NCLS + j] = t;
    lg[j] = t;
  }
  __syncthreads();
  if (j < NCLS) {
    float mx = fmaxf(lg[0], fmaxf(lg[1], lg[2]));
    float e0 = __expf(lg[0] - mx), e1 = __expf(lg[1] - mx), e2 = __expf(lg[2] - mx);
    float mine = (j == 0) ? e0 : ((j == 1) ? e1 : e2);
    preds[(size_t)g * NCLS + j] = mine / (e0 + e1 + e2);
  }
}

// ---------------------------------------------------------------------------
extern "C" void kernel_launch(void* const* d_in, const int* in_sizes, int n_in,
                              void* d_out, int out_size, void* d_ws, size_t ws_size,
                              hipStream_t stream)
{
  const float* x       = (const float*)d_in[0];
  const int*   ei      = (const int*)d_in[1];     // [2,E] int32
  const int*   batch   = (const int*)d_in[2];
  const float* memory  = (const float*)d_in[3];
  const float* enc_W   = (const float*)d_in[4];
  const float* enc_b   = (const float*)d_in[5];
  const float* gat_W   = (const float*)d_in[6];   // [NL,128,1024]
  const float* att_src = (const float*)d_in[7];   // [NL,8,128]
  const float* att_dst = (const float*)d_in[8];
  const float* gat_b   = (const float*)d_in[9];   // [NL,128]
  const float* W_ih    = (const float*)d_in[10];  // [384,128]
  const float* W_hh    = (const float*)d_in[11];
  const float* b_ih    = (const float*)d_in[12];
  const float* b_hh    = (const float*)d_in[13];
  const float* c1W     = (const float*)d_in[14];  // [128,64]
  const float* c1b     = (const float*)d_in[15];
  const float* c2W     = (const float*)d_in[16];  // [64,3]
  const float* c2b     = (const float*)d_in[17];

  const int N = in_sizes[0] / HIDC;
  const int E = in_sizes[1] / 2;
  const int EN = E + N;

  // workspace layout
  char* ws = (char*)d_ws;
  size_t off = 0;
  auto alloc = [&](size_t bytes) -> void* {
    void* p = ws + off;
    off += (bytes + 255) & ~(size_t)255;
    return p;
  };
  float* h0     = (float*)alloc((size_t)N * HIDC * 4);
  float* h1     = (float*)alloc((size_t)N * HIDC * 4);
  float* xl     = (float*)alloc((size_t)N * NHEAD * HIDC * 4);
  float* aS     = (float*)alloc((size_t)N * NHEAD * 4);
  float* aD     = (float*)alloc((size_t)N * NHEAD * 4);
  float* WtA    = (float*)alloc((size_t)384 * 128 * 4);
  float* WtB    = (float*)alloc((size_t)384 * 128 * 4);
  int*   rowptr = (int*)alloc((size_t)(N + 1) * 4);
  int*   cursor = (int*)alloc((size_t)N * 4);
  int*   degtmp = (int*)alloc((size_t)N * 4);
  int*   csr    = (int*)alloc((size_t)EN * 4);
  float* cntbuf = (float*)alloc(64 * 4);
  float* gi = xl;                        // reuse xl after last GAT layer
  float* gh = xl + (size_t)N * 384;

  float* out_logits = (float*)d_out;                   // [64,3]
  float* out_pooled = (float*)d_out + NGRAPH * NCLS;   // [64,128]
  float* out_preds  = (float*)d_out + NGRAPH * NCLS + NGRAPH * HIDC;

  // zero what we accumulate into
  hipMemsetAsync(d_out, 0, (size_t)out_size * 4, stream);
  hipMemsetAsync(cntbuf, 0, 64 * 4, stream);
  hipMemsetAsync(cursor, 0, (size_t)N * 4, stream);
  hipMemsetAsync(degtmp, 0, (size_t)N * 4, stream);

  // CSR build
  hist_kernel<<<(EN + 255) / 256, 256, 0, stream>>>(ei, degtmp, E, N);
  scan_kernel<<<1, 1024, 0, stream>>>(degtmp, rowptr, N);
  scatter_kernel<<<(EN + 255) / 256, 256, 0, stream>>>(ei, rowptr, cursor, csr, E, N);

  // GRU weight transposes
  transpose_w<<<(384 * 128 + 255) / 256, 256, 0, stream>>>(W_ih, WtA, 384);
  transpose_w<<<(384 * 128 + 255) / 256, 256, 0, stream>>>(W_hh, WtB, 384);

  auto mm = [&](const float* A, const float* B, const float* bias, float* C,
                int M, int Nc, int relu) {
    dim3 g((M + 31) / 32, (Nc + 255) / 256);
    mm_k128<<<g, 128, 0, stream>>>(A, B, bias, C, M, Nc, relu);
  };

  // encoder
  mm(x, enc_W, enc_b, h0, N, HIDC, 1);

  float* hcur = h0;
  float* hnxt = h1;
  for (int l = 0; l < NLAY; ++l) {
    mm(hcur, gat_W + (size_t)l * 128 * 1024, nullptr, xl, N, NHEAD * HIDC, 0);
    alpha_kernel<<<(N + 7) / 8, 256, 0, stream>>>(
        xl, att_src + (size_t)l * NHEAD * HIDC, att_dst + (size_t)l * NHEAD * HIDC,
        aS, aD, N);
    gat_aggregate<<<N, 256, 0, stream>>>(
        xl, rowptr, csr, aS, aD, gat_b + (size_t)l * HIDC, hnxt, N, (l < NLAY - 1) ? 1 : 0);
    float* t = hcur; hcur = hnxt; hnxt = t;
  }

  // GRU
  mm(hcur, WtA, b_ih, gi, N, 384, 0);
  mm(memory, WtB, b_hh, gh, N, 384, 0);
  gru_gate_kernel<<<((N * HIDC) + 255) / 256, 256, 0, stream>>>(gi, gh, memory, hnxt, N);

  // pooling + classifier
  pool_kernel<<<(N + 127) / 128, 128, 0, stream>>>(hnxt, batch, out_pooled, cntbuf, N);
  classifier_kernel<<<NGRAPH, 64, 0, stream>>>(out_pooled, cntbuf, c1W, c1b, c2W, c2b,
                                               out_logits, out_preds);
}

// Round 2
// 1662.836 us; speedup vs baseline: 1.7881x; 1.7881x over previous
//
#include <hip/hip_runtime.h>
#include <cstdint>
#include <cstddef>

#define HIDC 128
#define NHEAD 8
#define NLAY 3
#define NGRAPH 64
#define NCLS 3

typedef __attribute__((ext_vector_type(8))) short short8;
typedef __attribute__((ext_vector_type(4))) float floatx4;

__device__ inline short f2bf(float x) {
  unsigned u = __float_as_uint(x);
  unsigned r = (u + 0x7fff + ((u >> 16) & 1)) >> 16;   // RNE
  return (short)r;
}
__device__ inline float bf2f(unsigned short u) {
  return __uint_as_float(((unsigned)u) << 16);
}

// ---------------------------------------------------------------------------
// Weight prep: Wt[n][k] = W[k][n], bf16   (and straight convert for [n][k] src)
// ---------------------------------------------------------------------------
__global__ void convt_kernel(const float* __restrict__ W, short* __restrict__ Wt,
                             int K, int Nc)
{
  int i = blockIdx.x * 256 + threadIdx.x;
  if (i >= K * Nc) return;
  int k = i / Nc, n = i - k * Nc;
  Wt[(size_t)n * K + k] = f2bf(W[i]);
}

__global__ void conv_kernel(const float* __restrict__ W, short* __restrict__ Wt,
                            int count)
{
  int i = blockIdx.x * 256 + threadIdx.x;
  if (i >= count) return;
  Wt[i] = f2bf(W[i]);
}

// ---------------------------------------------------------------------------
// C[M,Nc] = act(A[M,128] @ B + bias), B given as Bt[Nc][128] bf16.
// Block 256 (4 waves, 2x2 wave grid), 64x64 tile, K=128, bf16 MFMA 16x16x32.
// ---------------------------------------------------------------------------
__global__ __launch_bounds__(256) void mm_bf16(
    const float* __restrict__ A, const short* __restrict__ Bt,
    const float* __restrict__ bias, void* __restrict__ C,
    int M, int Nc, int relu, int out_bf16)
{
  __shared__ short Asl[64 * 136];    // pad to 136 shorts: 16B-aligned rows, 2-way-free banks
  const int tid = threadIdx.x;
  const int m0 = blockIdx.x * 64;
  const int n0 = blockIdx.y * 64;

  // stage A tile fp32 -> bf16 LDS
  const float4* A4 = (const float4*)A;
#pragma unroll
  for (int it = 0; it < 8; ++it) {
    int idx = tid + it * 256;
    int r = idx >> 5, k4 = idx & 31;
    int row = m0 + r; if (row >= M) row = M - 1;
    float4 a = A4[(size_t)row * 32 + k4];
    ushort4 p;
    p.x = (unsigned short)f2bf(a.x); p.y = (unsigned short)f2bf(a.y);
    p.z = (unsigned short)f2bf(a.z); p.w = (unsigned short)f2bf(a.w);
    *(ushort4*)&Asl[r * 136 + k4 * 4] = p;
  }
  __syncthreads();

  const int wid = tid >> 6, lane = tid & 63;
  const int l15 = lane & 15, quad = lane >> 4;
  const int wm = wid & 1, wn = wid >> 1;
  const int mb = wm * 32;              // LDS row base for this wave
  const int nb = n0 + wn * 32;         // global col base

  floatx4 acc00 = {0.f, 0.f, 0.f, 0.f};
  floatx4 acc01 = acc00, acc10 = acc00, acc11 = acc00;

#pragma unroll
  for (int kk = 0; kk < 4; ++kk) {
    int k = kk * 32 + quad * 8;
    short8 a0 = *(const short8*)&Asl[(mb + l15) * 136 + k];
    short8 a1 = *(const short8*)&Asl[(mb + 16 + l15) * 136 + k];
    short8 b0 = *(const short8*)&Bt[(size_t)(nb + l15) * 128 + k];
    short8 b1 = *(const short8*)&Bt[(size_t)(nb + 16 + l15) * 128 + k];
    acc00 = __builtin_amdgcn_mfma_f32_16x16x32_bf16(a0, b0, acc00, 0, 0, 0);
    acc01 = __builtin_amdgcn_mfma_f32_16x16x32_bf16(a0, b1, acc01, 0, 0, 0);
    acc10 = __builtin_amdgcn_mfma_f32_16x16x32_bf16(a1, b0, acc10, 0, 0, 0);
    acc11 = __builtin_amdgcn_mfma_f32_16x16x32_bf16(a1, b1, acc11, 0, 0, 0);
  }

  // epilogue: C/D layout col=lane&15, row=quad*4+reg
  float* Cf = (float*)C;
  unsigned short* Cb = (unsigned short*)C;
#pragma unroll
  for (int mt = 0; mt < 2; ++mt) {
#pragma unroll
    for (int nt = 0; nt < 2; ++nt) {
      floatx4 acc = (mt == 0) ? (nt == 0 ? acc00 : acc01)
                              : (nt == 0 ? acc10 : acc11);
      int colg = nb + nt * 16 + l15;
      float bv = bias ? bias[colg] : 0.f;
#pragma unroll
      for (int r = 0; r < 4; ++r) {
        int rowg = m0 + mb + mt * 16 + quad * 4 + r;
        if (rowg < M) {
          float v = acc[r] + bv;
          if (relu) v = fmaxf(v, 0.f);
          if (out_bf16) Cb[(size_t)rowg * Nc + colg] = (unsigned short)f2bf(v);
          else          Cf[(size_t)rowg * Nc + colg] = v;
        }
      }
    }
  }
}

// ---------------------------------------------------------------------------
// alpha_s[n,h] = sum_c xl[n,h,c]*a_src[h,c] ; xl is bf16. 8 nodes/block.
// ---------------------------------------------------------------------------
__global__ __launch_bounds__(256) void alpha_kernel(
    const unsigned short* __restrict__ xl, const float* __restrict__ a_src,
    const float* __restrict__ a_dst, float* __restrict__ alpha_s,
    float* __restrict__ alpha_d, int N)
{
  __shared__ float s_as[1024], s_ad[1024];
  const int tid = threadIdx.x;
  for (int i = tid; i < 1024; i += 256) { s_as[i] = a_src[i]; s_ad[i] = a_dst[i]; }
  __syncthreads();
  float4 av = ((const float4*)s_as)[tid];
  float4 dv = ((const float4*)s_ad)[tid];
  int head = tid >> 5;
  int n0 = blockIdx.x * 8;
  int n1 = n0 + 8; if (n1 > N) n1 = N;
  const ushort4* xl4 = (const ushort4*)xl;
  for (int n = n0; n < n1; ++n) {
    ushort4 u = xl4[(size_t)n * 256 + tid];
    float vx = bf2f(u.x), vy = bf2f(u.y), vz = bf2f(u.z), vw = bf2f(u.w);
    float ps = vx * av.x + vy * av.y + vz * av.z + vw * av.w;
    float pd = vx * dv.x + vy * dv.y + vz * dv.z + vw * dv.w;
    for (int off = 16; off; off >>= 1) {
      ps += __shfl_xor(ps, off, 32);
      pd += __shfl_xor(pd, off, 32);
    }
    if ((tid & 31) == 0) {
      alpha_s[(size_t)n * NHEAD + head] = ps;
      alpha_d[(size_t)n * NHEAD + head] = pd;
    }
  }
}

// ---------------------------------------------------------------------------
// CSR build (counting sort by dst).
// ---------------------------------------------------------------------------
__global__ void hist_kernel(const int* __restrict__ ei, int* __restrict__ deg, int E, int N)
{
  int i = blockIdx.x * 256 + threadIdx.x;
  if (i >= E + N) return;
  int dst = (i < E) ? ei[E + i] : (i - E);
  atomicAdd(&deg[dst], 1);
}

__global__ __launch_bounds__(1024) void scan_kernel(const int* __restrict__ deg,
                                                    int* __restrict__ rowptr, int N)
{
  __shared__ int sd[1024];
  __shared__ int s_carry;
  if (threadIdx.x == 0) s_carry = 0;
  __syncthreads();
  for (int base = 0; base < N; base += 1024) {
    int i = base + threadIdx.x;
    int v = (i < N) ? deg[i] : 0;
    sd[threadIdx.x] = v;
    __syncthreads();
    for (int off = 1; off < 1024; off <<= 1) {
      int t = (threadIdx.x >= off) ? sd[threadIdx.x - off] : 0;
      __syncthreads();
      sd[threadIdx.x] += t;
      __syncthreads();
    }
    int incl = sd[threadIdx.x];
    int carry = s_carry;
    if (i < N) rowptr[i] = carry + incl - v;   // exclusive prefix
    __syncthreads();
    if (threadIdx.x == 1023) s_carry = carry + sd[1023];
    __syncthreads();
  }
  if (threadIdx.x == 0) rowptr[N] = s_carry;
}

__global__ void scatter_kernel(const int* __restrict__ ei, const int* __restrict__ rowptr,
                               int* __restrict__ cursor, int* __restrict__ csr_src,
                               int E, int N)
{
  int i = blockIdx.x * 256 + threadIdx.x;
  if (i >= E + N) return;
  int src, dst;
  if (i < E) { src = ei[i]; dst = ei[E + i]; }
  else { src = i - E; dst = i - E; }
  int pos = rowptr[dst] + atomicAdd(&cursor[dst], 1);
  csr_src[pos] = src;
}

// ---------------------------------------------------------------------------
// GAT aggregation: one block per dst node; 8 groups of 32 lanes (one head each).
// xl is bf16 [N,8,128]. Edge softmax + weighted gather, head mean.
// ---------------------------------------------------------------------------
#define MAXC 8
__global__ __launch_bounds__(256) void gat_aggregate(
    const unsigned short* __restrict__ xl, const int* __restrict__ rowptr,
    const int* __restrict__ csr_src, const float* __restrict__ alpha_s,
    const float* __restrict__ alpha_d, const float* __restrict__ bias,
    float* __restrict__ out, int N, int do_relu)
{
  const int dst = blockIdx.x;
  const int tid = threadIdx.x;
  const int h = tid >> 5, lane = tid & 31;
  __shared__ float sh[NHEAD * HIDC];
  const int start = rowptr[dst];
  const int deg = rowptr[dst + 1] - start;
  const float ad = alpha_d[(size_t)dst * NHEAD + h];
  const int nch = (deg + 31) >> 5;
  const ushort4* xl4 = (const ushort4*)xl;

  float s_arr[MAXC]; int src_arr[MAXC];
  float m = -1e30f;
  for (int c = 0; c < nch; ++c) {
    int e = c * 32 + lane;
    float s = -1e30f; int src = 0;
    if (e < deg) {
      src = csr_src[start + e];
      s = alpha_s[(size_t)src * NHEAD + h] + ad;
      s = (s > 0.f) ? s : 0.2f * s;
    }
    if (c < MAXC) { s_arr[c] = s; src_arr[c] = src; }
    m = fmaxf(m, s);
  }
  for (int off = 16; off; off >>= 1) m = fmaxf(m, __shfl_xor(m, off, 32));

  float denom = 0.f;
  float4 acc = make_float4(0.f, 0.f, 0.f, 0.f);
  for (int c = 0; c < nch; ++c) {
    int e0 = c * 32;
    float s; int src;
    if (c < MAXC) { s = s_arr[c]; src = src_arr[c]; }
    else {
      int e = e0 + lane; s = -1e30f; src = 0;
      if (e < deg) {
        src = csr_src[start + e];
        s = alpha_s[(size_t)src * NHEAD + h] + ad;
        s = (s > 0.f) ? s : 0.2f * s;
      }
    }
    float p = (e0 + lane < deg) ? __expf(s - m) : 0.f;
    denom += p;
    int cnt_e = deg - e0; if (cnt_e > 32) cnt_e = 32;
    for (int e = 0; e < cnt_e; ++e) {
      float w = __shfl(p, e, 32);
      int se = __shfl(src, e, 32);
      ushort4 u = xl4[(size_t)se * 256 + h * 32 + lane];
      acc.x += w * bf2f(u.x); acc.y += w * bf2f(u.y);
      acc.z += w * bf2f(u.z); acc.w += w * bf2f(u.w);
    }
  }
  for (int off = 16; off; off >>= 1) denom += __shfl_xor(denom, off, 32);
  float inv = 1.f / (denom + 1e-16f);
  float4 r;
  r.x = acc.x * inv; r.y = acc.y * inv; r.z = acc.z * inv; r.w = acc.w * inv;
  ((float4*)sh)[h * 32 + lane] = r;
  __syncthreads();
  if (tid < HIDC) {
    float sum = 0.f;
#pragma unroll
    for (int hh = 0; hh < NHEAD; ++hh) sum += sh[hh * HIDC + tid];
    float val = sum * 0.125f + bias[tid];
    if (do_relu) val = fmaxf(val, 0.f);
    out[(size_t)dst * HIDC + tid] = val;
  }
}

// ---------------------------------------------------------------------------
// GRU gates (torch order r,z,n)
// ---------------------------------------------------------------------------
__global__ __launch_bounds__(256) void gru_gate_kernel(
    const float* __restrict__ gi, const float* __restrict__ gh,
    const float* __restrict__ mem, float* __restrict__ hout, int N)
{
  int idx = blockIdx.x * 256 + threadIdx.x;
  if (idx >= N * HIDC) return;
  int n = idx >> 7, c = idx & 127;
  size_t b = (size_t)n * 384;
  float gir = gi[b + c], giz = gi[b + 128 + c], gin = gi[b + 256 + c];
  float ghr = gh[b + c], ghz = gh[b + 128 + c], ghn = gh[b + 256 + c];
  float rg = 1.f / (1.f + __expf(-(gir + ghr)));
  float zg = 1.f / (1.f + __expf(-(giz + ghz)));
  float ncand = tanhf(gin + rg * ghn);
  hout[idx] = (1.f - zg) * ncand + zg * mem[idx];
}

// ---------------------------------------------------------------------------
// global_mean_pool (batch ids sorted): run-length accumulate + atomic flush.
// ---------------------------------------------------------------------------
__global__ __launch_bounds__(128) void pool_kernel(
    const float* __restrict__ h, const int* __restrict__ batch,
    float* __restrict__ pooled_sums, float* __restrict__ cnt, int N)
{
  int n0 = blockIdx.x * 128;
  int c = threadIdx.x;
  int end = n0 + 128; if (end > N) end = N;
  if (n0 >= N) return;
  int cur = batch[n0];
  float acc = 0.f; float count = 0.f;
  for (int n = n0; n < end; ++n) {
    int b = batch[n];
    if (b != cur) {
      atomicAdd(&pooled_sums[(size_t)cur * HIDC + c], acc);
      if (c == 0) atomicAdd(&cnt[cur], count);
      acc = 0.f; count = 0.f; cur = b;
    }
    acc += h[(size_t)n * HIDC + c];
    count += 1.f;
  }
  atomicAdd(&pooled_sums[(size_t)cur * HIDC + c], acc);
  if (c == 0) atomicAdd(&cnt[cur], count);
}

// ---------------------------------------------------------------------------
// finalize pooled, classifier MLP, softmax (fp32, tiny)
// ---------------------------------------------------------------------------
__global__ __launch_bounds__(64) void classifier_kernel(
    float* __restrict__ pooled, const float* __restrict__ cnt,
    const float* __restrict__ c1W, const float* __restrict__ c1b,
    const float* __restrict__ c2W, const float* __restrict__ c2b,
    float* __restrict__ logits, float* __restrict__ preds)
{
  int g = blockIdx.x, j = threadIdx.x;
  __shared__ float sp[128];
  __shared__ float hid[64];
  __shared__ float lg[3];
  float invc = 1.f / fmaxf(cnt[g], 1.f);
  float p0 = pooled[(size_t)g * 128 + j] * invc;
  float p1 = pooled[(size_t)g * 128 + 64 + j] * invc;
  pooled[(size_t)g * 128 + j] = p0;
  pooled[(size_t)g * 128 + 64 + j] = p1;
  sp[j] = p0; sp[j + 64] = p1;
  __syncthreads();
  float a = c1b[j];
#pragma unroll
  for (int k = 0; k < 128; ++k) a = fmaf(sp[k], c1W[k * 64 + j], a);
  hid[j] = fmaxf(a, 0.f);
  __syncthreads();
  if (j < NCLS) {
    float t = c2b[j];
#pragma unroll
    for (int k = 0; k < 64; ++k) t = fmaf(hid[k], c2W[k * NCLS + j], t);
    logits[(size_t)g * NCLS + j] = t;
    lg[j] = t;
  }
  __syncthreads();
  if (j < NCLS) {
    float mx = fmaxf(lg[0], fmaxf(lg[1], lg[2]));
    float e0 = __expf(lg[0] - mx), e1 = __expf(lg[1] - mx), e2 = __expf(lg[2] - mx);
    float mine = (j == 0) ? e0 : ((j == 1) ? e1 : e2);
    preds[(size_t)g * NCLS + j] = mine / (e0 + e1 + e2);
  }
}

// ---------------------------------------------------------------------------
extern "C" void kernel_launch(void* const* d_in, const int* in_sizes, int n_in,
                              void* d_out, int out_size, void* d_ws, size_t ws_size,
                              hipStream_t stream)
{
  const float* x       = (const float*)d_in[0];
  const int*   ei      = (const int*)d_in[1];     // [2,E] int32
  const int*   batch   = (const int*)d_in[2];
  const float* memory  = (const float*)d_in[3];
  const float* enc_W   = (const float*)d_in[4];
  const float* enc_b   = (const float*)d_in[5];
  const float* gat_W   = (const float*)d_in[6];   // [NL,128,1024]
  const float* att_src = (const float*)d_in[7];   // [NL,8,128]
  const float* att_dst = (const float*)d_in[8];
  const float* gat_b   = (const float*)d_in[9];   // [NL,128]
  const float* W_ih    = (const float*)d_in[10];  // [384,128]
  const float* W_hh    = (const float*)d_in[11];
  const float* b_ih    = (const float*)d_in[12];
  const float* b_hh    = (const float*)d_in[13];
  const float* c1W     = (const float*)d_in[14];  // [128,64]
  const float* c1b     = (const float*)d_in[15];
  const float* c2W     = (const float*)d_in[16];  // [64,3]
  const float* c2b     = (const float*)d_in[17];

  const int N = in_sizes[0] / HIDC;
  const int E = in_sizes[1] / 2;
  const int EN = E + N;

  // workspace layout
  char* ws = (char*)d_ws;
  size_t off = 0;
  auto alloc = [&](size_t bytes) -> void* {
    void* p = ws + off;
    off += (bytes + 255) & ~(size_t)255;
    return p;
  };
  float* h0     = (float*)alloc((size_t)N * HIDC * 4);
  float* h1     = (float*)alloc((size_t)N * HIDC * 4);
  // union: xl (bf16 [N,1024]) while GAT layers run; gi/gh (fp32 [N,384] each) for GRU
  char*  big    = (char*)alloc((size_t)N * 384 * 4 * 2);
  unsigned short* xl = (unsigned short*)big;
  float* gi     = (float*)big;
  float* gh     = gi + (size_t)N * 384;
  float* aS     = (float*)alloc((size_t)N * NHEAD * 4);
  float* aD     = (float*)alloc((size_t)N * NHEAD * 4);
  short* encT   = (short*)alloc((size_t)128 * 128 * 2);
  short* gatT   = (short*)alloc((size_t)NLAY * 1024 * 128 * 2);
  short* ihT    = (short*)alloc((size_t)384 * 128 * 2);
  short* hhT    = (short*)alloc((size_t)384 * 128 * 2);
  int*   rowptr = (int*)alloc((size_t)(N + 1) * 4);
  int*   cursor = (int*)alloc((size_t)N * 4);
  int*   degtmp = (int*)alloc((size_t)N * 4);
  int*   csr    = (int*)alloc((size_t)EN * 4);
  float* cntbuf = (float*)alloc(64 * 4);

  float* out_logits = (float*)d_out;                   // [64,3]
  float* out_pooled = (float*)d_out + NGRAPH * NCLS;   // [64,128]
  float* out_preds  = (float*)d_out + NGRAPH * NCLS + NGRAPH * HIDC;

  // zero what we accumulate into
  hipMemsetAsync(d_out, 0, (size_t)out_size * 4, stream);
  hipMemsetAsync(cntbuf, 0, 64 * 4, stream);
  hipMemsetAsync(cursor, 0, (size_t)N * 4, stream);
  hipMemsetAsync(degtmp, 0, (size_t)N * 4, stream);

  // CSR build
  hist_kernel<<<(EN + 255) / 256, 256, 0, stream>>>(ei, degtmp, E, N);
  scan_kernel<<<1, 1024, 0, stream>>>(degtmp, rowptr, N);
  scatter_kernel<<<(EN + 255) / 256, 256, 0, stream>>>(ei, rowptr, cursor, csr, E, N);

  // weight prep: bf16, [n][k] layout
  convt_kernel<<<(128 * 128 + 255) / 256, 256, 0, stream>>>(enc_W, encT, 128, 128);
  for (int l = 0; l < NLAY; ++l)
    convt_kernel<<<(128 * 1024 + 255) / 256, 256, 0, stream>>>(
        gat_W + (size_t)l * 128 * 1024, gatT + (size_t)l * 1024 * 128, 128, 1024);
  conv_kernel<<<(384 * 128 + 255) / 256, 256, 0, stream>>>(W_ih, ihT, 384 * 128);
  conv_kernel<<<(384 * 128 + 255) / 256, 256, 0, stream>>>(W_hh, hhT, 384 * 128);

  auto mm = [&](const float* A, const short* Bt, const float* bias, void* C,
                int M, int Nc, int relu, int obf) {
    dim3 g((M + 63) / 64, Nc / 64);
    mm_bf16<<<g, 256, 0, stream>>>(A, Bt, bias, C, M, Nc, relu, obf);
  };

  // encoder
  mm(x, encT, enc_b, h0, N, HIDC, 1, 0);

  float* hcur = h0;
  float* hnxt = h1;
  for (int l = 0; l < NLAY; ++l) {
    mm(hcur, gatT + (size_t)l * 1024 * 128, nullptr, xl, N, NHEAD * HIDC, 0, 1);
    alpha_kernel<<<(N + 7) / 8, 256, 0, stream>>>(
        xl, att_src + (size_t)l * NHEAD * HIDC, att_dst + (size_t)l * NHEAD * HIDC,
        aS, aD, N);
    gat_aggregate<<<N, 256, 0, stream>>>(
        xl, rowptr, csr, aS, aD, gat_b + (size_t)l * HIDC, hnxt, N, (l < NLAY - 1) ? 1 : 0);
    float* t = hcur; hcur = hnxt; hnxt = t;
  }

  // GRU (gi/gh overlay xl region — xl is dead here)
  mm(hcur, ihT, b_ih, gi, N, 384, 0, 0);
  mm(memory, hhT, b_hh, gh, N, 384, 0, 0);
  gru_gate_kernel<<<((N * HIDC) + 255) / 256, 256, 0, stream>>>(gi, gh, memory, hnxt, N);

  // pooling + classifier
  pool_kernel<<<(N + 127) / 128, 128, 0, stream>>>(hnxt, batch, out_pooled, cntbuf, N);
  classifier_kernel<<<NGRAPH, 64, 0, stream>>>(out_pooled, cntbuf, c1W, c1b, c2W, c2b,
                                               out_logits, out_preds);
}

// Round 3
// 1314.631 us; speedup vs baseline: 2.2617x; 1.2649x over previous
//
#include <hip/hip_runtime.h>
#include <cstdint>
#include <cstddef>

#define HIDC 128
#define NHEAD 8
#define NLAY 3
#define NGRAPH 64
#define NCLS 3
#define CHUNK 256

typedef __attribute__((ext_vector_type(8))) short short8;
typedef __attribute__((ext_vector_type(4))) float floatx4;

__device__ inline short f2bf(float x) {
  unsigned u = __float_as_uint(x);
  unsigned r = (u + 0x7fff + ((u >> 16) & 1)) >> 16;   // RNE
  return (short)r;
}
__device__ inline float bf2f(unsigned short u) {
  return __uint_as_float(((unsigned)u) << 16);
}

// ---------------------------------------------------------------------------
// Weight prep
// ---------------------------------------------------------------------------
__global__ void convt_kernel(const float* __restrict__ W, short* __restrict__ Wt,
                             int K, int Nc)
{
  int i = blockIdx.x * 256 + threadIdx.x;
  if (i >= K * Nc) return;
  int k = i / Nc, n = i - k * Nc;
  Wt[(size_t)n * K + k] = f2bf(W[i]);
}

__global__ void conv_kernel(const float* __restrict__ W, short* __restrict__ Wt,
                            int count)
{
  int i = blockIdx.x * 256 + threadIdx.x;
  if (i >= count) return;
  Wt[i] = f2bf(W[i]);
}

// Wp[l][c][h*128+k] = gat_W[l][k][h*128+c] / 8   (head-mean folded in)
__global__ void rearr_kernel(const float* __restrict__ gat_W, short* __restrict__ Wp)
{
  int i = blockIdx.x * 256 + threadIdx.x;
  if (i >= NLAY * 131072) return;
  int l = i >> 17, rem = i & 131071;
  int k = rem >> 10, hc = rem & 1023;
  int hh = hc >> 7, cc = hc & 127;
  Wp[(size_t)l * 131072 + (size_t)cc * 1024 + hh * 128 + k] = f2bf(gat_W[i] * 0.125f);
}

// waSD[l][k][j16]: j16<8 -> W_h a_src_h projection, j16>=8 -> a_dst
__global__ __launch_bounds__(256) void wa_kernel(
    const float* __restrict__ gat_W, const float* __restrict__ att_src,
    const float* __restrict__ att_dst, float* __restrict__ waSD)
{
  int l = blockIdx.x;
  for (int idx = threadIdx.x; idx < 2048; idx += 256) {
    int k = idx >> 4, j16 = idx & 15;
    int hh = j16 & 7;
    const float* a = ((j16 < 8) ? att_src : att_dst) + (size_t)l * 1024 + hh * 128;
    const float* w = gat_W + (size_t)l * 131072 + (size_t)k * 1024 + hh * 128;
    float s = 0.f;
    for (int cc = 0; cc < 128; ++cc) s += w[cc] * a[cc];
    waSD[(size_t)l * 2048 + idx] = s;
  }
}

// ---------------------------------------------------------------------------
// C[M,Nc] = act(A_fp32[M,128] @ B + bias), Bt[Nc][128] bf16. 64x64 tile.
// ---------------------------------------------------------------------------
__global__ __launch_bounds__(256) void mm_bf16(
    const float* __restrict__ A, const short* __restrict__ Bt,
    const float* __restrict__ bias, void* __restrict__ C,
    int M, int Nc, int relu, int out_bf16)
{
  __shared__ short Asl[64 * 136];
  const int tid = threadIdx.x;
  const int m0 = blockIdx.x * 64;
  const int n0 = blockIdx.y * 64;

  const float4* A4 = (const float4*)A;
#pragma unroll
  for (int it = 0; it < 8; ++it) {
    int idx = tid + it * 256;
    int r = idx >> 5, k4 = idx & 31;
    int row = m0 + r; if (row >= M) row = M - 1;
    float4 a = A4[(size_t)row * 32 + k4];
    ushort4 p;
    p.x = (unsigned short)f2bf(a.x); p.y = (unsigned short)f2bf(a.y);
    p.z = (unsigned short)f2bf(a.z); p.w = (unsigned short)f2bf(a.w);
    *(ushort4*)&Asl[r * 136 + k4 * 4] = p;
  }
  __syncthreads();

  const int wid = tid >> 6, lane = tid & 63;
  const int l15 = lane & 15, quad = lane >> 4;
  const int wm = wid & 1, wn = wid >> 1;
  const int mb = wm * 32;
  const int nb = n0 + wn * 32;

  floatx4 acc00 = {0.f, 0.f, 0.f, 0.f};
  floatx4 acc01 = acc00, acc10 = acc00, acc11 = acc00;

#pragma unroll
  for (int kk = 0; kk < 4; ++kk) {
    int k = kk * 32 + quad * 8;
    short8 a0 = *(const short8*)&Asl[(mb + l15) * 136 + k];
    short8 a1 = *(const short8*)&Asl[(mb + 16 + l15) * 136 + k];
    short8 b0 = *(const short8*)&Bt[(size_t)(nb + l15) * 128 + k];
    short8 b1 = *(const short8*)&Bt[(size_t)(nb + 16 + l15) * 128 + k];
    acc00 = __builtin_amdgcn_mfma_f32_16x16x32_bf16(a0, b0, acc00, 0, 0, 0);
    acc01 = __builtin_amdgcn_mfma_f32_16x16x32_bf16(a0, b1, acc01, 0, 0, 0);
    acc10 = __builtin_amdgcn_mfma_f32_16x16x32_bf16(a1, b0, acc10, 0, 0, 0);
    acc11 = __builtin_amdgcn_mfma_f32_16x16x32_bf16(a1, b1, acc11, 0, 0, 0);
  }

  float* Cf = (float*)C;
  unsigned short* Cb = (unsigned short*)C;
#pragma unroll
  for (int mt = 0; mt < 2; ++mt) {
#pragma unroll
    for (int nt = 0; nt < 2; ++nt) {
      floatx4 acc = (mt == 0) ? (nt == 0 ? acc00 : acc01)
                              : (nt == 0 ? acc10 : acc11);
      int colg = nb + nt * 16 + l15;
      float bv = bias ? bias[colg] : 0.f;
#pragma unroll
      for (int r = 0; r < 4; ++r) {
        int rowg = m0 + mb + mt * 16 + quad * 4 + r;
        if (rowg < M && colg < Nc) {
          float v = acc[r] + bv;
          if (relu) v = fmaxf(v, 0.f);
          if (out_bf16) Cb[(size_t)rowg * Nc + colg] = (unsigned short)f2bf(v);
          else          Cf[(size_t)rowg * Nc + colg] = v;
        }
      }
    }
  }
}

// ---------------------------------------------------------------------------
// C[M,128] = act(A_bf16[M,K] @ B + bias), Bt[128][K] bf16, K mult of 64.
// 64x128 tile, 4 waves: 2 m-groups x 2 n-groups of 64 cols.
// ---------------------------------------------------------------------------
__global__ __launch_bounds__(256) void mm_bf16A(
    const unsigned short* __restrict__ A, const short* __restrict__ Bt,
    const float* __restrict__ bias, void* __restrict__ C,
    int M, int Nc, int K, int relu, int out_bf16)
{
  __shared__ short As[64 * 72];
  const int tid = threadIdx.x;
  const int m0 = blockIdx.x * 64;
  const int n0 = blockIdx.y * 128;
  const int wid = tid >> 6, lane = tid & 63;
  const int l15 = lane & 15, quad = lane >> 4;
  const int wm = wid & 1, wn = wid >> 1;
  const int mb = wm * 32;
  const int nb = n0 + wn * 64;

  floatx4 acc[2][4];
#pragma unroll
  for (int a = 0; a < 2; ++a)
#pragma unroll
    for (int g = 0; g < 4; ++g) acc[a][g] = (floatx4){0.f, 0.f, 0.f, 0.f};

  for (int kb = 0; kb < K; kb += 64) {
    __syncthreads();
#pragma unroll
    for (int it = 0; it < 2; ++it) {
      int idx = tid + it * 256;
      int r = idx >> 3, k8 = (idx & 7) * 8;
      int row = m0 + r; if (row >= M) row = M - 1;
      *(short8*)&As[r * 72 + k8] = *(const short8*)&A[(size_t)row * K + kb + k8];
    }
    __syncthreads();
#pragma unroll
    for (int kk = 0; kk < 2; ++kk) {
      int ko = kk * 32 + quad * 8;
      short8 a0 = *(const short8*)&As[(mb + l15) * 72 + ko];
      short8 a1 = *(const short8*)&As[(mb + 16 + l15) * 72 + ko];
#pragma unroll
      for (int g = 0; g < 4; ++g) {
        int col = nb + g * 16 + l15; if (col >= Nc) col = Nc - 1;
        short8 b = *(const short8*)&Bt[(size_t)col * K + kb + ko];
        acc[0][g] = __builtin_amdgcn_mfma_f32_16x16x32_bf16(a0, b, acc[0][g], 0, 0, 0);
        acc[1][g] = __builtin_amdgcn_mfma_f32_16x16x32_bf16(a1, b, acc[1][g], 0, 0, 0);
      }
    }
  }

  float* Cf = (float*)C;
  unsigned short* Cb = (unsigned short*)C;
#pragma unroll
  for (int mt = 0; mt < 2; ++mt) {
#pragma unroll
    for (int g = 0; g < 4; ++g) {
      int colg = nb + g * 16 + l15;
      if (colg >= Nc) continue;
      float bv = bias ? bias[colg] : 0.f;
#pragma unroll
      for (int r = 0; r < 4; ++r) {
        int rowg = m0 + mb + mt * 16 + quad * 4 + r;
        if (rowg < M) {
          float v = acc[mt][g][r] + bv;
          if (relu) v = fmaxf(v, 0.f);
          if (out_bf16) Cb[(size_t)rowg * Nc + colg] = (unsigned short)f2bf(v);
          else          Cf[(size_t)rowg * Nc + colg] = v;
        }
      }
    }
  }
}

// ---------------------------------------------------------------------------
// alphas via precomputed projection: aS/aD[n][h] = h[n,:] . waSD[:,j16]
// 16 nodes per 256-thread block; thread j16 of a node does a full dot-128.
// ---------------------------------------------------------------------------
__global__ __launch_bounds__(256) void alpha2_kernel(
    const float* __restrict__ h, const float* __restrict__ waSD,
    float* __restrict__ aS, float* __restrict__ aD, int N)
{
  __shared__ float s_wa[2048];
  const int tid = threadIdx.x;
  for (int i = tid; i < 2048; i += 256) s_wa[i] = waSD[i];
  __syncthreads();
  int node = blockIdx.x * 16 + (tid >> 4);
  int j = tid & 15;
  if (node >= N) return;
  const float4* h4 = (const float4*)(h + (size_t)node * 128);
  float s = 0.f;
#pragma unroll
  for (int k4 = 0; k4 < 32; ++k4) {
    float4 v = h4[k4];
    s += v.x * s_wa[(k4 * 4 + 0) * 16 + j];
    s += v.y * s_wa[(k4 * 4 + 1) * 16 + j];
    s += v.z * s_wa[(k4 * 4 + 2) * 16 + j];
    s += v.w * s_wa[(k4 * 4 + 3) * 16 + j];
  }
  if (j < 8) aS[(size_t)node * 8 + j] = s;
  else       aD[(size_t)node * 8 + (j - 8)] = s;
}

// ---------------------------------------------------------------------------
// CSR build (counting sort by dst).
// ---------------------------------------------------------------------------
__global__ void hist_kernel(const int* __restrict__ ei, int* __restrict__ deg, int E, int N)
{
  int i = blockIdx.x * 256 + threadIdx.x;
  if (i >= E + N) return;
  int dst = (i < E) ? ei[E + i] : (i - E);
  atomicAdd(&deg[dst], 1);
}

__global__ __launch_bounds__(1024) void scan_kernel(const int* __restrict__ deg,
                                                    int* __restrict__ rowptr, int N)
{
  __shared__ int sd[1024];
  __shared__ int s_carry;
  if (threadIdx.x == 0) s_carry = 0;
  __syncthreads();
  for (int base = 0; base < N; base += 1024) {
    int i = base + threadIdx.x;
    int v = (i < N) ? deg[i] : 0;
    sd[threadIdx.x] = v;
    __syncthreads();
    for (int off = 1; off < 1024; off <<= 1) {
      int t = (threadIdx.x >= off) ? sd[threadIdx.x - off] : 0;
      __syncthreads();
      sd[threadIdx.x] += t;
      __syncthreads();
    }
    int incl = sd[threadIdx.x];
    int carry = s_carry;
    if (i < N) rowptr[i] = carry + incl - v;
    __syncthreads();
    if (threadIdx.x == 1023) s_carry = carry + sd[1023];
    __syncthreads();
  }
  if (threadIdx.x == 0) rowptr[N] = s_carry;
}

__global__ void scatter_kernel(const int* __restrict__ ei, const int* __restrict__ rowptr,
                               int* __restrict__ cursor, int* __restrict__ csr_src,
                               int E, int N)
{
  int i = blockIdx.x * 256 + threadIdx.x;
  if (i >= E + N) return;
  int src, dst;
  if (i < E) { src = ei[i]; dst = ei[E + i]; }
  else { src = i - E; dst = i - E; }
  int pos = rowptr[dst] + atomicAdd(&cursor[dst], 1);
  csr_src[pos] = src;
}

// ---------------------------------------------------------------------------
// Aggregate-then-transform GAT: per dst, edge softmax over precomputed alphas,
// then agg[dst,h,:] = sum_e p_eh * h[src_e,:] (normalized), bf16 out.
// Block 256: pass A layout (el,hh)=(tid>>3,tid&7); pass B (c,half)=(tid&127,tid>>7).
// ---------------------------------------------------------------------------
__global__ __launch_bounds__(256) void gat_aggregate2(
    const float* __restrict__ h, const int* __restrict__ rowptr,
    const int* __restrict__ csr_src, const float* __restrict__ aS,
    const float* __restrict__ aD, unsigned short* __restrict__ agg, int N)
{
  const int dst = blockIdx.x;
  const int tid = threadIdx.x;
  __shared__ int s_src[CHUNK];
  __shared__ float s_pe[CHUNK * 8];
  __shared__ float s_red[256];
  __shared__ float m8[8], d8[8];
  const int start = rowptr[dst];
  const int deg = rowptr[dst + 1] - start;
  const int el = tid >> 3, hh = tid & 7;
  const float adh = aD[(size_t)dst * 8 + hh];

  // pass 1: per-head max of leaky_relu(alpha_s[src]+alpha_d[dst])
  float m = -1e30f;
  for (int base = 0; base < deg; base += 32) {
    int e = base + el;
    if (e < deg) {
      int s = csr_src[start + e];
      float v = aS[(size_t)s * 8 + hh] + adh;
      v = (v > 0.f) ? v : 0.2f * v;
      m = fmaxf(m, v);
    }
  }
  s_red[tid] = m;
  __syncthreads();
  for (int off = 128; off >= 8; off >>= 1) {
    if (tid < off) s_red[tid] = fmaxf(s_red[tid], s_red[tid + off]);
    __syncthreads();
  }
  if (tid < 8) m8[tid] = s_red[tid];
  __syncthreads();

  const int c = tid & 127, half = tid >> 7;
  float acc[8];
#pragma unroll
  for (int q = 0; q < 8; ++q) acc[q] = 0.f;
  float dsum = 0.f;
  const float mh = m8[hh];

  for (int base = 0; base < deg; base += CHUNK) {
    int cend = deg - base; if (cend > CHUNK) cend = CHUNK;
    if (tid < cend) s_src[tid] = csr_src[start + base + tid];
    __syncthreads();
    for (int sb = 0; sb < cend; sb += 32) {
      int e = sb + el;
      if (e < cend) {
        float v = aS[(size_t)s_src[e] * 8 + hh] + adh;
        v = (v > 0.f) ? v : 0.2f * v;
        float p = __expf(v - mh);
        s_pe[e * 8 + hh] = p;
        dsum += p;
      }
    }
    __syncthreads();
    for (int e = half; e < cend; e += 2) {
      float hv = h[(size_t)s_src[e] * 128 + c];
#pragma unroll
      for (int q = 0; q < 8; ++q) acc[q] += s_pe[e * 8 + q] * hv;
    }
    __syncthreads();
  }

  // denom reduce (head classes preserved: strides are multiples of 8)
  s_red[tid] = dsum;
  __syncthreads();
  for (int off = 128; off >= 8; off >>= 1) {
    if (tid < off) s_red[tid] += s_red[tid + off];
    __syncthreads();
  }
  if (tid < 8) d8[tid] = s_red[tid];
  __syncthreads();

  if (half == 1) {
#pragma unroll
    for (int q = 0; q < 8; ++q) s_pe[c * 8 + q] = acc[q];
  }
  __syncthreads();
  if (half == 0) {
#pragma unroll
    for (int q = 0; q < 8; ++q) {
      float tot = (acc[q] + s_pe[c * 8 + q]) / (d8[q] + 1e-16f);
      agg[((size_t)dst * 8 + q) * 128 + c] = (unsigned short)f2bf(tot);
    }
  }
}

// ---------------------------------------------------------------------------
// GRU gates (torch order r,z,n)
// ---------------------------------------------------------------------------
__global__ __launch_bounds__(256) void gru_gate_kernel(
    const float* __restrict__ gi, const float* __restrict__ gh,
    const float* __restrict__ mem, float* __restrict__ hout, int N)
{
  int idx = blockIdx.x * 256 + threadIdx.x;
  if (idx >= N * HIDC) return;
  int n = idx >> 7, c = idx & 127;
  size_t b = (size_t)n * 384;
  float gir = gi[b + c], giz = gi[b + 128 + c], gin = gi[b + 256 + c];
  float ghr = gh[b + c], ghz = gh[b + 128 + c], ghn = gh[b + 256 + c];
  float rg = 1.f / (1.f + __expf(-(gir + ghr)));
  float zg = 1.f / (1.f + __expf(-(giz + ghz)));
  float ncand = tanhf(gin + rg * ghn);
  hout[idx] = (1.f - zg) * ncand + zg * mem[idx];
}

// ---------------------------------------------------------------------------
// global_mean_pool
// ---------------------------------------------------------------------------
__global__ __launch_bounds__(128) void pool_kernel(
    const float* __restrict__ h, const int* __restrict__ batch,
    float* __restrict__ pooled_sums, float* __restrict__ cnt, int N)
{
  int n0 = blockIdx.x * 128;
  int c = threadIdx.x;
  int end = n0 + 128; if (end > N) end = N;
  if (n0 >= N) return;
  int cur = batch[n0];
  float acc = 0.f; float count = 0.f;
  for (int n = n0; n < end; ++n) {
    int b = batch[n];
    if (b != cur) {
      atomicAdd(&pooled_sums[(size_t)cur * HIDC + c], acc);
      if (c == 0) atomicAdd(&cnt[cur], count);
      acc = 0.f; count = 0.f; cur = b;
    }
    acc += h[(size_t)n * HIDC + c];
    count += 1.f;
  }
  atomicAdd(&pooled_sums[(size_t)cur * HIDC + c], acc);
  if (c == 0) atomicAdd(&cnt[cur], count);
}

// ---------------------------------------------------------------------------
// finalize pooled, classifier MLP, softmax
// ---------------------------------------------------------------------------
__global__ __launch_bounds__(64) void classifier_kernel(
    float* __restrict__ pooled, const float* __restrict__ cnt,
    const float* __restrict__ c1W, const float* __restrict__ c1b,
    const float* __restrict__ c2W, const float* __restrict__ c2b,
    float* __restrict__ logits, float* __restrict__ preds)
{
  int g = blockIdx.x, j = threadIdx.x;
  __shared__ float sp[128];
  __shared__ float hid[64];
  __shared__ float lg[3];
  float invc = 1.f / fmaxf(cnt[g], 1.f);
  float p0 = pooled[(size_t)g * 128 + j] * invc;
  float p1 = pooled[(size_t)g * 128 + 64 + j] * invc;
  pooled[(size_t)g * 128 + j] = p0;
  pooled[(size_t)g * 128 + 64 + j] = p1;
  sp[j] = p0; sp[j + 64] = p1;
  __syncthreads();
  float a = c1b[j];
#pragma unroll
  for (int k = 0; k < 128; ++k) a = fmaf(sp[k], c1W[k * 64 + j], a);
  hid[j] = fmaxf(a, 0.f);
  __syncthreads();
  if (j < NCLS) {
    float t = c2b[j];
#pragma unroll
    for (int k = 0; k < 64; ++k) t = fmaf(hid[k], c2W[k * NCLS + j], t);
    logits[(size_t)g * NCLS + j] = t;
    lg[j] = t;
  }
  __syncthreads();
  if (j < NCLS) {
    float mx = fmaxf(lg[0], fmaxf(lg[1], lg[2]));
    float e0 = __expf(lg[0] - mx), e1 = __expf(lg[1] - mx), e2 = __expf(lg[2] - mx);
    float mine = (j == 0) ? e0 : ((j == 1) ? e1 : e2);
    preds[(size_t)g * NCLS + j] = mine / (e0 + e1 + e2);
  }
}

// ---------------------------------------------------------------------------
extern "C" void kernel_launch(void* const* d_in, const int* in_sizes, int n_in,
                              void* d_out, int out_size, void* d_ws, size_t ws_size,
                              hipStream_t stream)
{
  const float* x       = (const float*)d_in[0];
  const int*   ei      = (const int*)d_in[1];
  const int*   batch   = (const int*)d_in[2];
  const float* memory  = (const float*)d_in[3];
  const float* enc_W   = (const float*)d_in[4];
  const float* enc_b   = (const float*)d_in[5];
  const float* gat_W   = (const float*)d_in[6];   // [NL,128,1024]
  const float* att_src = (const float*)d_in[7];
  const float* att_dst = (const float*)d_in[8];
  const float* gat_b   = (const float*)d_in[9];
  const float* W_ih    = (const float*)d_in[10];
  const float* W_hh    = (const float*)d_in[11];
  const float* b_ih    = (const float*)d_in[12];
  const float* b_hh    = (const float*)d_in[13];
  const float* c1W     = (const float*)d_in[14];
  const float* c1b     = (const float*)d_in[15];
  const float* c2W     = (const float*)d_in[16];
  const float* c2b     = (const float*)d_in[17];

  const int N = in_sizes[0] / HIDC;
  const int E = in_sizes[1] / 2;
  const int EN = E + N;

  char* ws = (char*)d_ws;
  size_t off = 0;
  auto alloc = [&](size_t bytes) -> void* {
    void* p = ws + off;
    off += (bytes + 255) & ~(size_t)255;
    return p;
  };
  float* h0     = (float*)alloc((size_t)N * HIDC * 4);
  float* h1     = (float*)alloc((size_t)N * HIDC * 4);
  // union: agg bf16 [N,1024] while GAT layers run; gi/gh fp32 [N,384] each for GRU
  char*  big    = (char*)alloc((size_t)N * 384 * 4 * 2);
  unsigned short* agg = (unsigned short*)big;
  float* gi     = (float*)big;
  float* gh     = gi + (size_t)N * 384;
  float* aS     = (float*)alloc((size_t)N * NHEAD * 4);
  float* aD     = (float*)alloc((size_t)N * NHEAD * 4);
  short* encT   = (short*)alloc((size_t)128 * 128 * 2);
  short* Wp     = (short*)alloc((size_t)NLAY * 131072 * 2);
  float* waSD   = (float*)alloc((size_t)NLAY * 2048 * 4);
  short* ihT    = (short*)alloc((size_t)384 * 128 * 2);
  short* hhT    = (short*)alloc((size_t)384 * 128 * 2);
  int*   rowptr = (int*)alloc((size_t)(N + 1) * 4);
  int*   cursor = (int*)alloc((size_t)N * 4);
  int*   degtmp = (int*)alloc((size_t)N * 4);
  int*   csr    = (int*)alloc((size_t)EN * 4);
  float* cntbuf = (float*)alloc(64 * 4);

  float* out_logits = (float*)d_out;
  float* out_pooled = (float*)d_out + NGRAPH * NCLS;
  float* out_preds  = (float*)d_out + NGRAPH * NCLS + NGRAPH * HIDC;

  hipMemsetAsync(d_out, 0, (size_t)out_size * 4, stream);
  hipMemsetAsync(cntbuf, 0, 64 * 4, stream);
  hipMemsetAsync(cursor, 0, (size_t)N * 4, stream);
  hipMemsetAsync(degtmp, 0, (size_t)N * 4, stream);

  // CSR build
  hist_kernel<<<(EN + 255) / 256, 256, 0, stream>>>(ei, degtmp, E, N);
  scan_kernel<<<1, 1024, 0, stream>>>(degtmp, rowptr, N);
  scatter_kernel<<<(EN + 255) / 256, 256, 0, stream>>>(ei, rowptr, cursor, csr, E, N);

  // weight prep
  convt_kernel<<<(128 * 128 + 255) / 256, 256, 0, stream>>>(enc_W, encT, 128, 128);
  rearr_kernel<<<(NLAY * 131072 + 255) / 256, 256, 0, stream>>>(gat_W, Wp);
  wa_kernel<<<NLAY, 256, 0, stream>>>(gat_W, att_src, att_dst, waSD);
  conv_kernel<<<(384 * 128 + 255) / 256, 256, 0, stream>>>(W_ih, ihT, 384 * 128);
  conv_kernel<<<(384 * 128 + 255) / 256, 256, 0, stream>>>(W_hh, hhT, 384 * 128);

  auto mm = [&](const float* A, const short* Bt, const float* bias, void* C,
                int M, int Nc, int relu, int obf) {
    dim3 g((M + 63) / 64, (Nc + 63) / 64);
    mm_bf16<<<g, 256, 0, stream>>>(A, Bt, bias, C, M, Nc, relu, obf);
  };

  // encoder: h0 = relu(x @ enc_W + enc_b), fp32 out
  mm(x, encT, enc_b, h0, N, HIDC, 1, 0);

  float* hcur = h0;
  float* hnxt = h1;
  for (int l = 0; l < NLAY; ++l) {
    alpha2_kernel<<<(N + 15) / 16, 256, 0, stream>>>(
        hcur, waSD + (size_t)l * 2048, aS, aD, N);
    gat_aggregate2<<<N, 256, 0, stream>>>(hcur, rowptr, csr, aS, aD, agg, N);
    dim3 g((N + 63) / 64, 1);
    mm_bf16A<<<g, 256, 0, stream>>>(agg, Wp + (size_t)l * 131072,
                                    gat_b + (size_t)l * HIDC, hnxt,
                                    N, HIDC, 1024, (l < NLAY - 1) ? 1 : 0, 0);
    float* t = hcur; hcur = hnxt; hnxt = t;
  }

  // GRU (gi/gh overlay agg region — agg is dead here)
  mm(hcur, ihT, b_ih, gi, N, 384, 0, 0);
  mm(memory, hhT, b_hh, gh, N, 384, 0, 0);
  gru_gate_kernel<<<((N * HIDC) + 255) / 256, 256, 0, stream>>>(gi, gh, memory, hnxt, N);

  // pooling + classifier
  pool_kernel<<<(N + 127) / 128, 128, 0, stream>>>(hnxt, batch, out_pooled, cntbuf, N);
  classifier_kernel<<<NGRAPH, 64, 0, stream>>>(out_pooled, cntbuf, c1W, c1b, c2W, c2b,
                                               out_logits, out_preds);
}

// Round 4
// 980.466 us; speedup vs baseline: 3.0326x; 1.3408x over previous
//
#include <hip/hip_runtime.h>
#include <cstdint>
#include <cstddef>

#define HIDC 128
#define NHEAD 8
#define NLAY 3
#define NGRAPH 64
#define NCLS 3
#define MAXI 6   // cached edge-groups per lane: fast path deg <= 48

typedef __attribute__((ext_vector_type(8))) short short8;
typedef __attribute__((ext_vector_type(4))) float floatx4;

__device__ inline short f2bf(float x) {
  unsigned u = __float_as_uint(x);
  unsigned r = (u + 0x7fff + ((u >> 16) & 1)) >> 16;   // RNE
  return (short)r;
}
__device__ inline float bf2f(unsigned short u) {
  return __uint_as_float(((unsigned)u) << 16);
}

// ---------------------------------------------------------------------------
// Weight prep
// ---------------------------------------------------------------------------
__global__ void convt_kernel(const float* __restrict__ W, short* __restrict__ Wt,
                             int K, int Nc)
{
  int i = blockIdx.x * 256 + threadIdx.x;
  if (i >= K * Nc) return;
  int k = i / Nc, n = i - k * Nc;
  Wt[(size_t)n * K + k] = f2bf(W[i]);
}

__global__ void conv_kernel(const float* __restrict__ W, short* __restrict__ Wt,
                            int count)
{
  int i = blockIdx.x * 256 + threadIdx.x;
  if (i >= count) return;
  Wt[i] = f2bf(W[i]);
}

// Wp[l][c][h*128+k] = gat_W[l][k][h*128+c] / 8   (head-mean folded in)
__global__ void rearr_kernel(const float* __restrict__ gat_W, short* __restrict__ Wp)
{
  int i = blockIdx.x * 256 + threadIdx.x;
  if (i >= NLAY * 131072) return;
  int l = i >> 17, rem = i & 131071;
  int k = rem >> 10, hc = rem & 1023;
  int hh = hc >> 7, cc = hc & 127;
  Wp[(size_t)l * 131072 + (size_t)cc * 1024 + hh * 128 + k] = f2bf(gat_W[i] * 0.125f);
}

// waSD[l][k][j16]: j16<8 -> W_h a_src_h projection, j16>=8 -> a_dst
__global__ __launch_bounds__(256) void wa_kernel(
    const float* __restrict__ gat_W, const float* __restrict__ att_src,
    const float* __restrict__ att_dst, float* __restrict__ waSD)
{
  int l = blockIdx.x;
  int idx = blockIdx.y * 256 + threadIdx.x;
  int k = idx >> 4, j16 = idx & 15;
  int hh = j16 & 7;
  const float* a = ((j16 < 8) ? att_src : att_dst) + (size_t)l * 1024 + hh * 128;
  const float* w = gat_W + (size_t)l * 131072 + (size_t)k * 1024 + hh * 128;
  float s = 0.f;
  for (int cc = 0; cc < 128; ++cc) s += w[cc] * a[cc];
  waSD[(size_t)l * 2048 + idx] = s;
}

// ---------------------------------------------------------------------------
// C[M,Nc] = act(A_fp32[M,128] @ B + bias), Bt[Nc][128] bf16. 64x64 tile.
// Writes fp32 C and optional bf16 mirror Cb2.
// ---------------------------------------------------------------------------
__global__ __launch_bounds__(256) void mm_bf16(
    const float* __restrict__ A, const short* __restrict__ Bt,
    const float* __restrict__ bias, float* __restrict__ Cf,
    unsigned short* __restrict__ Cb2, int M, int Nc, int relu)
{
  __shared__ short Asl[64 * 136];
  const int tid = threadIdx.x;
  const int m0 = blockIdx.x * 64;
  const int n0 = blockIdx.y * 64;

  const float4* A4 = (const float4*)A;
#pragma unroll
  for (int it = 0; it < 8; ++it) {
    int idx = tid + it * 256;
    int r = idx >> 5, k4 = idx & 31;
    int row = m0 + r; if (row >= M) row = M - 1;
    float4 a = A4[(size_t)row * 32 + k4];
    ushort4 p;
    p.x = (unsigned short)f2bf(a.x); p.y = (unsigned short)f2bf(a.y);
    p.z = (unsigned short)f2bf(a.z); p.w = (unsigned short)f2bf(a.w);
    *(ushort4*)&Asl[r * 136 + k4 * 4] = p;
  }
  __syncthreads();

  const int wid = tid >> 6, lane = tid & 63;
  const int l15 = lane & 15, quad = lane >> 4;
  const int wm = wid & 1, wn = wid >> 1;
  const int mb = wm * 32;
  const int nb = n0 + wn * 32;

  floatx4 acc00 = {0.f, 0.f, 0.f, 0.f};
  floatx4 acc01 = acc00, acc10 = acc00, acc11 = acc00;

#pragma unroll
  for (int kk = 0; kk < 4; ++kk) {
    int k = kk * 32 + quad * 8;
    short8 a0 = *(const short8*)&Asl[(mb + l15) * 136 + k];
    short8 a1 = *(const short8*)&Asl[(mb + 16 + l15) * 136 + k];
    short8 b0 = *(const short8*)&Bt[(size_t)(nb + l15) * 128 + k];
    short8 b1 = *(const short8*)&Bt[(size_t)(nb + 16 + l15) * 128 + k];
    acc00 = __builtin_amdgcn_mfma_f32_16x16x32_bf16(a0, b0, acc00, 0, 0, 0);
    acc01 = __builtin_amdgcn_mfma_f32_16x16x32_bf16(a0, b1, acc01, 0, 0, 0);
    acc10 = __builtin_amdgcn_mfma_f32_16x16x32_bf16(a1, b0, acc10, 0, 0, 0);
    acc11 = __builtin_amdgcn_mfma_f32_16x16x32_bf16(a1, b1, acc11, 0, 0, 0);
  }

#pragma unroll
  for (int mt = 0; mt < 2; ++mt) {
#pragma unroll
    for (int nt = 0; nt < 2; ++nt) {
      floatx4 acc = (mt == 0) ? (nt == 0 ? acc00 : acc01)
                              : (nt == 0 ? acc10 : acc11);
      int colg = nb + nt * 16 + l15;
      float bv = bias ? bias[colg] : 0.f;
#pragma unroll
      for (int r = 0; r < 4; ++r) {
        int rowg = m0 + mb + mt * 16 + quad * 4 + r;
        if (rowg < M && colg < Nc) {
          float v = acc[r] + bv;
          if (relu) v = fmaxf(v, 0.f);
          Cf[(size_t)rowg * Nc + colg] = v;
          if (Cb2) Cb2[(size_t)rowg * Nc + colg] = (unsigned short)f2bf(v);
        }
      }
    }
  }
}

// ---------------------------------------------------------------------------
// C[M,128] = act(A_bf16[M,K] @ B + bias), Bt[128][K] bf16, K mult of 64.
// fp32 out + optional bf16 mirror.
// ---------------------------------------------------------------------------
__global__ __launch_bounds__(256) void mm_bf16A(
    const unsigned short* __restrict__ A, const short* __restrict__ Bt,
    const float* __restrict__ bias, float* __restrict__ Cf,
    unsigned short* __restrict__ Cb2, int M, int Nc, int K, int relu)
{
  __shared__ short As[64 * 72];
  const int tid = threadIdx.x;
  const int m0 = blockIdx.x * 64;
  const int n0 = blockIdx.y * 128;
  const int wid = tid >> 6, lane = tid & 63;
  const int l15 = lane & 15, quad = lane >> 4;
  const int wm = wid & 1, wn = wid >> 1;
  const int mb = wm * 32;
  const int nb = n0 + wn * 64;

  floatx4 acc[2][4];
#pragma unroll
  for (int a = 0; a < 2; ++a)
#pragma unroll
    for (int g = 0; g < 4; ++g) acc[a][g] = (floatx4){0.f, 0.f, 0.f, 0.f};

  for (int kb = 0; kb < K; kb += 64) {
    __syncthreads();
#pragma unroll
    for (int it = 0; it < 2; ++it) {
      int idx = tid + it * 256;
      int r = idx >> 3, k8 = (idx & 7) * 8;
      int row = m0 + r; if (row >= M) row = M - 1;
      *(short8*)&As[r * 72 + k8] = *(const short8*)&A[(size_t)row * K + kb + k8];
    }
    __syncthreads();
#pragma unroll
    for (int kk = 0; kk < 2; ++kk) {
      int ko = kk * 32 + quad * 8;
      short8 a0 = *(const short8*)&As[(mb + l15) * 72 + ko];
      short8 a1 = *(const short8*)&As[(mb + 16 + l15) * 72 + ko];
#pragma unroll
      for (int g = 0; g < 4; ++g) {
        int col = nb + g * 16 + l15; if (col >= Nc) col = Nc - 1;
        short8 b = *(const short8*)&Bt[(size_t)col * K + kb + ko];
        acc[0][g] = __builtin_amdgcn_mfma_f32_16x16x32_bf16(a0, b, acc[0][g], 0, 0, 0);
        acc[1][g] = __builtin_amdgcn_mfma_f32_16x16x32_bf16(a1, b, acc[1][g], 0, 0, 0);
      }
    }
  }

#pragma unroll
  for (int mt = 0; mt < 2; ++mt) {
#pragma unroll
    for (int g = 0; g < 4; ++g) {
      int colg = nb + g * 16 + l15;
      if (colg >= Nc) continue;
      float bv = bias ? bias[colg] : 0.f;
#pragma unroll
      for (int r = 0; r < 4; ++r) {
        int rowg = m0 + mb + mt * 16 + quad * 4 + r;
        if (rowg < M) {
          float v = acc[mt][g][r] + bv;
          if (relu) v = fmaxf(v, 0.f);
          Cf[(size_t)rowg * Nc + colg] = v;
          if (Cb2) Cb2[(size_t)rowg * Nc + colg] = (unsigned short)f2bf(v);
        }
      }
    }
  }
}

// ---------------------------------------------------------------------------
// alphas via precomputed projection: aS/aD[n][h] = h[n,:] . waSD[:,j16]
// ---------------------------------------------------------------------------
__global__ __launch_bounds__(256) void alpha2_kernel(
    const float* __restrict__ h, const float* __restrict__ waSD,
    float* __restrict__ aS, float* __restrict__ aD, int N)
{
  __shared__ float s_wa[2048];
  const int tid = threadIdx.x;
  for (int i = tid; i < 2048; i += 256) s_wa[i] = waSD[i];
  __syncthreads();
  int node = blockIdx.x * 16 + (tid >> 4);
  int j = tid & 15;
  if (node >= N) return;
  const float4* h4 = (const float4*)(h + (size_t)node * 128);
  float s = 0.f;
#pragma unroll
  for (int k4 = 0; k4 < 32; ++k4) {
    float4 v = h4[k4];
    s += v.x * s_wa[(k4 * 4 + 0) * 16 + j];
    s += v.y * s_wa[(k4 * 4 + 1) * 16 + j];
    s += v.z * s_wa[(k4 * 4 + 2) * 16 + j];
    s += v.w * s_wa[(k4 * 4 + 3) * 16 + j];
  }
  if (j < 8) aS[(size_t)node * 8 + j] = s;
  else       aD[(size_t)node * 8 + (j - 8)] = s;
}

// ---------------------------------------------------------------------------
// CSR build: histogram, 3-stage scan, scatter
// ---------------------------------------------------------------------------
__global__ void hist_kernel(const int* __restrict__ ei, int* __restrict__ deg, int E, int N)
{
  int i = blockIdx.x * 256 + threadIdx.x;
  if (i >= E + N) return;
  int dst = (i < E) ? ei[E + i] : (i - E);
  atomicAdd(&deg[dst], 1);
}

__global__ __launch_bounds__(1024) void scan1_kernel(
    const int* __restrict__ deg, int* __restrict__ rowptr,
    int* __restrict__ bsum, int N)
{
  __shared__ int sd[1024];
  int i = blockIdx.x * 1024 + threadIdx.x;
  int v = (i < N) ? deg[i] : 0;
  sd[threadIdx.x] = v;
  __syncthreads();
  for (int off = 1; off < 1024; off <<= 1) {
    int t = (threadIdx.x >= off) ? sd[threadIdx.x - off] : 0;
    __syncthreads();
    sd[threadIdx.x] += t;
    __syncthreads();
  }
  if (i < N) rowptr[i] = sd[threadIdx.x] - v;
  if (threadIdx.x == 1023) bsum[blockIdx.x] = sd[1023];
}

__global__ __launch_bounds__(64) void scan2_kernel(int* __restrict__ bsum, int nb)
{
  int lane = threadIdx.x;
  int v = (lane < nb) ? bsum[lane] : 0;
  int incl = v;
  for (int off = 1; off < 64; off <<= 1) {
    int t = __shfl_up(incl, off);
    if (lane >= off) incl += t;
  }
  if (lane < nb) bsum[lane] = incl - v;   // exclusive
}

__global__ void scan3_kernel(int* __restrict__ rowptr, const int* __restrict__ bsum,
                             int N, int EN)
{
  int i = blockIdx.x * 256 + threadIdx.x;
  if (i < N) rowptr[i] += bsum[i >> 10];
  if (i == 0) rowptr[N] = EN;
}

__global__ void scatter_kernel(const int* __restrict__ ei, const int* __restrict__ rowptr,
                               int* __restrict__ cursor, int* __restrict__ csr_src,
                               int E, int N)
{
  int i = blockIdx.x * 256 + threadIdx.x;
  if (i >= E + N) return;
  int src, dst;
  if (i < E) { src = ei[i]; dst = ei[E + i]; }
  else { src = i - E; dst = i - E; }
  int pos = rowptr[dst] + atomicAdd(&cursor[dst], 1);
  csr_src[pos] = src;
}

// ---------------------------------------------------------------------------
// GAT aggregation v3: ONE WAVE PER DST, 4 dst per block, no LDS, no barriers.
// Lane = (el, hh): el = lane>>3 edge slot, hh = lane&7 head.
// Softmax over shfl_xor reductions (el strides preserve hh classes).
// Aggregation: lane covers channels c = 2*lane, 2*lane+1; h gathered as bf16.
// ---------------------------------------------------------------------------
__global__ __launch_bounds__(256) void gat_agg3(
    const unsigned short* __restrict__ hb, const int* __restrict__ rowptr,
    const int* __restrict__ csr_src, const float* __restrict__ aS,
    const float* __restrict__ aD, unsigned short* __restrict__ agg, int N)
{
  const int wid = threadIdx.x >> 6;
  const int lane = threadIdx.x & 63;
  const int dst = blockIdx.x * 4 + wid;
  if (dst >= N) return;
  const int el = lane >> 3, hh = lane & 7;
  const int start = rowptr[dst];
  const int deg = rowptr[dst + 1] - start;
  const float adh = aD[(size_t)dst * 8 + hh];

  // pass 1: per-(edge,head) scores, cached; per-head max via xor reduce
  int src_c[MAXI]; float v_c[MAXI];
  float m = -1e30f;
#pragma unroll
  for (int i = 0; i < MAXI; ++i) {
    int e = i * 8 + el;
    int s = 0; float v = -1e30f;
    if (e < deg) {
      s = csr_src[start + e];
      v = aS[(size_t)s * 8 + hh] + adh;
      v = (v > 0.f) ? v : 0.2f * v;
    }
    src_c[i] = s; v_c[i] = v;
    m = fmaxf(m, v);
  }
  for (int e0 = MAXI * 8; e0 < deg; e0 += 8) {
    int e = e0 + el;
    if (e < deg) {
      int s = csr_src[start + e];
      float v = aS[(size_t)s * 8 + hh] + adh;
      v = (v > 0.f) ? v : 0.2f * v;
      m = fmaxf(m, v);
    }
  }
  m = fmaxf(m, __shfl_xor(m, 8));
  m = fmaxf(m, __shfl_xor(m, 16));
  m = fmaxf(m, __shfl_xor(m, 32));

  // pass 2: p, denom, weighted bf16 gather
  const int c2 = lane * 2;
  float dsum = 0.f;
  float accx[8], accy[8];
#pragma unroll
  for (int q = 0; q < 8; ++q) { accx[q] = 0.f; accy[q] = 0.f; }

#pragma unroll
  for (int i = 0; i < MAXI; ++i) {
    if (i * 8 >= deg) break;                      // wave-uniform
    int e = i * 8 + el;
    float p = (e < deg) ? __expf(v_c[i] - m) : 0.f;
    dsum += p;
    int cnt = deg - i * 8; if (cnt > 8) cnt = 8;
#pragma unroll
    for (int ee = 0; ee < 8; ++ee) {
      if (ee >= cnt) break;                       // wave-uniform
      int se = __shfl(src_c[i], ee * 8);
      unsigned hv = *(const unsigned*)&hb[(size_t)se * 128 + c2];
      float hx = bf2f((unsigned short)hv);
      float hy = bf2f((unsigned short)(hv >> 16));
#pragma unroll
      for (int q = 0; q < 8; ++q) {
        float pq = __shfl(p, ee * 8 + q);
        accx[q] = fmaf(pq, hx, accx[q]);
        accy[q] = fmaf(pq, hy, accy[q]);
      }
    }
  }
  for (int e0 = MAXI * 8; e0 < deg; e0 += 8) {    // overflow path (deg > 48)
    int e = e0 + el;
    float p = 0.f; int s = 0;
    if (e < deg) {
      s = csr_src[start + e];
      float v = aS[(size_t)s * 8 + hh] + adh;
      v = (v > 0.f) ? v : 0.2f * v;
      p = __expf(v - m);
    }
    dsum += p;
    int cnt = deg - e0; if (cnt > 8) cnt = 8;
    for (int ee = 0; ee < cnt; ++ee) {
      int se = __shfl(s, ee * 8);
      unsigned hv = *(const unsigned*)&hb[(size_t)se * 128 + c2];
      float hx = bf2f((unsigned short)hv);
      float hy = bf2f((unsigned short)(hv >> 16));
#pragma unroll
      for (int q = 0; q < 8; ++q) {
        float pq = __shfl(p, ee * 8 + q);
        accx[q] = fmaf(pq, hx, accx[q]);
        accy[q] = fmaf(pq, hy, accy[q]);
      }
    }
  }

  dsum += __shfl_xor(dsum, 8);
  dsum += __shfl_xor(dsum, 16);
  dsum += __shfl_xor(dsum, 32);
  float inv = 1.f / (dsum + 1e-16f);

#pragma unroll
  for (int q = 0; q < 8; ++q) {
    float invq = __shfl(inv, q);                  // lane q holds hh=q denom
    float ax = accx[q] * invq, ay = accy[q] * invq;
    unsigned pk = ((unsigned)(unsigned short)f2bf(ay) << 16) |
                  (unsigned)(unsigned short)f2bf(ax);
    *(unsigned*)&agg[(size_t)dst * 1024 + q * 128 + c2] = pk;
  }
}

// ---------------------------------------------------------------------------
// Fused GRU: gi = h@W_ih^T+b_ih, gh = mem@W_hh^T+b_hh, gates r,z,n, h-out.
// Block: 64 rows; wave w handles rows w*16..w*16+15, all 128 cols per gate.
// ---------------------------------------------------------------------------
__global__ __launch_bounds__(256) void gru_fused(
    const float* __restrict__ h, const float* __restrict__ mem,
    const short* __restrict__ BtI, const short* __restrict__ BtH,
    const float* __restrict__ bI, const float* __restrict__ bH,
    float* __restrict__ hout, int M)
{
  __shared__ short Ah[64 * 136];
  __shared__ short Am[64 * 136];
  const int tid = threadIdx.x;
  const int m0 = blockIdx.x * 64;
  const float4* h4 = (const float4*)h;
  const float4* m4 = (const float4*)mem;
#pragma unroll
  for (int it = 0; it < 8; ++it) {
    int idx = tid + it * 256;
    int r = idx >> 5, k4 = idx & 31;
    int row = m0 + r; if (row >= M) row = M - 1;
    float4 a = h4[(size_t)row * 32 + k4];
    ushort4 p;
    p.x = (unsigned short)f2bf(a.x); p.y = (unsigned short)f2bf(a.y);
    p.z = (unsigned short)f2bf(a.z); p.w = (unsigned short)f2bf(a.w);
    *(ushort4*)&Ah[r * 136 + k4 * 4] = p;
    float4 b = m4[(size_t)row * 32 + k4];
    ushort4 q;
    q.x = (unsigned short)f2bf(b.x); q.y = (unsigned short)f2bf(b.y);
    q.z = (unsigned short)f2bf(b.z); q.w = (unsigned short)f2bf(b.w);
    *(ushort4*)&Am[r * 136 + k4 * 4] = q;
  }
  __syncthreads();

  const int wid = tid >> 6, lane = tid & 63;
  const int l15 = lane & 15, quad = lane >> 4;
  const int mb = wid * 16;

  float rs[8][4], zs[8][4];

  for (int g = 0; g < 3; ++g) {
    floatx4 accI[8], accH[8];
#pragma unroll
    for (int nt = 0; nt < 8; ++nt) {
      accI[nt] = (floatx4){0.f, 0.f, 0.f, 0.f};
      accH[nt] = (floatx4){0.f, 0.f, 0.f, 0.f};
    }
#pragma unroll
    for (int kk = 0; kk < 4; ++kk) {
      int ko = kk * 32 + quad * 8;
      short8 ah = *(const short8*)&Ah[(mb + l15) * 136 + ko];
      short8 am = *(const short8*)&Am[(mb + l15) * 136 + ko];
#pragma unroll
      for (int nt = 0; nt < 8; ++nt) {
        int col = g * 128 + nt * 16 + l15;
        short8 bi = *(const short8*)&BtI[(size_t)col * 128 + ko];
        short8 bh = *(const short8*)&BtH[(size_t)col * 128 + ko];
        accI[nt] = __builtin_amdgcn_mfma_f32_16x16x32_bf16(ah, bi, accI[nt], 0, 0, 0);
        accH[nt] = __builtin_amdgcn_mfma_f32_16x16x32_bf16(am, bh, accH[nt], 0, 0, 0);
      }
    }
#pragma unroll
    for (int nt = 0; nt < 8; ++nt) {
      int col = nt * 16 + l15;
      int col3 = g * 128 + col;
      float bvi = bI[col3], bvh = bH[col3];
#pragma unroll
      for (int r = 0; r < 4; ++r) {
        if (g == 0) {
          float v = accI[nt][r] + accH[nt][r] + bvi + bvh;
          rs[nt][r] = 1.f / (1.f + __expf(-v));
        } else if (g == 1) {
          float v = accI[nt][r] + accH[nt][r] + bvi + bvh;
          zs[nt][r] = 1.f / (1.f + __expf(-v));
        } else {
          int rowg = m0 + mb + quad * 4 + r;
          if (rowg < M) {
            float gin = accI[nt][r] + bvi;
            float ghn = accH[nt][r] + bvh;
            float nc = tanhf(gin + rs[nt][r] * ghn);
            float z = zs[nt][r];
            float mv = mem[(size_t)rowg * 128 + col];
            hout[(size_t)rowg * 128 + col] = (1.f - z) * nc + z * mv;
          }
        }
      }
    }
  }
}

// ---------------------------------------------------------------------------
// global_mean_pool
// ---------------------------------------------------------------------------
__global__ __launch_bounds__(128) void pool_kernel(
    const float* __restrict__ h, const int* __restrict__ batch,
    float* __restrict__ pooled_sums, float* __restrict__ cnt, int N)
{
  int n0 = blockIdx.x * 128;
  int c = threadIdx.x;
  int end = n0 + 128; if (end > N) end = N;
  if (n0 >= N) return;
  int cur = batch[n0];
  float acc = 0.f; float count = 0.f;
  for (int n = n0; n < end; ++n) {
    int b = batch[n];
    if (b != cur) {
      atomicAdd(&pooled_sums[(size_t)cur * HIDC + c], acc);
      if (c == 0) atomicAdd(&cnt[cur], count);
      acc = 0.f; count = 0.f; cur = b;
    }
    acc += h[(size_t)n * HIDC + c];
    count += 1.f;
  }
  atomicAdd(&pooled_sums[(size_t)cur * HIDC + c], acc);
  if (c == 0) atomicAdd(&cnt[cur], count);
}

// ---------------------------------------------------------------------------
// finalize pooled, classifier MLP, softmax
// ---------------------------------------------------------------------------
__global__ __launch_bounds__(64) void classifier_kernel(
    float* __restrict__ pooled, const float* __restrict__ cnt,
    const float* __restrict__ c1W, const float* __restrict__ c1b,
    const float* __restrict__ c2W, const float* __restrict__ c2b,
    float* __restrict__ logits, float* __restrict__ preds)
{
  int g = blockIdx.x, j = threadIdx.x;
  __shared__ float sp[128];
  __shared__ float hid[64];
  __shared__ float lg[3];
  float invc = 1.f / fmaxf(cnt[g], 1.f);
  float p0 = pooled[(size_t)g * 128 + j] * invc;
  float p1 = pooled[(size_t)g * 128 + 64 + j] * invc;
  pooled[(size_t)g * 128 + j] = p0;
  pooled[(size_t)g * 128 + 64 + j] = p1;
  sp[j] = p0; sp[j + 64] = p1;
  __syncthreads();
  float a = c1b[j];
#pragma unroll
  for (int k = 0; k < 128; ++k) a = fmaf(sp[k], c1W[k * 64 + j], a);
  hid[j] = fmaxf(a, 0.f);
  __syncthreads();
  if (j < NCLS) {
    float t = c2b[j];
#pragma unroll
    for (int k = 0; k < 64; ++k) t = fmaf(hid[k], c2W[k * NCLS + j], t);
    logits[(size_t)g * NCLS + j] = t;
    lg[j] = t;
  }
  __syncthreads();
  if (j < NCLS) {
    float mx = fmaxf(lg[0], fmaxf(lg[1], lg[2]));
    float e0 = __expf(lg[0] - mx), e1 = __expf(lg[1] - mx), e2 = __expf(lg[2] - mx);
    float mine = (j == 0) ? e0 : ((j == 1) ? e1 : e2);
    preds[(size_t)g * NCLS + j] = mine / (e0 + e1 + e2);
  }
}

// ---------------------------------------------------------------------------
extern "C" void kernel_launch(void* const* d_in, const int* in_sizes, int n_in,
                              void* d_out, int out_size, void* d_ws, size_t ws_size,
                              hipStream_t stream)
{
  const float* x       = (const float*)d_in[0];
  const int*   ei      = (const int*)d_in[1];
  const int*   batch   = (const int*)d_in[2];
  const float* memory  = (const float*)d_in[3];
  const float* enc_W   = (const float*)d_in[4];
  const float* enc_b   = (const float*)d_in[5];
  const float* gat_W   = (const float*)d_in[6];   // [NL,128,1024]
  const float* att_src = (const float*)d_in[7];
  const float* att_dst = (const float*)d_in[8];
  const float* gat_b   = (const float*)d_in[9];
  const float* W_ih    = (const float*)d_in[10];
  const float* W_hh    = (const float*)d_in[11];
  const float* b_ih    = (const float*)d_in[12];
  const float* b_hh    = (const float*)d_in[13];
  const float* c1W     = (const float*)d_in[14];
  const float* c1b     = (const float*)d_in[15];
  const float* c2W     = (const float*)d_in[16];
  const float* c2b     = (const float*)d_in[17];

  const int N = in_sizes[0] / HIDC;
  const int E = in_sizes[1] / 2;
  const int EN = E + N;
  const int NB = (N + 1023) / 1024;

  char* ws = (char*)d_ws;
  size_t off = 0;
  auto alloc = [&](size_t bytes) -> void* {
    void* p = ws + off;
    off += (bytes + 255) & ~(size_t)255;
    return p;
  };
  float* h0     = (float*)alloc((size_t)N * HIDC * 4);
  float* h1     = (float*)alloc((size_t)N * HIDC * 4);
  unsigned short* hb0 = (unsigned short*)alloc((size_t)N * HIDC * 2);
  unsigned short* hb1 = (unsigned short*)alloc((size_t)N * HIDC * 2);
  unsigned short* agg = (unsigned short*)alloc((size_t)N * 1024 * 2);
  float* aS     = (float*)alloc((size_t)N * NHEAD * 4);
  float* aD     = (float*)alloc((size_t)N * NHEAD * 4);
  short* encT   = (short*)alloc((size_t)128 * 128 * 2);
  short* Wp     = (short*)alloc((size_t)NLAY * 131072 * 2);
  float* waSD   = (float*)alloc((size_t)NLAY * 2048 * 4);
  short* ihT    = (short*)alloc((size_t)384 * 128 * 2);
  short* hhT    = (short*)alloc((size_t)384 * 128 * 2);
  int*   rowptr = (int*)alloc((size_t)(N + 1) * 4);
  int*   cursor = (int*)alloc((size_t)N * 4);
  int*   degtmp = (int*)alloc((size_t)N * 4);
  int*   bsum   = (int*)alloc(64 * 4);
  int*   csr    = (int*)alloc((size_t)EN * 4);
  float* cntbuf = (float*)alloc(64 * 4);

  float* out_logits = (float*)d_out;
  float* out_pooled = (float*)d_out + NGRAPH * NCLS;
  float* out_preds  = (float*)d_out + NGRAPH * NCLS + NGRAPH * HIDC;

  hipMemsetAsync(d_out, 0, (size_t)out_size * 4, stream);
  hipMemsetAsync(cntbuf, 0, 64 * 4, stream);
  hipMemsetAsync(cursor, 0, (size_t)N * 4, stream);
  hipMemsetAsync(degtmp, 0, (size_t)N * 4, stream);

  // CSR build
  hist_kernel<<<(EN + 255) / 256, 256, 0, stream>>>(ei, degtmp, E, N);
  scan1_kernel<<<NB, 1024, 0, stream>>>(degtmp, rowptr, bsum, N);
  scan2_kernel<<<1, 64, 0, stream>>>(bsum, NB);
  scan3_kernel<<<(N + 255) / 256, 256, 0, stream>>>(rowptr, bsum, N, EN);
  scatter_kernel<<<(EN + 255) / 256, 256, 0, stream>>>(ei, rowptr, cursor, csr, E, N);

  // weight prep
  convt_kernel<<<(128 * 128 + 255) / 256, 256, 0, stream>>>(enc_W, encT, 128, 128);
  rearr_kernel<<<(NLAY * 131072 + 255) / 256, 256, 0, stream>>>(gat_W, Wp);
  {
    dim3 g(NLAY, 8);
    wa_kernel<<<g, 256, 0, stream>>>(gat_W, att_src, att_dst, waSD);
  }
  conv_kernel<<<(384 * 128 + 255) / 256, 256, 0, stream>>>(W_ih, ihT, 384 * 128);
  conv_kernel<<<(384 * 128 + 255) / 256, 256, 0, stream>>>(W_hh, hhT, 384 * 128);

  // encoder: h0 = relu(x @ enc_W + enc_b), fp32 + bf16 mirror
  {
    dim3 g((N + 63) / 64, 2);
    mm_bf16<<<g, 256, 0, stream>>>(x, encT, enc_b, h0, hb0, N, HIDC, 1);
  }

  float* hcur = h0;  unsigned short* hbcur = hb0;
  float* hnxt = h1;  unsigned short* hbnxt = hb1;
  for (int l = 0; l < NLAY; ++l) {
    alpha2_kernel<<<(N + 15) / 16, 256, 0, stream>>>(
        hcur, waSD + (size_t)l * 2048, aS, aD, N);
    gat_agg3<<<(N + 3) / 4, 256, 0, stream>>>(hbcur, rowptr, csr, aS, aD, agg, N);
    dim3 g((N + 63) / 64, 1);
    mm_bf16A<<<g, 256, 0, stream>>>(agg, Wp + (size_t)l * 131072,
                                    gat_b + (size_t)l * HIDC, hnxt,
                                    (l < NLAY - 1) ? hbnxt : (unsigned short*)nullptr,
                                    N, HIDC, 1024, (l < NLAY - 1) ? 1 : 0);
    float* t = hcur; hcur = hnxt; hnxt = t;
    unsigned short* tb = hbcur; hbcur = hbnxt; hbnxt = tb;
  }

  // fused GRU: hnxt = GRU(hcur, memory)
  gru_fused<<<(N + 63) / 64, 256, 0, stream>>>(hcur, memory, ihT, hhT, b_ih, b_hh,
                                               hnxt, N);

  // pooling + classifier
  pool_kernel<<<(N + 127) / 128, 128, 0, stream>>>(hnxt, batch, out_pooled, cntbuf, N);
  classifier_kernel<<<NGRAPH, 64, 0, stream>>>(out_pooled, cntbuf, c1W, c1b, c2W, c2b,
                                               out_logits, out_preds);
}

// Round 5
// 931.813 us; speedup vs baseline: 3.1909x; 1.0522x over previous
//
#include <hip/hip_runtime.h>
#include <cstdint>
#include <cstddef>

#define HIDC 128
#define NHEAD 8
#define NLAY 3
#define NGRAPH 64
#define NCLS 3
#define MAXI 6   // cached edge-groups per lane: fast path deg <= 48

typedef __attribute__((ext_vector_type(8))) short short8;
typedef __attribute__((ext_vector_type(4))) float floatx4;

__device__ inline short f2bf(float x) {
  unsigned u = __float_as_uint(x);
  unsigned r = (u + 0x7fff + ((u >> 16) & 1)) >> 16;   // RNE
  return (short)r;
}
__device__ inline float bf2f(unsigned short u) {
  return __uint_as_float(((unsigned)u) << 16);
}

// ---------------------------------------------------------------------------
// Weight prep
// ---------------------------------------------------------------------------
__global__ void convt_kernel(const float* __restrict__ W, short* __restrict__ Wt,
                             int K, int Nc)
{
  int i = blockIdx.x * 256 + threadIdx.x;
  if (i >= K * Nc) return;
  int k = i / Nc, n = i - k * Nc;
  Wt[(size_t)n * K + k] = f2bf(W[i]);
}

__global__ void conv_kernel(const float* __restrict__ W, short* __restrict__ Wt,
                            int count)
{
  int i = blockIdx.x * 256 + threadIdx.x;
  if (i >= count) return;
  Wt[i] = f2bf(W[i]);
}

// Wp[l][c][h*128+k] = gat_W[l][k][h*128+c] / 8   (head-mean folded in)
__global__ void rearr_kernel(const float* __restrict__ gat_W, short* __restrict__ Wp)
{
  int i = blockIdx.x * 256 + threadIdx.x;
  if (i >= NLAY * 131072) return;
  int l = i >> 17, rem = i & 131071;
  int k = rem >> 10, hc = rem & 1023;
  int hh = hc >> 7, cc = hc & 127;
  Wp[(size_t)l * 131072 + (size_t)cc * 1024 + hh * 128 + k] = f2bf(gat_W[i] * 0.125f);
}

// waSD[l][k][j16]: j16<8 -> W_h a_src_h projection, j16>=8 -> a_dst
__global__ __launch_bounds__(256) void wa_kernel(
    const float* __restrict__ gat_W, const float* __restrict__ att_src,
    const float* __restrict__ att_dst, float* __restrict__ waSD)
{
  int l = blockIdx.x;
  int idx = blockIdx.y * 256 + threadIdx.x;
  int k = idx >> 4, j16 = idx & 15;
  int hh = j16 & 7;
  const float* a = ((j16 < 8) ? att_src : att_dst) + (size_t)l * 1024 + hh * 128;
  const float* w = gat_W + (size_t)l * 131072 + (size_t)k * 1024 + hh * 128;
  float s = 0.f;
  for (int cc = 0; cc < 128; ++cc) s += w[cc] * a[cc];
  waSD[(size_t)l * 2048 + idx] = s;
}

// Bt512[col][k] for fused GRU matmul over A=[h_bf16 | mem_bf16] (K=256):
// cols 0..255: r,z combined (W_ih k<128, W_hh k>=128); 256..383: gi_n; 384..511: gh_n
__global__ void build_gru_B(const float* __restrict__ W_ih,
                            const float* __restrict__ W_hh,
                            short* __restrict__ Bt512)
{
  int i = blockIdx.x * 256 + threadIdx.x;
  if (i >= 512 * 256) return;
  int col = i >> 8, k = i & 255;
  float v;
  if (k < 128) {
    if (col < 384) v = W_ih[(size_t)col * 128 + k];          // r,z rows 0..255; gi_n rows 256..383
    else v = 0.f;
  } else {
    int k2 = k - 128;
    if (col < 256) v = W_hh[(size_t)col * 128 + k2];         // r,z
    else if (col < 384) v = 0.f;
    else v = W_hh[(size_t)(col - 128) * 128 + k2];           // gh_n rows 256..383
  }
  Bt512[i] = f2bf(v);
}

// ---------------------------------------------------------------------------
// C[M,Nc] = act(A_fp32[M,128] @ B + bias), Bt[Nc][128] bf16. 64x64 tile.
// Writes fp32 C and optional bf16 mirror Cb2.
// ---------------------------------------------------------------------------
__global__ __launch_bounds__(256) void mm_bf16(
    const float* __restrict__ A, const short* __restrict__ Bt,
    const float* __restrict__ bias, float* __restrict__ Cf,
    unsigned short* __restrict__ Cb2, int M, int Nc, int relu)
{
  __shared__ short Asl[64 * 136];
  const int tid = threadIdx.x;
  const int m0 = blockIdx.x * 64;
  const int n0 = blockIdx.y * 64;

  const float4* A4 = (const float4*)A;
#pragma unroll
  for (int it = 0; it < 8; ++it) {
    int idx = tid + it * 256;
    int r = idx >> 5, k4 = idx & 31;
    int row = m0 + r; if (row >= M) row = M - 1;
    float4 a = A4[(size_t)row * 32 + k4];
    ushort4 p;
    p.x = (unsigned short)f2bf(a.x); p.y = (unsigned short)f2bf(a.y);
    p.z = (unsigned short)f2bf(a.z); p.w = (unsigned short)f2bf(a.w);
    *(ushort4*)&Asl[r * 136 + k4 * 4] = p;
  }
  __syncthreads();

  const int wid = tid >> 6, lane = tid & 63;
  const int l15 = lane & 15, quad = lane >> 4;
  const int wm = wid & 1, wn = wid >> 1;
  const int mb = wm * 32;
  const int nb = n0 + wn * 32;

  floatx4 acc00 = {0.f, 0.f, 0.f, 0.f};
  floatx4 acc01 = acc00, acc10 = acc00, acc11 = acc00;

#pragma unroll
  for (int kk = 0; kk < 4; ++kk) {
    int k = kk * 32 + quad * 8;
    short8 a0 = *(const short8*)&Asl[(mb + l15) * 136 + k];
    short8 a1 = *(const short8*)&Asl[(mb + 16 + l15) * 136 + k];
    short8 b0 = *(const short8*)&Bt[(size_t)(nb + l15) * 128 + k];
    short8 b1 = *(const short8*)&Bt[(size_t)(nb + 16 + l15) * 128 + k];
    acc00 = __builtin_amdgcn_mfma_f32_16x16x32_bf16(a0, b0, acc00, 0, 0, 0);
    acc01 = __builtin_amdgcn_mfma_f32_16x16x32_bf16(a0, b1, acc01, 0, 0, 0);
    acc10 = __builtin_amdgcn_mfma_f32_16x16x32_bf16(a1, b0, acc10, 0, 0, 0);
    acc11 = __builtin_amdgcn_mfma_f32_16x16x32_bf16(a1, b1, acc11, 0, 0, 0);
  }

#pragma unroll
  for (int mt = 0; mt < 2; ++mt) {
#pragma unroll
    for (int nt = 0; nt < 2; ++nt) {
      floatx4 acc = (mt == 0) ? (nt == 0 ? acc00 : acc01)
                              : (nt == 0 ? acc10 : acc11);
      int colg = nb + nt * 16 + l15;
      float bv = bias ? bias[colg] : 0.f;
#pragma unroll
      for (int r = 0; r < 4; ++r) {
        int rowg = m0 + mb + mt * 16 + quad * 4 + r;
        if (rowg < M && colg < Nc) {
          float v = acc[r] + bv;
          if (relu) v = fmaxf(v, 0.f);
          Cf[(size_t)rowg * Nc + colg] = v;
          if (Cb2) Cb2[(size_t)rowg * Nc + colg] = (unsigned short)f2bf(v);
        }
      }
    }
  }
}

// ---------------------------------------------------------------------------
// C[M,128] = act(A_bf16[M,K] @ B + bias), Bt[128][K] bf16, K mult of 64.
// fp32 out + optional bf16 mirror.
// ---------------------------------------------------------------------------
__global__ __launch_bounds__(256) void mm_bf16A(
    const unsigned short* __restrict__ A, const short* __restrict__ Bt,
    const float* __restrict__ bias, float* __restrict__ Cf,
    unsigned short* __restrict__ Cb2, int M, int Nc, int K, int relu)
{
  __shared__ short As[64 * 72];
  const int tid = threadIdx.x;
  const int m0 = blockIdx.x * 64;
  const int n0 = blockIdx.y * 128;
  const int wid = tid >> 6, lane = tid & 63;
  const int l15 = lane & 15, quad = lane >> 4;
  const int wm = wid & 1, wn = wid >> 1;
  const int mb = wm * 32;
  const int nb = n0 + wn * 64;

  floatx4 acc[2][4];
#pragma unroll
  for (int a = 0; a < 2; ++a)
#pragma unroll
    for (int g = 0; g < 4; ++g) acc[a][g] = (floatx4){0.f, 0.f, 0.f, 0.f};

  for (int kb = 0; kb < K; kb += 64) {
    __syncthreads();
#pragma unroll
    for (int it = 0; it < 2; ++it) {
      int idx = tid + it * 256;
      int r = idx >> 3, k8 = (idx & 7) * 8;
      int row = m0 + r; if (row >= M) row = M - 1;
      *(short8*)&As[r * 72 + k8] = *(const short8*)&A[(size_t)row * K + kb + k8];
    }
    __syncthreads();
#pragma unroll
    for (int kk = 0; kk < 2; ++kk) {
      int ko = kk * 32 + quad * 8;
      short8 a0 = *(const short8*)&As[(mb + l15) * 72 + ko];
      short8 a1 = *(const short8*)&As[(mb + 16 + l15) * 72 + ko];
#pragma unroll
      for (int g = 0; g < 4; ++g) {
        int col = nb + g * 16 + l15; if (col >= Nc) col = Nc - 1;
        short8 b = *(const short8*)&Bt[(size_t)col * K + kb + ko];
        acc[0][g] = __builtin_amdgcn_mfma_f32_16x16x32_bf16(a0, b, acc[0][g], 0, 0, 0);
        acc[1][g] = __builtin_amdgcn_mfma_f32_16x16x32_bf16(a1, b, acc[1][g], 0, 0, 0);
      }
    }
  }

#pragma unroll
  for (int mt = 0; mt < 2; ++mt) {
#pragma unroll
    for (int g = 0; g < 4; ++g) {
      int colg = nb + g * 16 + l15;
      if (colg >= Nc) continue;
      float bv = bias ? bias[colg] : 0.f;
#pragma unroll
      for (int r = 0; r < 4; ++r) {
        int rowg = m0 + mb + mt * 16 + quad * 4 + r;
        if (rowg < M) {
          float v = acc[mt][g][r] + bv;
          if (relu) v = fmaxf(v, 0.f);
          Cf[(size_t)rowg * Nc + colg] = v;
          if (Cb2) Cb2[(size_t)rowg * Nc + colg] = (unsigned short)f2bf(v);
        }
      }
    }
  }
}

// ---------------------------------------------------------------------------
// GRU matmul: S[M,512] = [hb | memb] @ Bt512^T, all bf16, K=256. Out bf16.
// Same structure as mm_bf16A with dual A source.
// ---------------------------------------------------------------------------
__global__ __launch_bounds__(256) void gru_mm(
    const unsigned short* __restrict__ hb, const unsigned short* __restrict__ memb,
    const short* __restrict__ Bt512, unsigned short* __restrict__ S, int M)
{
  __shared__ short As[64 * 72];
  const int tid = threadIdx.x;
  const int m0 = blockIdx.x * 64;
  const int n0 = blockIdx.y * 128;
  const int wid = tid >> 6, lane = tid & 63;
  const int l15 = lane & 15, quad = lane >> 4;
  const int wm = wid & 1, wn = wid >> 1;
  const int mb = wm * 32;
  const int nb = n0 + wn * 64;

  floatx4 acc[2][4];
#pragma unroll
  for (int a = 0; a < 2; ++a)
#pragma unroll
    for (int g = 0; g < 4; ++g) acc[a][g] = (floatx4){0.f, 0.f, 0.f, 0.f};

  for (int kb = 0; kb < 256; kb += 64) {
    const unsigned short* Asrc = (kb < 128) ? hb : memb;
    int kloc = (kb < 128) ? kb : kb - 128;
    __syncthreads();
#pragma unroll
    for (int it = 0; it < 2; ++it) {
      int idx = tid + it * 256;
      int r = idx >> 3, k8 = (idx & 7) * 8;
      int row = m0 + r; if (row >= M) row = M - 1;
      *(short8*)&As[r * 72 + k8] = *(const short8*)&Asrc[(size_t)row * 128 + kloc + k8];
    }
    __syncthreads();
#pragma unroll
    for (int kk = 0; kk < 2; ++kk) {
      int ko = kk * 32 + quad * 8;
      short8 a0 = *(const short8*)&As[(mb + l15) * 72 + ko];
      short8 a1 = *(const short8*)&As[(mb + 16 + l15) * 72 + ko];
#pragma unroll
      for (int g = 0; g < 4; ++g) {
        int col = nb + g * 16 + l15;
        short8 b = *(const short8*)&Bt512[(size_t)col * 256 + kb + ko];
        acc[0][g] = __builtin_amdgcn_mfma_f32_16x16x32_bf16(a0, b, acc[0][g], 0, 0, 0);
        acc[1][g] = __builtin_amdgcn_mfma_f32_16x16x32_bf16(a1, b, acc[1][g], 0, 0, 0);
      }
    }
  }

#pragma unroll
  for (int mt = 0; mt < 2; ++mt) {
#pragma unroll
    for (int g = 0; g < 4; ++g) {
      int colg = nb + g * 16 + l15;
#pragma unroll
      for (int r = 0; r < 4; ++r) {
        int rowg = m0 + mb + mt * 16 + quad * 4 + r;
        if (rowg < M)
          S[(size_t)rowg * 512 + colg] = (unsigned short)f2bf(acc[mt][g][r]);
      }
    }
  }
}

// ---------------------------------------------------------------------------
// GRU gates from fused S (bf16): r=sig(S0+bi+bh), z=sig(S1+..), n=tanh(gin+r*ghn)
// ---------------------------------------------------------------------------
__global__ __launch_bounds__(256) void gru_gate2(
    const unsigned short* __restrict__ S, const float* __restrict__ mem,
    const float* __restrict__ bI, const float* __restrict__ bH,
    float* __restrict__ hout, int N)
{
  int idx = blockIdx.x * 256 + threadIdx.x;
  if (idx >= N * HIDC) return;
  int n = idx >> 7, c = idx & 127;
  size_t b = (size_t)n * 512;
  float sr  = bf2f(S[b + c])       + bI[c]       + bH[c];
  float sz  = bf2f(S[b + 128 + c]) + bI[128 + c] + bH[128 + c];
  float gin = bf2f(S[b + 256 + c]) + bI[256 + c];
  float ghn = bf2f(S[b + 384 + c]) + bH[256 + c];
  float rg = 1.f / (1.f + __expf(-sr));
  float zg = 1.f / (1.f + __expf(-sz));
  float nc = tanhf(gin + rg * ghn);
  hout[idx] = (1.f - zg) * nc + zg * mem[idx];
}

// ---------------------------------------------------------------------------
// alphas via precomputed projection: aS/aD[n][h] = h[n,:] . waSD[:,j16]
// ---------------------------------------------------------------------------
__global__ __launch_bounds__(256) void alpha2_kernel(
    const float* __restrict__ h, const float* __restrict__ waSD,
    float* __restrict__ aS, float* __restrict__ aD, int N)
{
  __shared__ float s_wa[2048];
  const int tid = threadIdx.x;
  for (int i = tid; i < 2048; i += 256) s_wa[i] = waSD[i];
  __syncthreads();
  int node = blockIdx.x * 16 + (tid >> 4);
  int j = tid & 15;
  if (node >= N) return;
  const float4* h4 = (const float4*)(h + (size_t)node * 128);
  float s = 0.f;
#pragma unroll
  for (int k4 = 0; k4 < 32; ++k4) {
    float4 v = h4[k4];
    s += v.x * s_wa[(k4 * 4 + 0) * 16 + j];
    s += v.y * s_wa[(k4 * 4 + 1) * 16 + j];
    s += v.z * s_wa[(k4 * 4 + 2) * 16 + j];
    s += v.w * s_wa[(k4 * 4 + 3) * 16 + j];
  }
  if (j < 8) aS[(size_t)node * 8 + j] = s;
  else       aD[(size_t)node * 8 + (j - 8)] = s;
}

// ---------------------------------------------------------------------------
// CSR build: histogram, 3-stage scan, scatter
// ---------------------------------------------------------------------------
__global__ void hist_kernel(const int* __restrict__ ei, int* __restrict__ deg, int E, int N)
{
  int i = blockIdx.x * 256 + threadIdx.x;
  if (i >= E + N) return;
  int dst = (i < E) ? ei[E + i] : (i - E);
  atomicAdd(&deg[dst], 1);
}

__global__ __launch_bounds__(1024) void scan1_kernel(
    const int* __restrict__ deg, int* __restrict__ rowptr,
    int* __restrict__ bsum, int N)
{
  __shared__ int sd[1024];
  int i = blockIdx.x * 1024 + threadIdx.x;
  int v = (i < N) ? deg[i] : 0;
  sd[threadIdx.x] = v;
  __syncthreads();
  for (int off = 1; off < 1024; off <<= 1) {
    int t = (threadIdx.x >= off) ? sd[threadIdx.x - off] : 0;
    __syncthreads();
    sd[threadIdx.x] += t;
    __syncthreads();
  }
  if (i < N) rowptr[i] = sd[threadIdx.x] - v;
  if (threadIdx.x == 1023) bsum[blockIdx.x] = sd[1023];
}

__global__ __launch_bounds__(64) void scan2_kernel(int* __restrict__ bsum, int nb)
{
  int lane = threadIdx.x;
  int v = (lane < nb) ? bsum[lane] : 0;
  int incl = v;
  for (int off = 1; off < 64; off <<= 1) {
    int t = __shfl_up(incl, off);
    if (lane >= off) incl += t;
  }
  if (lane < nb) bsum[lane] = incl - v;   // exclusive
}

__global__ void scan3_kernel(int* __restrict__ rowptr, const int* __restrict__ bsum,
                             int N, int EN)
{
  int i = blockIdx.x * 256 + threadIdx.x;
  if (i < N) rowptr[i] += bsum[i >> 10];
  if (i == 0) rowptr[N] = EN;
}

__global__ void scatter_kernel(const int* __restrict__ ei, const int* __restrict__ rowptr,
                               int* __restrict__ cursor, int* __restrict__ csr_src,
                               int E, int N)
{
  int i = blockIdx.x * 256 + threadIdx.x;
  if (i >= E + N) return;
  int src, dst;
  if (i < E) { src = ei[i]; dst = ei[E + i]; }
  else { src = i - E; dst = i - E; }
  int pos = rowptr[dst] + atomicAdd(&cursor[dst], 1);
  csr_src[pos] = src;
}

// ---------------------------------------------------------------------------
// GAT aggregation v3: ONE WAVE PER DST, 4 dst per block, no LDS, no barriers.
// ---------------------------------------------------------------------------
__global__ __launch_bounds__(256) void gat_agg3(
    const unsigned short* __restrict__ hb, const int* __restrict__ rowptr,
    const int* __restrict__ csr_src, const float* __restrict__ aS,
    const float* __restrict__ aD, unsigned short* __restrict__ agg, int N)
{
  const int wid = threadIdx.x >> 6;
  const int lane = threadIdx.x & 63;
  const int dst = blockIdx.x * 4 + wid;
  if (dst >= N) return;
  const int el = lane >> 3, hh = lane & 7;
  const int start = rowptr[dst];
  const int deg = rowptr[dst + 1] - start;
  const float adh = aD[(size_t)dst * 8 + hh];

  int src_c[MAXI]; float v_c[MAXI];
  float m = -1e30f;
#pragma unroll
  for (int i = 0; i < MAXI; ++i) {
    int e = i * 8 + el;
    int s = 0; float v = -1e30f;
    if (e < deg) {
      s = csr_src[start + e];
      v = aS[(size_t)s * 8 + hh] + adh;
      v = (v > 0.f) ? v : 0.2f * v;
    }
    src_c[i] = s; v_c[i] = v;
    m = fmaxf(m, v);
  }
  for (int e0 = MAXI * 8; e0 < deg; e0 += 8) {
    int e = e0 + el;
    if (e < deg) {
      int s = csr_src[start + e];
      float v = aS[(size_t)s * 8 + hh] + adh;
      v = (v > 0.f) ? v : 0.2f * v;
      m = fmaxf(m, v);
    }
  }
  m = fmaxf(m, __shfl_xor(m, 8));
  m = fmaxf(m, __shfl_xor(m, 16));
  m = fmaxf(m, __shfl_xor(m, 32));

  const int c2 = lane * 2;
  float dsum = 0.f;
  float accx[8], accy[8];
#pragma unroll
  for (int q = 0; q < 8; ++q) { accx[q] = 0.f; accy[q] = 0.f; }

#pragma unroll
  for (int i = 0; i < MAXI; ++i) {
    if (i * 8 >= deg) break;
    int e = i * 8 + el;
    float p = (e < deg) ? __expf(v_c[i] - m) : 0.f;
    dsum += p;
    int cnt = deg - i * 8; if (cnt > 8) cnt = 8;
#pragma unroll
    for (int ee = 0; ee < 8; ++ee) {
      if (ee >= cnt) break;
      int se = __shfl(src_c[i], ee * 8);
      unsigned hv = *(const unsigned*)&hb[(size_t)se * 128 + c2];
      float hx = bf2f((unsigned short)hv);
      float hy = bf2f((unsigned short)(hv >> 16));
#pragma unroll
      for (int q = 0; q < 8; ++q) {
        float pq = __shfl(p, ee * 8 + q);
        accx[q] = fmaf(pq, hx, accx[q]);
        accy[q] = fmaf(pq, hy, accy[q]);
      }
    }
  }
  for (int e0 = MAXI * 8; e0 < deg; e0 += 8) {
    int e = e0 + el;
    float p = 0.f; int s = 0;
    if (e < deg) {
      s = csr_src[start + e];
      float v = aS[(size_t)s * 8 + hh] + adh;
      v = (v > 0.f) ? v : 0.2f * v;
      p = __expf(v - m);
    }
    dsum += p;
    int cnt = deg - e0; if (cnt > 8) cnt = 8;
    for (int ee = 0; ee < cnt; ++ee) {
      int se = __shfl(s, ee * 8);
      unsigned hv = *(const unsigned*)&hb[(size_t)se * 128 + c2];
      float hx = bf2f((unsigned short)hv);
      float hy = bf2f((unsigned short)(hv >> 16));
#pragma unroll
      for (int q = 0; q < 8; ++q) {
        float pq = __shfl(p, ee * 8 + q);
        accx[q] = fmaf(pq, hx, accx[q]);
        accy[q] = fmaf(pq, hy, accy[q]);
      }
    }
  }

  dsum += __shfl_xor(dsum, 8);
  dsum += __shfl_xor(dsum, 16);
  dsum += __shfl_xor(dsum, 32);
  float inv = 1.f / (dsum + 1e-16f);

#pragma unroll
  for (int q = 0; q < 8; ++q) {
    float invq = __shfl(inv, q);
    float ax = accx[q] * invq, ay = accy[q] * invq;
    unsigned pk = ((unsigned)(unsigned short)f2bf(ay) << 16) |
                  (unsigned)(unsigned short)f2bf(ax);
    *(unsigned*)&agg[(size_t)dst * 1024 + q * 128 + c2] = pk;
  }
}

// ---------------------------------------------------------------------------
// global_mean_pool
// ---------------------------------------------------------------------------
__global__ __launch_bounds__(128) void pool_kernel(
    const float* __restrict__ h, const int* __restrict__ batch,
    float* __restrict__ pooled_sums, float* __restrict__ cnt, int N)
{
  int n0 = blockIdx.x * 128;
  int c = threadIdx.x;
  int end = n0 + 128; if (end > N) end = N;
  if (n0 >= N) return;
  int cur = batch[n0];
  float acc = 0.f; float count = 0.f;
  for (int n = n0; n < end; ++n) {
    int b = batch[n];
    if (b != cur) {
      atomicAdd(&pooled_sums[(size_t)cur * HIDC + c], acc);
      if (c == 0) atomicAdd(&cnt[cur], count);
      acc = 0.f; count = 0.f; cur = b;
    }
    acc += h[(size_t)n * HIDC + c];
    count += 1.f;
  }
  atomicAdd(&pooled_sums[(size_t)cur * HIDC + c], acc);
  if (c == 0) atomicAdd(&cnt[cur], count);
}

// ---------------------------------------------------------------------------
// finalize pooled, classifier MLP, softmax
// ---------------------------------------------------------------------------
__global__ __launch_bounds__(64) void classifier_kernel(
    float* __restrict__ pooled, const float* __restrict__ cnt,
    const float* __restrict__ c1W, const float* __restrict__ c1b,
    const float* __restrict__ c2W, const float* __restrict__ c2b,
    float* __restrict__ logits, float* __restrict__ preds)
{
  int g = blockIdx.x, j = threadIdx.x;
  __shared__ float sp[128];
  __shared__ float hid[64];
  __shared__ float lg[3];
  float invc = 1.f / fmaxf(cnt[g], 1.f);
  float p0 = pooled[(size_t)g * 128 + j] * invc;
  float p1 = pooled[(size_t)g * 128 + 64 + j] * invc;
  pooled[(size_t)g * 128 + j] = p0;
  pooled[(size_t)g * 128 + 64 + j] = p1;
  sp[j] = p0; sp[j + 64] = p1;
  __syncthreads();
  float a = c1b[j];
#pragma unroll
  for (int k = 0; k < 128; ++k) a = fmaf(sp[k], c1W[k * 64 + j], a);
  hid[j] = fmaxf(a, 0.f);
  __syncthreads();
  if (j < NCLS) {
    float t = c2b[j];
#pragma unroll
    for (int k = 0; k < 64; ++k) t = fmaf(hid[k], c2W[k * NCLS + j], t);
    logits[(size_t)g * NCLS + j] = t;
    lg[j] = t;
  }
  __syncthreads();
  if (j < NCLS) {
    float mx = fmaxf(lg[0], fmaxf(lg[1], lg[2]));
    float e0 = __expf(lg[0] - mx), e1 = __expf(lg[1] - mx), e2 = __expf(lg[2] - mx);
    float mine = (j == 0) ? e0 : ((j == 1) ? e1 : e2);
    preds[(size_t)g * NCLS + j] = mine / (e0 + e1 + e2);
  }
}

// ---------------------------------------------------------------------------
extern "C" void kernel_launch(void* const* d_in, const int* in_sizes, int n_in,
                              void* d_out, int out_size, void* d_ws, size_t ws_size,
                              hipStream_t stream)
{
  const float* x       = (const float*)d_in[0];
  const int*   ei      = (const int*)d_in[1];
  const int*   batch   = (const int*)d_in[2];
  const float* memory  = (const float*)d_in[3];
  const float* enc_W   = (const float*)d_in[4];
  const float* enc_b   = (const float*)d_in[5];
  const float* gat_W   = (const float*)d_in[6];   // [NL,128,1024]
  const float* att_src = (const float*)d_in[7];
  const float* att_dst = (const float*)d_in[8];
  const float* gat_b   = (const float*)d_in[9];
  const float* W_ih    = (const float*)d_in[10];
  const float* W_hh    = (const float*)d_in[11];
  const float* b_ih    = (const float*)d_in[12];
  const float* b_hh    = (const float*)d_in[13];
  const float* c1W     = (const float*)d_in[14];
  const float* c1b     = (const float*)d_in[15];
  const float* c2W     = (const float*)d_in[16];
  const float* c2b     = (const float*)d_in[17];

  const int N = in_sizes[0] / HIDC;
  const int E = in_sizes[1] / 2;
  const int EN = E + N;
  const int NB = (N + 1023) / 1024;

  char* ws = (char*)d_ws;
  size_t off = 0;
  auto alloc = [&](size_t bytes) -> void* {
    void* p = ws + off;
    off += (bytes + 255) & ~(size_t)255;
    return p;
  };
  float* h0     = (float*)alloc((size_t)N * HIDC * 4);
  float* h1     = (float*)alloc((size_t)N * HIDC * 4);
  unsigned short* hb0 = (unsigned short*)alloc((size_t)N * HIDC * 2);
  unsigned short* hb1 = (unsigned short*)alloc((size_t)N * HIDC * 2);
  unsigned short* agg = (unsigned short*)alloc((size_t)N * 1024 * 2);  // also S[N,512]
  unsigned short* memb = (unsigned short*)alloc((size_t)N * HIDC * 2);
  float* aS     = (float*)alloc((size_t)N * NHEAD * 4);
  float* aD     = (float*)alloc((size_t)N * NHEAD * 4);
  short* encT   = (short*)alloc((size_t)128 * 128 * 2);
  short* Wp     = (short*)alloc((size_t)NLAY * 131072 * 2);
  float* waSD   = (float*)alloc((size_t)NLAY * 2048 * 4);
  short* Bt512  = (short*)alloc((size_t)512 * 256 * 2);
  int*   rowptr = (int*)alloc((size_t)(N + 1) * 4);
  int*   cursor = (int*)alloc((size_t)N * 4);
  int*   degtmp = (int*)alloc((size_t)N * 4);
  int*   bsum   = (int*)alloc(64 * 4);
  int*   csr    = (int*)alloc((size_t)EN * 4);
  float* cntbuf = (float*)alloc(64 * 4);

  float* out_logits = (float*)d_out;
  float* out_pooled = (float*)d_out + NGRAPH * NCLS;
  float* out_preds  = (float*)d_out + NGRAPH * NCLS + NGRAPH * HIDC;

  hipMemsetAsync(d_out, 0, (size_t)out_size * 4, stream);
  hipMemsetAsync(cntbuf, 0, 64 * 4, stream);
  hipMemsetAsync(cursor, 0, (size_t)N * 4, stream);
  hipMemsetAsync(degtmp, 0, (size_t)N * 4, stream);

  // CSR build
  hist_kernel<<<(EN + 255) / 256, 256, 0, stream>>>(ei, degtmp, E, N);
  scan1_kernel<<<NB, 1024, 0, stream>>>(degtmp, rowptr, bsum, N);
  scan2_kernel<<<1, 64, 0, stream>>>(bsum, NB);
  scan3_kernel<<<(N + 255) / 256, 256, 0, stream>>>(rowptr, bsum, N, EN);
  scatter_kernel<<<(EN + 255) / 256, 256, 0, stream>>>(ei, rowptr, cursor, csr, E, N);

  // weight prep
  convt_kernel<<<(128 * 128 + 255) / 256, 256, 0, stream>>>(enc_W, encT, 128, 128);
  rearr_kernel<<<(NLAY * 131072 + 255) / 256, 256, 0, stream>>>(gat_W, Wp);
  {
    dim3 g(NLAY, 8);
    wa_kernel<<<g, 256, 0, stream>>>(gat_W, att_src, att_dst, waSD);
  }
  build_gru_B<<<(512 * 256 + 255) / 256, 256, 0, stream>>>(W_ih, W_hh, Bt512);
  conv_kernel<<<((N * HIDC) + 255) / 256, 256, 0, stream>>>(memory, (short*)memb, N * HIDC);

  // encoder: h0 = relu(x @ enc_W + enc_b), fp32 + bf16 mirror
  {
    dim3 g((N + 63) / 64, 2);
    mm_bf16<<<g, 256, 0, stream>>>(x, encT, enc_b, h0, hb0, N, HIDC, 1);
  }

  float* hcur = h0;  unsigned short* hbcur = hb0;
  float* hnxt = h1;  unsigned short* hbnxt = hb1;
  for (int l = 0; l < NLAY; ++l) {
    alpha2_kernel<<<(N + 15) / 16, 256, 0, stream>>>(
        hcur, waSD + (size_t)l * 2048, aS, aD, N);
    gat_agg3<<<(N + 3) / 4, 256, 0, stream>>>(hbcur, rowptr, csr, aS, aD, agg, N);
    dim3 g((N + 63) / 64, 1);
    mm_bf16A<<<g, 256, 0, stream>>>(agg, Wp + (size_t)l * 131072,
                                    gat_b + (size_t)l * HIDC, hnxt, hbnxt,
                                    N, HIDC, 1024, (l < NLAY - 1) ? 1 : 0);
    float* t = hcur; hcur = hnxt; hnxt = t;
    unsigned short* tb = hbcur; hbcur = hbnxt; hbnxt = tb;
  }

  // fused-weight GRU: S = [hb|memb] @ Bt512^T (bf16), then gates
  {
    dim3 g((N + 63) / 64, 4);
    gru_mm<<<g, 256, 0, stream>>>(hbcur, memb, Bt512, agg, N);   // agg reused as S
  }
  gru_gate2<<<((N * HIDC) + 255) / 256, 256, 0, stream>>>(agg, memory, b_ih, b_hh,
                                                          hnxt, N);

  // pooling + classifier
  pool_kernel<<<(N + 127) / 128, 128, 0, stream>>>(hnxt, batch, out_pooled, cntbuf, N);
  classifier_kernel<<<NGRAPH, 64, 0, stream>>>(out_pooled, cntbuf, c1W, c1b, c2W, c2b,
                                               out_logits, out_preds);
}

// Round 6
// 892.331 us; speedup vs baseline: 3.3321x; 1.0442x over previous
//
#include <hip/hip_runtime.h>
#include <cstdint>
#include <cstddef>

#define HIDC 128
#define NHEAD 8
#define NLAY 3
#define NGRAPH 64
#define NCLS 3
#define MAXI 6   // cached edge-groups per lane: fast path deg <= 48

typedef __attribute__((ext_vector_type(8))) short short8;
typedef __attribute__((ext_vector_type(4))) float floatx4;

__device__ inline short f2bf(float x) {
  unsigned u = __float_as_uint(x);
  unsigned r = (u + 0x7fff + ((u >> 16) & 1)) >> 16;   // RNE
  return (short)r;
}
__device__ inline float bf2f(unsigned short u) {
  return __uint_as_float(((unsigned)u) << 16);
}

// ---------------------------------------------------------------------------
// Weight prep
// ---------------------------------------------------------------------------
__global__ void convt_kernel(const float* __restrict__ W, short* __restrict__ Wt,
                             int K, int Nc)
{
  int i = blockIdx.x * 256 + threadIdx.x;
  if (i >= K * Nc) return;
  int k = i / Nc, n = i - k * Nc;
  Wt[(size_t)n * K + k] = f2bf(W[i]);
}

__global__ void conv_kernel(const float* __restrict__ W, short* __restrict__ Wt,
                            int count)
{
  int i = blockIdx.x * 256 + threadIdx.x;
  if (i >= count) return;
  Wt[i] = f2bf(W[i]);
}

// Wp[l][c][h*128+k] = gat_W[l][k][h*128+c] / 8   (head-mean folded in)
__global__ void rearr_kernel(const float* __restrict__ gat_W, short* __restrict__ Wp)
{
  int i = blockIdx.x * 256 + threadIdx.x;
  if (i >= NLAY * 131072) return;
  int l = i >> 17, rem = i & 131071;
  int k = rem >> 10, hc = rem & 1023;
  int hh = hc >> 7, cc = hc & 127;
  Wp[(size_t)l * 131072 + (size_t)cc * 1024 + hh * 128 + k] = f2bf(gat_W[i] * 0.125f);
}

// waSD[l][k][j16]: j16<8 -> W_h a_src_h projection, j16>=8 -> a_dst
__global__ __launch_bounds__(256) void wa_kernel(
    const float* __restrict__ gat_W, const float* __restrict__ att_src,
    const float* __restrict__ att_dst, float* __restrict__ waSD)
{
  int l = blockIdx.x;
  int idx = blockIdx.y * 256 + threadIdx.x;
  int k = idx >> 4, j16 = idx & 15;
  int hh = j16 & 7;
  const float* a = ((j16 < 8) ? att_src : att_dst) + (size_t)l * 1024 + hh * 128;
  const float* w = gat_W + (size_t)l * 131072 + (size_t)k * 1024 + hh * 128;
  float s = 0.f;
  for (int cc = 0; cc < 128; ++cc) s += w[cc] * a[cc];
  waSD[(size_t)l * 2048 + idx] = s;
}

// Bt512[col][k] for fused GRU matmul over A=[h_bf16 | mem_bf16] (K=256)
__global__ void build_gru_B(const float* __restrict__ W_ih,
                            const float* __restrict__ W_hh,
                            short* __restrict__ Bt512)
{
  int i = blockIdx.x * 256 + threadIdx.x;
  if (i >= 512 * 256) return;
  int col = i >> 8, k = i & 255;
  float v;
  if (k < 128) {
    if (col < 384) v = W_ih[(size_t)col * 128 + k];
    else v = 0.f;
  } else {
    int k2 = k - 128;
    if (col < 256) v = W_hh[(size_t)col * 128 + k2];
    else if (col < 384) v = 0.f;
    else v = W_hh[(size_t)(col - 128) * 128 + k2];
  }
  Bt512[i] = f2bf(v);
}

// ---------------------------------------------------------------------------
// C[M,Nc] = act(A_fp32[M,128] @ B + bias), Bt[Nc][128] bf16. 64x64 tile.
// bf16-only output.
// ---------------------------------------------------------------------------
__global__ __launch_bounds__(256) void mm_bf16(
    const float* __restrict__ A, const short* __restrict__ Bt,
    const float* __restrict__ bias, unsigned short* __restrict__ Cb2,
    int M, int Nc, int relu)
{
  __shared__ short Asl[64 * 136];
  const int tid = threadIdx.x;
  const int m0 = blockIdx.x * 64;
  const int n0 = blockIdx.y * 64;

  const float4* A4 = (const float4*)A;
#pragma unroll
  for (int it = 0; it < 8; ++it) {
    int idx = tid + it * 256;
    int r = idx >> 5, k4 = idx & 31;
    int row = m0 + r; if (row >= M) row = M - 1;
    float4 a = A4[(size_t)row * 32 + k4];
    ushort4 p;
    p.x = (unsigned short)f2bf(a.x); p.y = (unsigned short)f2bf(a.y);
    p.z = (unsigned short)f2bf(a.z); p.w = (unsigned short)f2bf(a.w);
    *(ushort4*)&Asl[r * 136 + k4 * 4] = p;
  }
  __syncthreads();

  const int wid = tid >> 6, lane = tid & 63;
  const int l15 = lane & 15, quad = lane >> 4;
  const int wm = wid & 1, wn = wid >> 1;
  const int mb = wm * 32;
  const int nb = n0 + wn * 32;

  floatx4 acc00 = {0.f, 0.f, 0.f, 0.f};
  floatx4 acc01 = acc00, acc10 = acc00, acc11 = acc00;

#pragma unroll
  for (int kk = 0; kk < 4; ++kk) {
    int k = kk * 32 + quad * 8;
    short8 a0 = *(const short8*)&Asl[(mb + l15) * 136 + k];
    short8 a1 = *(const short8*)&Asl[(mb + 16 + l15) * 136 + k];
    short8 b0 = *(const short8*)&Bt[(size_t)(nb + l15) * 128 + k];
    short8 b1 = *(const short8*)&Bt[(size_t)(nb + 16 + l15) * 128 + k];
    acc00 = __builtin_amdgcn_mfma_f32_16x16x32_bf16(a0, b0, acc00, 0, 0, 0);
    acc01 = __builtin_amdgcn_mfma_f32_16x16x32_bf16(a0, b1, acc01, 0, 0, 0);
    acc10 = __builtin_amdgcn_mfma_f32_16x16x32_bf16(a1, b0, acc10, 0, 0, 0);
    acc11 = __builtin_amdgcn_mfma_f32_16x16x32_bf16(a1, b1, acc11, 0, 0, 0);
  }

#pragma unroll
  for (int mt = 0; mt < 2; ++mt) {
#pragma unroll
    for (int nt = 0; nt < 2; ++nt) {
      floatx4 acc = (mt == 0) ? (nt == 0 ? acc00 : acc01)
                              : (nt == 0 ? acc10 : acc11);
      int colg = nb + nt * 16 + l15;
      float bv = bias ? bias[colg] : 0.f;
#pragma unroll
      for (int r = 0; r < 4; ++r) {
        int rowg = m0 + mb + mt * 16 + quad * 4 + r;
        if (rowg < M && colg < Nc) {
          float v = acc[r] + bv;
          if (relu) v = fmaxf(v, 0.f);
          Cb2[(size_t)rowg * Nc + colg] = (unsigned short)f2bf(v);
        }
      }
    }
  }
}

// ---------------------------------------------------------------------------
// C[M,128] = act(A_bf16[M,K] @ B + bias), Bt[128][K] bf16, K mult of 64.
// bf16-only output.
// ---------------------------------------------------------------------------
__global__ __launch_bounds__(256) void mm_bf16A(
    const unsigned short* __restrict__ A, const short* __restrict__ Bt,
    const float* __restrict__ bias, unsigned short* __restrict__ Cb2,
    int M, int Nc, int K, int relu)
{
  __shared__ short As[64 * 72];
  const int tid = threadIdx.x;
  const int m0 = blockIdx.x * 64;
  const int n0 = blockIdx.y * 128;
  const int wid = tid >> 6, lane = tid & 63;
  const int l15 = lane & 15, quad = lane >> 4;
  const int wm = wid & 1, wn = wid >> 1;
  const int mb = wm * 32;
  const int nb = n0 + wn * 64;

  floatx4 acc[2][4];
#pragma unroll
  for (int a = 0; a < 2; ++a)
#pragma unroll
    for (int g = 0; g < 4; ++g) acc[a][g] = (floatx4){0.f, 0.f, 0.f, 0.f};

  for (int kb = 0; kb < K; kb += 64) {
    __syncthreads();
#pragma unroll
    for (int it = 0; it < 2; ++it) {
      int idx = tid + it * 256;
      int r = idx >> 3, k8 = (idx & 7) * 8;
      int row = m0 + r; if (row >= M) row = M - 1;
      *(short8*)&As[r * 72 + k8] = *(const short8*)&A[(size_t)row * K + kb + k8];
    }
    __syncthreads();
#pragma unroll
    for (int kk = 0; kk < 2; ++kk) {
      int ko = kk * 32 + quad * 8;
      short8 a0 = *(const short8*)&As[(mb + l15) * 72 + ko];
      short8 a1 = *(const short8*)&As[(mb + 16 + l15) * 72 + ko];
#pragma unroll
      for (int g = 0; g < 4; ++g) {
        int col = nb + g * 16 + l15; if (col >= Nc) col = Nc - 1;
        short8 b = *(const short8*)&Bt[(size_t)col * K + kb + ko];
        acc[0][g] = __builtin_amdgcn_mfma_f32_16x16x32_bf16(a0, b, acc[0][g], 0, 0, 0);
        acc[1][g] = __builtin_amdgcn_mfma_f32_16x16x32_bf16(a1, b, acc[1][g], 0, 0, 0);
      }
    }
  }

#pragma unroll
  for (int mt = 0; mt < 2; ++mt) {
#pragma unroll
    for (int g = 0; g < 4; ++g) {
      int colg = nb + g * 16 + l15;
      if (colg >= Nc) continue;
      float bv = bias ? bias[colg] : 0.f;
#pragma unroll
      for (int r = 0; r < 4; ++r) {
        int rowg = m0 + mb + mt * 16 + quad * 4 + r;
        if (rowg < M) {
          float v = acc[mt][g][r] + bv;
          if (relu) v = fmaxf(v, 0.f);
          Cb2[(size_t)rowg * Nc + colg] = (unsigned short)f2bf(v);
        }
      }
    }
  }
}

// ---------------------------------------------------------------------------
// GRU matmul: S[M,512] = [hb | memb] @ Bt512^T, all bf16, K=256. Out bf16.
// ---------------------------------------------------------------------------
__global__ __launch_bounds__(256) void gru_mm(
    const unsigned short* __restrict__ hb, const unsigned short* __restrict__ memb,
    const short* __restrict__ Bt512, unsigned short* __restrict__ S, int M)
{
  __shared__ short As[64 * 72];
  const int tid = threadIdx.x;
  const int m0 = blockIdx.x * 64;
  const int n0 = blockIdx.y * 128;
  const int wid = tid >> 6, lane = tid & 63;
  const int l15 = lane & 15, quad = lane >> 4;
  const int wm = wid & 1, wn = wid >> 1;
  const int mb = wm * 32;
  const int nb = n0 + wn * 64;

  floatx4 acc[2][4];
#pragma unroll
  for (int a = 0; a < 2; ++a)
#pragma unroll
    for (int g = 0; g < 4; ++g) acc[a][g] = (floatx4){0.f, 0.f, 0.f, 0.f};

  for (int kb = 0; kb < 256; kb += 64) {
    const unsigned short* Asrc = (kb < 128) ? hb : memb;
    int kloc = (kb < 128) ? kb : kb - 128;
    __syncthreads();
#pragma unroll
    for (int it = 0; it < 2; ++it) {
      int idx = tid + it * 256;
      int r = idx >> 3, k8 = (idx & 7) * 8;
      int row = m0 + r; if (row >= M) row = M - 1;
      *(short8*)&As[r * 72 + k8] = *(const short8*)&Asrc[(size_t)row * 128 + kloc + k8];
    }
    __syncthreads();
#pragma unroll
    for (int kk = 0; kk < 2; ++kk) {
      int ko = kk * 32 + quad * 8;
      short8 a0 = *(const short8*)&As[(mb + l15) * 72 + ko];
      short8 a1 = *(const short8*)&As[(mb + 16 + l15) * 72 + ko];
#pragma unroll
      for (int g = 0; g < 4; ++g) {
        int col = nb + g * 16 + l15;
        short8 b = *(const short8*)&Bt512[(size_t)col * 256 + kb + ko];
        acc[0][g] = __builtin_amdgcn_mfma_f32_16x16x32_bf16(a0, b, acc[0][g], 0, 0, 0);
        acc[1][g] = __builtin_amdgcn_mfma_f32_16x16x32_bf16(a1, b, acc[1][g], 0, 0, 0);
      }
    }
  }

#pragma unroll
  for (int mt = 0; mt < 2; ++mt) {
#pragma unroll
    for (int g = 0; g < 4; ++g) {
      int colg = nb + g * 16 + l15;
#pragma unroll
      for (int r = 0; r < 4; ++r) {
        int rowg = m0 + mb + mt * 16 + quad * 4 + r;
        if (rowg < M)
          S[(size_t)rowg * 512 + colg] = (unsigned short)f2bf(acc[mt][g][r]);
      }
    }
  }
}

// ---------------------------------------------------------------------------
// GRU gates from fused S (bf16)
// ---------------------------------------------------------------------------
__global__ __launch_bounds__(256) void gru_gate2(
    const unsigned short* __restrict__ S, const float* __restrict__ mem,
    const float* __restrict__ bI, const float* __restrict__ bH,
    float* __restrict__ hout, int N)
{
  int idx = blockIdx.x * 256 + threadIdx.x;
  if (idx >= N * HIDC) return;
  int n = idx >> 7, c = idx & 127;
  size_t b = (size_t)n * 512;
  float sr  = bf2f(S[b + c])       + bI[c]       + bH[c];
  float sz  = bf2f(S[b + 128 + c]) + bI[128 + c] + bH[128 + c];
  float gin = bf2f(S[b + 256 + c]) + bI[256 + c];
  float ghn = bf2f(S[b + 384 + c]) + bH[256 + c];
  float rg = 1.f / (1.f + __expf(-sr));
  float zg = 1.f / (1.f + __expf(-sz));
  float nc = tanhf(gin + rg * ghn);
  hout[idx] = (1.f - zg) * nc + zg * mem[idx];
}

// ---------------------------------------------------------------------------
// alphas from bf16 h: aS/aD[n][h] = h[n,:] . waSD[:,j16]
// ---------------------------------------------------------------------------
__global__ __launch_bounds__(256) void alpha2b_kernel(
    const unsigned short* __restrict__ hb, const float* __restrict__ waSD,
    float* __restrict__ aS, float* __restrict__ aD, int N)
{
  __shared__ float s_wa[2048];
  const int tid = threadIdx.x;
  for (int i = tid; i < 2048; i += 256) s_wa[i] = waSD[i];
  __syncthreads();
  int node = blockIdx.x * 16 + (tid >> 4);
  int j = tid & 15;
  if (node >= N) return;
  const short8* h8 = (const short8*)(hb + (size_t)node * 128);
  float s = 0.f;
#pragma unroll
  for (int k8 = 0; k8 < 16; ++k8) {
    short8 v = h8[k8];
#pragma unroll
    for (int t = 0; t < 8; ++t)
      s += bf2f((unsigned short)v[t]) * s_wa[(k8 * 8 + t) * 16 + j];
  }
  if (j < 8) aS[(size_t)node * 8 + j] = s;
  else       aD[(size_t)node * 8 + (j - 8)] = s;
}

// ---------------------------------------------------------------------------
// CSR build: histogram, 3-stage scan, scatter
// ---------------------------------------------------------------------------
__global__ void hist_kernel(const int* __restrict__ ei, int* __restrict__ deg, int E, int N)
{
  int i = blockIdx.x * 256 + threadIdx.x;
  if (i >= E + N) return;
  int dst = (i < E) ? ei[E + i] : (i - E);
  atomicAdd(&deg[dst], 1);
}

__global__ __launch_bounds__(1024) void scan1_kernel(
    const int* __restrict__ deg, int* __restrict__ rowptr,
    int* __restrict__ bsum, int N)
{
  __shared__ int sd[1024];
  int i = blockIdx.x * 1024 + threadIdx.x;
  int v = (i < N) ? deg[i] : 0;
  sd[threadIdx.x] = v;
  __syncthreads();
  for (int off = 1; off < 1024; off <<= 1) {
    int t = (threadIdx.x >= off) ? sd[threadIdx.x - off] : 0;
    __syncthreads();
    sd[threadIdx.x] += t;
    __syncthreads();
  }
  if (i < N) rowptr[i] = sd[threadIdx.x] - v;
  if (threadIdx.x == 1023) bsum[blockIdx.x] = sd[1023];
}

__global__ __launch_bounds__(64) void scan2_kernel(int* __restrict__ bsum, int nb)
{
  int lane = threadIdx.x;
  int v = (lane < nb) ? bsum[lane] : 0;
  int incl = v;
  for (int off = 1; off < 64; off <<= 1) {
    int t = __shfl_up(incl, off);
    if (lane >= off) incl += t;
  }
  if (lane < nb) bsum[lane] = incl - v;
}

__global__ void scan3_kernel(int* __restrict__ rowptr, const int* __restrict__ bsum,
                             int N, int EN)
{
  int i = blockIdx.x * 256 + threadIdx.x;
  if (i < N) rowptr[i] += bsum[i >> 10];
  if (i == 0) rowptr[N] = EN;
}

__global__ void scatter_kernel(const int* __restrict__ ei, const int* __restrict__ rowptr,
                               int* __restrict__ cursor, int* __restrict__ csr_src,
                               int E, int N)
{
  int i = blockIdx.x * 256 + threadIdx.x;
  if (i >= E + N) return;
  int src, dst;
  if (i < E) { src = ei[i]; dst = ei[E + i]; }
  else { src = i - E; dst = i - E; }
  int pos = rowptr[dst] + atomicAdd(&cursor[dst], 1);
  csr_src[pos] = src;
}

// ---------------------------------------------------------------------------
// GAT aggregation v4: one wave per dst, wave-private LDS p/src staging,
// batched gathers (8 outstanding), no barriers, no bpermute broadcast.
// ---------------------------------------------------------------------------
__global__ __launch_bounds__(256) void gat_agg4(
    const unsigned short* __restrict__ hb, const int* __restrict__ rowptr,
    const int* __restrict__ csr_src, const float* __restrict__ aS,
    const float* __restrict__ aD, unsigned short* __restrict__ agg, int N)
{
  __shared__ float s_p[4][48][8];   // per-wave p (unnormalized), 0 for padding
  __shared__ int   s_src[4][48];    // per-wave src ids, 0 for padding
  const int wid = threadIdx.x >> 6;
  const int lane = threadIdx.x & 63;
  const int dst = blockIdx.x * 4 + wid;
  if (dst >= N) return;
  const int el = lane >> 3, hh = lane & 7;
  const int start = rowptr[dst];
  const int deg = rowptr[dst + 1] - start;
  const float adh = aD[(size_t)dst * 8 + hh];

  // pass 1: scores, per-head max
  int src_c[MAXI]; float v_c[MAXI];
  float m = -1e30f;
#pragma unroll
  for (int i = 0; i < MAXI; ++i) {
    int e = i * 8 + el;
    int s = 0; float v = -1e30f;
    if (e < deg) {
      s = csr_src[start + e];
      v = aS[(size_t)s * 8 + hh] + adh;
      v = (v > 0.f) ? v : 0.2f * v;
    }
    src_c[i] = s; v_c[i] = v;
    m = fmaxf(m, v);
  }
  for (int e0 = MAXI * 8; e0 < deg; e0 += 8) {
    int e = e0 + el;
    if (e < deg) {
      int s = csr_src[start + e];
      float v = aS[(size_t)s * 8 + hh] + adh;
      v = (v > 0.f) ? v : 0.2f * v;
      m = fmaxf(m, v);
    }
  }
  m = fmaxf(m, __shfl_xor(m, 8));
  m = fmaxf(m, __shfl_xor(m, 16));
  m = fmaxf(m, __shfl_xor(m, 32));

  // p + stage to wave-private LDS
  float dsum = 0.f;
#pragma unroll
  for (int i = 0; i < MAXI; ++i) {
    int e = i * 8 + el;
    float p = (e < deg) ? __expf(v_c[i] - m) : 0.f;
    dsum += p;
    s_p[wid][e][hh] = p;
    if (hh == 0) s_src[wid][e] = src_c[i];
  }

  // pass 2: batched gather + FMA (fast path; p=0 padding makes it branch-free)
  float accx[8], accy[8];
#pragma unroll
  for (int q = 0; q < 8; ++q) { accx[q] = 0.f; accy[q] = 0.f; }
  const unsigned* hb32 = (const unsigned*)hb;

#pragma unroll
  for (int i = 0; i < MAXI; ++i) {
    if (i * 8 >= deg) break;                       // wave-uniform
    int4 sa = *(const int4*)&s_src[wid][i * 8];
    int4 sb = *(const int4*)&s_src[wid][i * 8 + 4];
    int srcs[8] = {sa.x, sa.y, sa.z, sa.w, sb.x, sb.y, sb.z, sb.w};
    unsigned hv[8];
#pragma unroll
    for (int ee = 0; ee < 8; ++ee)
      hv[ee] = hb32[(unsigned)srcs[ee] * 64 + lane];
#pragma unroll
    for (int ee = 0; ee < 8; ++ee) {
      float4 pA = *(const float4*)&s_p[wid][i * 8 + ee][0];
      float4 pB = *(const float4*)&s_p[wid][i * 8 + ee][4];
      float hx = bf2f((unsigned short)hv[ee]);
      float hy = bf2f((unsigned short)(hv[ee] >> 16));
      accx[0] = fmaf(pA.x, hx, accx[0]); accy[0] = fmaf(pA.x, hy, accy[0]);
      accx[1] = fmaf(pA.y, hx, accx[1]); accy[1] = fmaf(pA.y, hy, accy[1]);
      accx[2] = fmaf(pA.z, hx, accx[2]); accy[2] = fmaf(pA.z, hy, accy[2]);
      accx[3] = fmaf(pA.w, hx, accx[3]); accy[3] = fmaf(pA.w, hy, accy[3]);
      accx[4] = fmaf(pB.x, hx, accx[4]); accy[4] = fmaf(pB.x, hy, accy[4]);
      accx[5] = fmaf(pB.y, hx, accx[5]); accy[5] = fmaf(pB.y, hy, accy[5]);
      accx[6] = fmaf(pB.z, hx, accx[6]); accy[6] = fmaf(pB.z, hy, accy[6]);
      accx[7] = fmaf(pB.w, hx, accx[7]); accy[7] = fmaf(pB.w, hy, accy[7]);
    }
  }
  // overflow path (deg > 48): recompute + shuffle broadcast
  const int c2 = lane * 2;
  for (int e0 = MAXI * 8; e0 < deg; e0 += 8) {
    int e = e0 + el;
    float p = 0.f; int s = 0;
    if (e < deg) {
      s = csr_src[start + e];
      float v = aS[(size_t)s * 8 + hh] + adh;
      v = (v > 0.f) ? v : 0.2f * v;
      p = __expf(v - m);
    }
    dsum += p;
    int cnt = deg - e0; if (cnt > 8) cnt = 8;
    for (int ee = 0; ee < cnt; ++ee) {
      int se = __shfl(s, ee * 8);
      unsigned hv = *(const unsigned*)&hb[(size_t)se * 128 + c2];
      float hx = bf2f((unsigned short)hv);
      float hy = bf2f((unsigned short)(hv >> 16));
#pragma unroll
      for (int q = 0; q < 8; ++q) {
        float pq = __shfl(p, ee * 8 + q);
        accx[q] = fmaf(pq, hx, accx[q]);
        accy[q] = fmaf(pq, hy, accy[q]);
      }
    }
  }

  dsum += __shfl_xor(dsum, 8);
  dsum += __shfl_xor(dsum, 16);
  dsum += __shfl_xor(dsum, 32);
  float inv = 1.f / (dsum + 1e-16f);

#pragma unroll
  for (int q = 0; q < 8; ++q) {
    float invq = __shfl(inv, q);                  // lane q holds hh=q denom
    float ax = accx[q] * invq, ay = accy[q] * invq;
    unsigned pk = ((unsigned)(unsigned short)f2bf(ay) << 16) |
                  (unsigned)(unsigned short)f2bf(ax);
    *(unsigned*)&agg[(size_t)dst * 1024 + q * 128 + c2] = pk;
  }
}

// ---------------------------------------------------------------------------
// global_mean_pool
// ---------------------------------------------------------------------------
__global__ __launch_bounds__(128) void pool_kernel(
    const float* __restrict__ h, const int* __restrict__ batch,
    float* __restrict__ pooled_sums, float* __restrict__ cnt, int N)
{
  int n0 = blockIdx.x * 128;
  int c = threadIdx.x;
  int end = n0 + 128; if (end > N) end = N;
  if (n0 >= N) return;
  int cur = batch[n0];
  float acc = 0.f; float count = 0.f;
  for (int n = n0; n < end; ++n) {
    int b = batch[n];
    if (b != cur) {
      atomicAdd(&pooled_sums[(size_t)cur * HIDC + c], acc);
      if (c == 0) atomicAdd(&cnt[cur], count);
      acc = 0.f; count = 0.f; cur = b;
    }
    acc += h[(size_t)n * HIDC + c];
    count += 1.f;
  }
  atomicAdd(&pooled_sums[(size_t)cur * HIDC + c], acc);
  if (c == 0) atomicAdd(&cnt[cur], count);
}

// ---------------------------------------------------------------------------
// finalize pooled, classifier MLP, softmax
// ---------------------------------------------------------------------------
__global__ __launch_bounds__(64) void classifier_kernel(
    float* __restrict__ pooled, const float* __restrict__ cnt,
    const float* __restrict__ c1W, const float* __restrict__ c1b,
    const float* __restrict__ c2W, const float* __restrict__ c2b,
    float* __restrict__ logits, float* __restrict__ preds)
{
  int g = blockIdx.x, j = threadIdx.x;
  __shared__ float sp[128];
  __shared__ float hid[64];
  __shared__ float lg[3];
  float invc = 1.f / fmaxf(cnt[g], 1.f);
  float p0 = pooled[(size_t)g * 128 + j] * invc;
  float p1 = pooled[(size_t)g * 128 + 64 + j] * invc;
  pooled[(size_t)g * 128 + j] = p0;
  pooled[(size_t)g * 128 + 64 + j] = p1;
  sp[j] = p0; sp[j + 64] = p1;
  __syncthreads();
  float a = c1b[j];
#pragma unroll
  for (int k = 0; k < 128; ++k) a = fmaf(sp[k], c1W[k * 64 + j], a);
  hid[j] = fmaxf(a, 0.f);
  __syncthreads();
  if (j < NCLS) {
    float t = c2b[j];
#pragma unroll
    for (int k = 0; k < 64; ++k) t = fmaf(hid[k], c2W[k * NCLS + j], t);
    logits[(size_t)g * NCLS + j] = t;
    lg[j] = t;
  }
  __syncthreads();
  if (j < NCLS) {
    float mx = fmaxf(lg[0], fmaxf(lg[1], lg[2]));
    float e0 = __expf(lg[0] - mx), e1 = __expf(lg[1] - mx), e2 = __expf(lg[2] - mx);
    float mine = (j == 0) ? e0 : ((j == 1) ? e1 : e2);
    preds[(size_t)g * NCLS + j] = mine / (e0 + e1 + e2);
  }
}

// ---------------------------------------------------------------------------
extern "C" void kernel_launch(void* const* d_in, const int* in_sizes, int n_in,
                              void* d_out, int out_size, void* d_ws, size_t ws_size,
                              hipStream_t stream)
{
  const float* x       = (const float*)d_in[0];
  const int*   ei      = (const int*)d_in[1];
  const int*   batch   = (const int*)d_in[2];
  const float* memory  = (const float*)d_in[3];
  const float* enc_W   = (const float*)d_in[4];
  const float* enc_b   = (const float*)d_in[5];
  const float* gat_W   = (const float*)d_in[6];   // [NL,128,1024]
  const float* att_src = (const float*)d_in[7];
  const float* att_dst = (const float*)d_in[8];
  const float* gat_b   = (const float*)d_in[9];
  const float* W_ih    = (const float*)d_in[10];
  const float* W_hh    = (const float*)d_in[11];
  const float* b_ih    = (const float*)d_in[12];
  const float* b_hh    = (const float*)d_in[13];
  const float* c1W     = (const float*)d_in[14];
  const float* c1b     = (const float*)d_in[15];
  const float* c2W     = (const float*)d_in[16];
  const float* c2b     = (const float*)d_in[17];

  const int N = in_sizes[0] / HIDC;
  const int E = in_sizes[1] / 2;
  const int EN = E + N;
  const int NB = (N + 1023) / 1024;

  char* ws = (char*)d_ws;
  size_t off = 0;
  auto alloc = [&](size_t bytes) -> void* {
    void* p = ws + off;
    off += (bytes + 255) & ~(size_t)255;
    return p;
  };
  unsigned short* hb0 = (unsigned short*)alloc((size_t)N * HIDC * 2);
  unsigned short* hb1 = (unsigned short*)alloc((size_t)N * HIDC * 2);
  float* hgru   = (float*)alloc((size_t)N * HIDC * 4);
  unsigned short* agg = (unsigned short*)alloc((size_t)N * 1024 * 2);  // also S[N,512]
  unsigned short* memb = (unsigned short*)alloc((size_t)N * HIDC * 2);
  float* aS     = (float*)alloc((size_t)N * NHEAD * 4);
  float* aD     = (float*)alloc((size_t)N * NHEAD * 4);
  short* encT   = (short*)alloc((size_t)128 * 128 * 2);
  short* Wp     = (short*)alloc((size_t)NLAY * 131072 * 2);
  float* waSD   = (float*)alloc((size_t)NLAY * 2048 * 4);
  short* Bt512  = (short*)alloc((size_t)512 * 256 * 2);
  int*   rowptr = (int*)alloc((size_t)(N + 1) * 4);
  int*   cursor = (int*)alloc((size_t)N * 4);
  int*   degtmp = (int*)alloc((size_t)N * 4);
  int*   bsum   = (int*)alloc(64 * 4);
  int*   csr    = (int*)alloc((size_t)EN * 4);
  float* cntbuf = (float*)alloc(64 * 4);

  float* out_logits = (float*)d_out;
  float* out_pooled = (float*)d_out + NGRAPH * NCLS;
  float* out_preds  = (float*)d_out + NGRAPH * NCLS + NGRAPH * HIDC;

  hipMemsetAsync(d_out, 0, (size_t)out_size * 4, stream);
  hipMemsetAsync(cntbuf, 0, 64 * 4, stream);
  hipMemsetAsync(cursor, 0, (size_t)N * 4, stream);
  hipMemsetAsync(degtmp, 0, (size_t)N * 4, stream);

  // CSR build
  hist_kernel<<<(EN + 255) / 256, 256, 0, stream>>>(ei, degtmp, E, N);
  scan1_kernel<<<NB, 1024, 0, stream>>>(degtmp, rowptr, bsum, N);
  scan2_kernel<<<1, 64, 0, stream>>>(bsum, NB);
  scan3_kernel<<<(N + 255) / 256, 256, 0, stream>>>(rowptr, bsum, N, EN);
  scatter_kernel<<<(EN + 255) / 256, 256, 0, stream>>>(ei, rowptr, cursor, csr, E, N);

  // weight prep
  convt_kernel<<<(128 * 128 + 255) / 256, 256, 0, stream>>>(enc_W, encT, 128, 128);
  rearr_kernel<<<(NLAY * 131072 + 255) / 256, 256, 0, stream>>>(gat_W, Wp);
  {
    dim3 g(NLAY, 8);
    wa_kernel<<<g, 256, 0, stream>>>(gat_W, att_src, att_dst, waSD);
  }
  build_gru_B<<<(512 * 256 + 255) / 256, 256, 0, stream>>>(W_ih, W_hh, Bt512);
  conv_kernel<<<((N * HIDC) + 255) / 256, 256, 0, stream>>>(memory, (short*)memb, N * HIDC);

  // encoder: hb0 = bf16(relu(x @ enc_W + enc_b))
  {
    dim3 g((N + 63) / 64, 2);
    mm_bf16<<<g, 256, 0, stream>>>(x, encT, enc_b, hb0, N, HIDC, 1);
  }

  unsigned short* hbcur = hb0;
  unsigned short* hbnxt = hb1;
  for (int l = 0; l < NLAY; ++l) {
    alpha2b_kernel<<<(N + 15) / 16, 256, 0, stream>>>(
        hbcur, waSD + (size_t)l * 2048, aS, aD, N);
    gat_agg4<<<(N + 3) / 4, 256, 0, stream>>>(hbcur, rowptr, csr, aS, aD, agg, N);
    dim3 g((N + 63) / 64, 1);
    mm_bf16A<<<g, 256, 0, stream>>>(agg, Wp + (size_t)l * 131072,
                                    gat_b + (size_t)l * HIDC, hbnxt,
                                    N, HIDC, 1024, (l < NLAY - 1) ? 1 : 0);
    unsigned short* tb = hbcur; hbcur = hbnxt; hbnxt = tb;
  }

  // fused-weight GRU: S = [hb|memb] @ Bt512^T (bf16), then gates
  {
    dim3 g((N + 63) / 64, 4);
    gru_mm<<<g, 256, 0, stream>>>(hbcur, memb, Bt512, agg, N);   // agg reused as S
  }
  gru_gate2<<<((N * HIDC) + 255) / 256, 256, 0, stream>>>(agg, memory, b_ih, b_hh,
                                                          hgru, N);

  // pooling + classifier
  pool_kernel<<<(N + 127) / 128, 128, 0, stream>>>(hgru, batch, out_pooled, cntbuf, N);
  classifier_kernel<<<NGRAPH, 64, 0, stream>>>(out_pooled, cntbuf, c1W, c1b, c2W, c2b,
                                               out_logits, out_preds);
}

// Round 7
// 835.072 us; speedup vs baseline: 3.5606x; 1.0686x over previous
//
#include <hip/hip_runtime.h>
#include <cstdint>
#include <cstddef>

#define HIDC 128
#define NHEAD 8
#define NLAY 3
#define NGRAPH 64
#define NCLS 3
#define MAXI 6   // fast path deg <= 48

typedef __attribute__((ext_vector_type(8))) short short8;
typedef __attribute__((ext_vector_type(4))) float floatx4;

__device__ inline short f2bf(float x) {
  unsigned u = __float_as_uint(x);
  unsigned r = (u + 0x7fff + ((u >> 16) & 1)) >> 16;   // RNE
  return (short)r;
}
__device__ inline float bf2f(unsigned short u) {
  return __uint_as_float(((unsigned)u) << 16);
}

// ---------------------------------------------------------------------------
// Weight prep
// ---------------------------------------------------------------------------
__global__ void convt_kernel(const float* __restrict__ W, short* __restrict__ Wt,
                             int K, int Nc)
{
  int i = blockIdx.x * 256 + threadIdx.x;
  if (i >= K * Nc) return;
  int k = i / Nc, n = i - k * Nc;
  Wt[(size_t)n * K + k] = f2bf(W[i]);
}

// Wp[l][c][h*128+k] = gat_W[l][k][h*128+c] / 8   (head-mean folded in)
__global__ void rearr_kernel(const float* __restrict__ gat_W, short* __restrict__ Wp)
{
  int i = blockIdx.x * 256 + threadIdx.x;
  if (i >= NLAY * 131072) return;
  int l = i >> 17, rem = i & 131071;
  int k = rem >> 10, hc = rem & 1023;
  int hh = hc >> 7, cc = hc & 127;
  Wp[(size_t)l * 131072 + (size_t)cc * 1024 + hh * 128 + k] = f2bf(gat_W[i] * 0.125f);
}

// waSD[l][k][j16]: j16<8 -> W_h a_src_h projection, j16>=8 -> a_dst
__global__ __launch_bounds__(256) void wa_kernel(
    const float* __restrict__ gat_W, const float* __restrict__ att_src,
    const float* __restrict__ att_dst, float* __restrict__ waSD)
{
  int l = blockIdx.x;
  int idx = blockIdx.y * 256 + threadIdx.x;
  int k = idx >> 4, j16 = idx & 15;
  int hh = j16 & 7;
  const float* a = ((j16 < 8) ? att_src : att_dst) + (size_t)l * 1024 + hh * 128;
  const float* w = gat_W + (size_t)l * 131072 + (size_t)k * 1024 + hh * 128;
  float s = 0.f;
  for (int cc = 0; cc < 128; ++cc) s += w[cc] * a[cc];
  waSD[(size_t)l * 2048 + idx] = s;
}

// Bt512[col][k] for fused GRU matmul over A=[h_bf16 | mem_bf16] (K=256)
__global__ void build_gru_B(const float* __restrict__ W_ih,
                            const float* __restrict__ W_hh,
                            short* __restrict__ Bt512)
{
  int i = blockIdx.x * 256 + threadIdx.x;
  if (i >= 512 * 256) return;
  int col = i >> 8, k = i & 255;
  float v;
  if (k < 128) {
    if (col < 384) v = W_ih[(size_t)col * 128 + k];
    else v = 0.f;
  } else {
    int k2 = k - 128;
    if (col < 256) v = W_hh[(size_t)col * 128 + k2];
    else if (col < 384) v = 0.f;
    else v = W_hh[(size_t)(col - 128) * 128 + k2];
  }
  Bt512[i] = f2bf(v);
}

// ---------------------------------------------------------------------------
// C[M,Nc] = act(A_fp32[M,128] @ B + bias), Bt[Nc][128] bf16. 64x64 tile.
// bf16-only output.
// ---------------------------------------------------------------------------
__global__ __launch_bounds__(256) void mm_bf16(
    const float* __restrict__ A, const short* __restrict__ Bt,
    const float* __restrict__ bias, unsigned short* __restrict__ Cb2,
    int M, int Nc, int relu)
{
  __shared__ short Asl[64 * 136];
  const int tid = threadIdx.x;
  const int m0 = blockIdx.x * 64;
  const int n0 = blockIdx.y * 64;

  const float4* A4 = (const float4*)A;
#pragma unroll
  for (int it = 0; it < 8; ++it) {
    int idx = tid + it * 256;
    int r = idx >> 5, k4 = idx & 31;
    int row = m0 + r; if (row >= M) row = M - 1;
    float4 a = A4[(size_t)row * 32 + k4];
    ushort4 p;
    p.x = (unsigned short)f2bf(a.x); p.y = (unsigned short)f2bf(a.y);
    p.z = (unsigned short)f2bf(a.z); p.w = (unsigned short)f2bf(a.w);
    *(ushort4*)&Asl[r * 136 + k4 * 4] = p;
  }
  __syncthreads();

  const int wid = tid >> 6, lane = tid & 63;
  const int l15 = lane & 15, quad = lane >> 4;
  const int wm = wid & 1, wn = wid >> 1;
  const int mb = wm * 32;
  const int nb = n0 + wn * 32;

  floatx4 acc00 = {0.f, 0.f, 0.f, 0.f};
  floatx4 acc01 = acc00, acc10 = acc00, acc11 = acc00;

#pragma unroll
  for (int kk = 0; kk < 4; ++kk) {
    int k = kk * 32 + quad * 8;
    short8 a0 = *(const short8*)&Asl[(mb + l15) * 136 + k];
    short8 a1 = *(const short8*)&Asl[(mb + 16 + l15) * 136 + k];
    short8 b0 = *(const short8*)&Bt[(size_t)(nb + l15) * 128 + k];
    short8 b1 = *(const short8*)&Bt[(size_t)(nb + 16 + l15) * 128 + k];
    acc00 = __builtin_amdgcn_mfma_f32_16x16x32_bf16(a0, b0, acc00, 0, 0, 0);
    acc01 = __builtin_amdgcn_mfma_f32_16x16x32_bf16(a0, b1, acc01, 0, 0, 0);
    acc10 = __builtin_amdgcn_mfma_f32_16x16x32_bf16(a1, b0, acc10, 0, 0, 0);
    acc11 = __builtin_amdgcn_mfma_f32_16x16x32_bf16(a1, b1, acc11, 0, 0, 0);
  }

#pragma unroll
  for (int mt = 0; mt < 2; ++mt) {
#pragma unroll
    for (int nt = 0; nt < 2; ++nt) {
      floatx4 acc = (mt == 0) ? (nt == 0 ? acc00 : acc01)
                              : (nt == 0 ? acc10 : acc11);
      int colg = nb + nt * 16 + l15;
      float bv = bias ? bias[colg] : 0.f;
#pragma unroll
      for (int r = 0; r < 4; ++r) {
        int rowg = m0 + mb + mt * 16 + quad * 4 + r;
        if (rowg < M && colg < Nc) {
          float v = acc[r] + bv;
          if (relu) v = fmaxf(v, 0.f);
          Cb2[(size_t)rowg * Nc + colg] = (unsigned short)f2bf(v);
        }
      }
    }
  }
}

// ---------------------------------------------------------------------------
// C[M,128] = act(A_bf16[M,K] @ B + bias), Bt[128][K] bf16, K mult of 64.
// bf16-only output.
// ---------------------------------------------------------------------------
__global__ __launch_bounds__(256) void mm_bf16A(
    const unsigned short* __restrict__ A, const short* __restrict__ Bt,
    const float* __restrict__ bias, unsigned short* __restrict__ Cb2,
    int M, int Nc, int K, int relu)
{
  __shared__ short As[64 * 72];
  const int tid = threadIdx.x;
  const int m0 = blockIdx.x * 64;
  const int n0 = blockIdx.y * 128;
  const int wid = tid >> 6, lane = tid & 63;
  const int l15 = lane & 15, quad = lane >> 4;
  const int wm = wid & 1, wn = wid >> 1;
  const int mb = wm * 32;
  const int nb = n0 + wn * 64;

  floatx4 acc[2][4];
#pragma unroll
  for (int a = 0; a < 2; ++a)
#pragma unroll
    for (int g = 0; g < 4; ++g) acc[a][g] = (floatx4){0.f, 0.f, 0.f, 0.f};

  for (int kb = 0; kb < K; kb += 64) {
    __syncthreads();
#pragma unroll
    for (int it = 0; it < 2; ++it) {
      int idx = tid + it * 256;
      int r = idx >> 3, k8 = (idx & 7) * 8;
      int row = m0 + r; if (row >= M) row = M - 1;
      *(short8*)&As[r * 72 + k8] = *(const short8*)&A[(size_t)row * K + kb + k8];
    }
    __syncthreads();
#pragma unroll
    for (int kk = 0; kk < 2; ++kk) {
      int ko = kk * 32 + quad * 8;
      short8 a0 = *(const short8*)&As[(mb + l15) * 72 + ko];
      short8 a1 = *(const short8*)&As[(mb + 16 + l15) * 72 + ko];
#pragma unroll
      for (int g = 0; g < 4; ++g) {
        int col = nb + g * 16 + l15; if (col >= Nc) col = Nc - 1;
        short8 b = *(const short8*)&Bt[(size_t)col * K + kb + ko];
        acc[0][g] = __builtin_amdgcn_mfma_f32_16x16x32_bf16(a0, b, acc[0][g], 0, 0, 0);
        acc[1][g] = __builtin_amdgcn_mfma_f32_16x16x32_bf16(a1, b, acc[1][g], 0, 0, 0);
      }
    }
  }

#pragma unroll
  for (int mt = 0; mt < 2; ++mt) {
#pragma unroll
    for (int g = 0; g < 4; ++g) {
      int colg = nb + g * 16 + l15;
      if (colg >= Nc) continue;
      float bv = bias ? bias[colg] : 0.f;
#pragma unroll
      for (int r = 0; r < 4; ++r) {
        int rowg = m0 + mb + mt * 16 + quad * 4 + r;
        if (rowg < M) {
          float v = acc[mt][g][r] + bv;
          if (relu) v = fmaxf(v, 0.f);
          Cb2[(size_t)rowg * Nc + colg] = (unsigned short)f2bf(v);
        }
      }
    }
  }
}

// ---------------------------------------------------------------------------
// GRU matmul: S[M,512] = [hb | mem_fp32->bf16] @ Bt512^T, K=256. Out bf16.
// ---------------------------------------------------------------------------
__global__ __launch_bounds__(256) void gru_mm(
    const unsigned short* __restrict__ hb, const float* __restrict__ mem,
    const short* __restrict__ Bt512, unsigned short* __restrict__ S, int M)
{
  __shared__ short As[64 * 72];
  const int tid = threadIdx.x;
  const int m0 = blockIdx.x * 64;
  const int n0 = blockIdx.y * 128;
  const int wid = tid >> 6, lane = tid & 63;
  const int l15 = lane & 15, quad = lane >> 4;
  const int wm = wid & 1, wn = wid >> 1;
  const int mb = wm * 32;
  const int nb = n0 + wn * 64;

  floatx4 acc[2][4];
#pragma unroll
  for (int a = 0; a < 2; ++a)
#pragma unroll
    for (int g = 0; g < 4; ++g) acc[a][g] = (floatx4){0.f, 0.f, 0.f, 0.f};

  for (int kb = 0; kb < 256; kb += 64) {
    __syncthreads();
#pragma unroll
    for (int it = 0; it < 2; ++it) {
      int idx = tid + it * 256;
      int r = idx >> 3, k8 = (idx & 7) * 8;
      int row = m0 + r; if (row >= M) row = M - 1;
      if (kb < 128) {
        *(short8*)&As[r * 72 + k8] = *(const short8*)&hb[(size_t)row * 128 + kb + k8];
      } else {
        const float4* m4 = (const float4*)(mem + (size_t)row * 128 + (kb - 128) + k8);
        float4 a = m4[0], b = m4[1];
        short8 p;
        p[0] = f2bf(a.x); p[1] = f2bf(a.y); p[2] = f2bf(a.z); p[3] = f2bf(a.w);
        p[4] = f2bf(b.x); p[5] = f2bf(b.y); p[6] = f2bf(b.z); p[7] = f2bf(b.w);
        *(short8*)&As[r * 72 + k8] = p;
      }
    }
    __syncthreads();
#pragma unroll
    for (int kk = 0; kk < 2; ++kk) {
      int ko = kk * 32 + quad * 8;
      short8 a0 = *(const short8*)&As[(mb + l15) * 72 + ko];
      short8 a1 = *(const short8*)&As[(mb + 16 + l15) * 72 + ko];
#pragma unroll
      for (int g = 0; g < 4; ++g) {
        int col = nb + g * 16 + l15;
        short8 b = *(const short8*)&Bt512[(size_t)col * 256 + kb + ko];
        acc[0][g] = __builtin_amdgcn_mfma_f32_16x16x32_bf16(a0, b, acc[0][g], 0, 0, 0);
        acc[1][g] = __builtin_amdgcn_mfma_f32_16x16x32_bf16(a1, b, acc[1][g], 0, 0, 0);
      }
    }
  }

#pragma unroll
  for (int mt = 0; mt < 2; ++mt) {
#pragma unroll
    for (int g = 0; g < 4; ++g) {
      int colg = nb + g * 16 + l15;
#pragma unroll
      for (int r = 0; r < 4; ++r) {
        int rowg = m0 + mb + mt * 16 + quad * 4 + r;
        if (rowg < M)
          S[(size_t)rowg * 512 + colg] = (unsigned short)f2bf(acc[mt][g][r]);
      }
    }
  }
}

// ---------------------------------------------------------------------------
// GRU gates from fused S (bf16)
// ---------------------------------------------------------------------------
__global__ __launch_bounds__(256) void gru_gate2(
    const unsigned short* __restrict__ S, const float* __restrict__ mem,
    const float* __restrict__ bI, const float* __restrict__ bH,
    float* __restrict__ hout, int N)
{
  int idx = blockIdx.x * 256 + threadIdx.x;
  if (idx >= N * HIDC) return;
  int n = idx >> 7, c = idx & 127;
  size_t b = (size_t)n * 512;
  float sr  = bf2f(S[b + c])       + bI[c]       + bH[c];
  float sz  = bf2f(S[b + 128 + c]) + bI[128 + c] + bH[128 + c];
  float gin = bf2f(S[b + 256 + c]) + bI[256 + c];
  float ghn = bf2f(S[b + 384 + c]) + bH[256 + c];
  float rg = 1.f / (1.f + __expf(-sr));
  float zg = 1.f / (1.f + __expf(-sz));
  float nc = tanhf(gin + rg * ghn);
  hout[idx] = (1.f - zg) * nc + zg * mem[idx];
}

// ---------------------------------------------------------------------------
// alphas from bf16 h: aS/aD[n][h] = h[n,:] . waSD[:,j16]
// ---------------------------------------------------------------------------
__global__ __launch_bounds__(256) void alpha2b_kernel(
    const unsigned short* __restrict__ hb, const float* __restrict__ waSD,
    float* __restrict__ aS, float* __restrict__ aD, int N)
{
  __shared__ float s_wa[2048];
  const int tid = threadIdx.x;
  for (int i = tid; i < 2048; i += 256) s_wa[i] = waSD[i];
  __syncthreads();
  int node = blockIdx.x * 16 + (tid >> 4);
  int j = tid & 15;
  if (node >= N) return;
  const short8* h8 = (const short8*)(hb + (size_t)node * 128);
  float s = 0.f;
#pragma unroll
  for (int k8 = 0; k8 < 16; ++k8) {
    short8 v = h8[k8];
#pragma unroll
    for (int t = 0; t < 8; ++t)
      s += bf2f((unsigned short)v[t]) * s_wa[(k8 * 8 + t) * 16 + j];
  }
  if (j < 8) aS[(size_t)node * 8 + j] = s;
  else       aD[(size_t)node * 8 + (j - 8)] = s;
}

// ---------------------------------------------------------------------------
// CSR build: histogram, 3-stage scan, scatter
// ---------------------------------------------------------------------------
__global__ void hist_kernel(const int* __restrict__ ei, int* __restrict__ deg, int E, int N)
{
  int i = blockIdx.x * 256 + threadIdx.x;
  if (i >= E + N) return;
  int dst = (i < E) ? ei[E + i] : (i - E);
  atomicAdd(&deg[dst], 1);
}

__global__ __launch_bounds__(1024) void scan1_kernel(
    const int* __restrict__ deg, int* __restrict__ rowptr,
    int* __restrict__ bsum, int N)
{
  __shared__ int sd[1024];
  int i = blockIdx.x * 1024 + threadIdx.x;
  int v = (i < N) ? deg[i] : 0;
  sd[threadIdx.x] = v;
  __syncthreads();
  for (int off = 1; off < 1024; off <<= 1) {
    int t = (threadIdx.x >= off) ? sd[threadIdx.x - off] : 0;
    __syncthreads();
    sd[threadIdx.x] += t;
    __syncthreads();
  }
  if (i < N) rowptr[i] = sd[threadIdx.x] - v;
  if (threadIdx.x == 1023) bsum[blockIdx.x] = sd[1023];
}

__global__ __launch_bounds__(64) void scan2_kernel(int* __restrict__ bsum, int nb)
{
  int lane = threadIdx.x;
  int v = (lane < nb) ? bsum[lane] : 0;
  int incl = v;
  for (int off = 1; off < 64; off <<= 1) {
    int t = __shfl_up(incl, off);
    if (lane >= off) incl += t;
  }
  if (lane < nb) bsum[lane] = incl - v;
}

__global__ void scan3_kernel(int* __restrict__ rowptr, const int* __restrict__ bsum,
                             int N, int EN)
{
  int i = blockIdx.x * 256 + threadIdx.x;
  if (i < N) rowptr[i] += bsum[i >> 10];
  if (i == 0) rowptr[N] = EN;
}

__global__ void scatter_kernel(const int* __restrict__ ei, const int* __restrict__ rowptr,
                               int* __restrict__ cursor, int* __restrict__ csr_src,
                               int E, int N)
{
  int i = blockIdx.x * 256 + threadIdx.x;
  if (i >= E + N) return;
  int src, dst;
  if (i < E) { src = ei[i]; dst = ei[E + i]; }
  else { src = i - E; dst = i - E; }
  int pos = rowptr[dst] + atomicAdd(&cursor[dst], 1);
  csr_src[pos] = src;
}

// ---------------------------------------------------------------------------
// GAT aggregation v5: one wave per dst, <=64 VGPR (8 waves/SIMD), wave-private
// LDS p/src staging, 8 outstanding gathers, no barriers.
// ---------------------------------------------------------------------------
__global__ __launch_bounds__(256, 8) void gat_agg5(
    const unsigned short* __restrict__ hb, const int* __restrict__ rowptr,
    const int* __restrict__ csr_src, const float* __restrict__ aS,
    const float* __restrict__ aD, unsigned short* __restrict__ agg, int N)
{
  __shared__ float s_p[4][48][8];   // per-wave p (unnormalized), 0 for padding
  __shared__ int   s_src[4][48];    // per-wave src ids, 0 for padding
  const int wid = threadIdx.x >> 6;
  const int lane = threadIdx.x & 63;
  const int dst = blockIdx.x * 4 + wid;
  if (dst >= N) return;
  const int el = lane >> 3, hh = lane & 7;
  const int start = rowptr[dst];
  const int deg = rowptr[dst + 1] - start;
  const float adh = aD[(size_t)dst * 8 + hh];

  // pass 1: scores (src ids staged straight to LDS), per-head max
  float v_c[MAXI];
  float m = -1e30f;
#pragma unroll
  for (int i = 0; i < MAXI; ++i) {
    int e = i * 8 + el;
    int s = 0; float v = -1e30f;
    if (e < deg) {
      s = csr_src[start + e];
      v = aS[(size_t)s * 8 + hh] + adh;
      v = (v > 0.f) ? v : 0.2f * v;
    }
    if (hh == 0) s_src[wid][e] = s;
    v_c[i] = v;
    m = fmaxf(m, v);
  }
  for (int e0 = MAXI * 8; e0 < deg; e0 += 8) {
    int e = e0 + el;
    if (e < deg) {
      int s = csr_src[start + e];
      float v = aS[(size_t)s * 8 + hh] + adh;
      v = (v > 0.f) ? v : 0.2f * v;
      m = fmaxf(m, v);
    }
  }
  m = fmaxf(m, __shfl_xor(m, 8));
  m = fmaxf(m, __shfl_xor(m, 16));
  m = fmaxf(m, __shfl_xor(m, 32));

  // p + stage to wave-private LDS
  float dsum = 0.f;
#pragma unroll
  for (int i = 0; i < MAXI; ++i) {
    int e = i * 8 + el;
    float p = (e < deg && v_c[i] > -1e29f) ? __expf(v_c[i] - m) : 0.f;
    dsum += p;
    s_p[wid][e][hh] = p;
  }

  // pass 2: batched gather + FMA (p=0 padding, src=0 padding -> branch-free)
  float accx[8], accy[8];
#pragma unroll
  for (int q = 0; q < 8; ++q) { accx[q] = 0.f; accy[q] = 0.f; }
  const unsigned* hb32 = (const unsigned*)hb;
  const int ng = (deg < MAXI * 8) ? ((deg + 7) >> 3) : MAXI;

  for (int i = 0; i < ng; ++i) {
    int4 sa = *(const int4*)&s_src[wid][i * 8];
    int4 sb = *(const int4*)&s_src[wid][i * 8 + 4];
    unsigned hv[8];
    hv[0] = hb32[(unsigned)sa.x * 64 + lane];
    hv[1] = hb32[(unsigned)sa.y * 64 + lane];
    hv[2] = hb32[(unsigned)sa.z * 64 + lane];
    hv[3] = hb32[(unsigned)sa.w * 64 + lane];
    hv[4] = hb32[(unsigned)sb.x * 64 + lane];
    hv[5] = hb32[(unsigned)sb.y * 64 + lane];
    hv[6] = hb32[(unsigned)sb.z * 64 + lane];
    hv[7] = hb32[(unsigned)sb.w * 64 + lane];
#pragma unroll
    for (int ee = 0; ee < 8; ++ee) {
      float4 pA = *(const float4*)&s_p[wid][i * 8 + ee][0];
      float4 pB = *(const float4*)&s_p[wid][i * 8 + ee][4];
      float hx = bf2f((unsigned short)hv[ee]);
      float hy = bf2f((unsigned short)(hv[ee] >> 16));
      accx[0] = fmaf(pA.x, hx, accx[0]); accy[0] = fmaf(pA.x, hy, accy[0]);
      accx[1] = fmaf(pA.y, hx, accx[1]); accy[1] = fmaf(pA.y, hy, accy[1]);
      accx[2] = fmaf(pA.z, hx, accx[2]); accy[2] = fmaf(pA.z, hy, accy[2]);
      accx[3] = fmaf(pA.w, hx, accx[3]); accy[3] = fmaf(pA.w, hy, accy[3]);
      accx[4] = fmaf(pB.x, hx, accx[4]); accy[4] = fmaf(pB.x, hy, accy[4]);
      accx[5] = fmaf(pB.y, hx, accx[5]); accy[5] = fmaf(pB.y, hy, accy[5]);
      accx[6] = fmaf(pB.z, hx, accx[6]); accy[6] = fmaf(pB.z, hy, accy[6]);
      accx[7] = fmaf(pB.w, hx, accx[7]); accy[7] = fmaf(pB.w, hy, accy[7]);
    }
  }
  // overflow path (deg > 48): recompute + shuffle broadcast
  const int c2 = lane * 2;
  for (int e0 = MAXI * 8; e0 < deg; e0 += 8) {
    int e = e0 + el;
    float p = 0.f; int s = 0;
    if (e < deg) {
      s = csr_src[start + e];
      float v = aS[(size_t)s * 8 + hh] + adh;
      v = (v > 0.f) ? v : 0.2f * v;
      p = __expf(v - m);
    }
    dsum += p;
    int cnt = deg - e0; if (cnt > 8) cnt = 8;
    for (int ee = 0; ee < cnt; ++ee) {
      int se = __shfl(s, ee * 8);
      unsigned hv = *(const unsigned*)&hb[(size_t)se * 128 + c2];
      float hx = bf2f((unsigned short)hv);
      float hy = bf2f((unsigned short)(hv >> 16));
#pragma unroll
      for (int q = 0; q < 8; ++q) {
        float pq = __shfl(p, ee * 8 + q);
        accx[q] = fmaf(pq, hx, accx[q]);
        accy[q] = fmaf(pq, hy, accy[q]);
      }
    }
  }

  dsum += __shfl_xor(dsum, 8);
  dsum += __shfl_xor(dsum, 16);
  dsum += __shfl_xor(dsum, 32);
  float inv = 1.f / (dsum + 1e-16f);

#pragma unroll
  for (int q = 0; q < 8; ++q) {
    float invq = __shfl(inv, q);                  // lane q holds hh=q denom
    float ax = accx[q] * invq, ay = accy[q] * invq;
    unsigned pk = ((unsigned)(unsigned short)f2bf(ay) << 16) |
                  (unsigned)(unsigned short)f2bf(ax);
    *(unsigned*)&agg[(size_t)dst * 1024 + q * 128 + c2] = pk;
  }
}

// ---------------------------------------------------------------------------
// global_mean_pool
// ---------------------------------------------------------------------------
__global__ __launch_bounds__(128) void pool_kernel(
    const float* __restrict__ h, const int* __restrict__ batch,
    float* __restrict__ pooled_sums, float* __restrict__ cnt, int N)
{
  int n0 = blockIdx.x * 128;
  int c = threadIdx.x;
  int end = n0 + 128; if (end > N) end = N;
  if (n0 >= N) return;
  int cur = batch[n0];
  float acc = 0.f; float count = 0.f;
  for (int n = n0; n < end; ++n) {
    int b = batch[n];
    if (b != cur) {
      atomicAdd(&pooled_sums[(size_t)cur * HIDC + c], acc);
      if (c == 0) atomicAdd(&cnt[cur], count);
      acc = 0.f; count = 0.f; cur = b;
    }
    acc += h[(size_t)n * HIDC + c];
    count += 1.f;
  }
  atomicAdd(&pooled_sums[(size_t)cur * HIDC + c], acc);
  if (c == 0) atomicAdd(&cnt[cur], count);
}

// ---------------------------------------------------------------------------
// finalize pooled, classifier MLP, softmax
// ---------------------------------------------------------------------------
__global__ __launch_bounds__(64) void classifier_kernel(
    float* __restrict__ pooled, const float* __restrict__ cnt,
    const float* __restrict__ c1W, const float* __restrict__ c1b,
    const float* __restrict__ c2W, const float* __restrict__ c2b,
    float* __restrict__ logits, float* __restrict__ preds)
{
  int g = blockIdx.x, j = threadIdx.x;
  __shared__ float sp[128];
  __shared__ float hid[64];
  __shared__ float lg[3];
  float invc = 1.f / fmaxf(cnt[g], 1.f);
  float p0 = pooled[(size_t)g * 128 + j] * invc;
  float p1 = pooled[(size_t)g * 128 + 64 + j] * invc;
  pooled[(size_t)g * 128 + j] = p0;
  pooled[(size_t)g * 128 + 64 + j] = p1;
  sp[j] = p0; sp[j + 64] = p1;
  __syncthreads();
  float a = c1b[j];
#pragma unroll
  for (int k = 0; k < 128; ++k) a = fmaf(sp[k], c1W[k * 64 + j], a);
  hid[j] = fmaxf(a, 0.f);
  __syncthreads();
  if (j < NCLS) {
    float t = c2b[j];
#pragma unroll
    for (int k = 0; k < 64; ++k) t = fmaf(hid[k], c2W[k * NCLS + j], t);
    logits[(size_t)g * NCLS + j] = t;
    lg[j] = t;
  }
  __syncthreads();
  if (j < NCLS) {
    float mx = fmaxf(lg[0], fmaxf(lg[1], lg[2]));
    float e0 = __expf(lg[0] - mx), e1 = __expf(lg[1] - mx), e2 = __expf(lg[2] - mx);
    float mine = (j == 0) ? e0 : ((j == 1) ? e1 : e2);
    preds[(size_t)g * NCLS + j] = mine / (e0 + e1 + e2);
  }
}

// ---------------------------------------------------------------------------
extern "C" void kernel_launch(void* const* d_in, const int* in_sizes, int n_in,
                              void* d_out, int out_size, void* d_ws, size_t ws_size,
                              hipStream_t stream)
{
  const float* x       = (const float*)d_in[0];
  const int*   ei      = (const int*)d_in[1];
  const int*   batch   = (const int*)d_in[2];
  const float* memory  = (const float*)d_in[3];
  const float* enc_W   = (const float*)d_in[4];
  const float* enc_b   = (const float*)d_in[5];
  const float* gat_W   = (const float*)d_in[6];   // [NL,128,1024]
  const float* att_src = (const float*)d_in[7];
  const float* att_dst = (const float*)d_in[8];
  const float* gat_b   = (const float*)d_in[9];
  const float* W_ih    = (const float*)d_in[10];
  const float* W_hh    = (const float*)d_in[11];
  const float* b_ih    = (const float*)d_in[12];
  const float* b_hh    = (const float*)d_in[13];
  const float* c1W     = (const float*)d_in[14];
  const float* c1b     = (const float*)d_in[15];
  const float* c2W     = (const float*)d_in[16];
  const float* c2b     = (const float*)d_in[17];

  const int N = in_sizes[0] / HIDC;
  const int E = in_sizes[1] / 2;
  const int EN = E + N;
  const int NB = (N + 1023) / 1024;

  char* ws = (char*)d_ws;
  size_t off = 0;
  auto alloc = [&](size_t bytes) -> void* {
    void* p = ws + off;
    off += (bytes + 255) & ~(size_t)255;
    return p;
  };
  unsigned short* hb0 = (unsigned short*)alloc((size_t)N * HIDC * 2);
  unsigned short* hb1 = (unsigned short*)alloc((size_t)N * HIDC * 2);
  float* hgru   = (float*)alloc((size_t)N * HIDC * 4);
  unsigned short* agg = (unsigned short*)alloc((size_t)N * 1024 * 2);  // also S[N,512]
  float* aS     = (float*)alloc((size_t)N * NHEAD * 4);
  float* aD     = (float*)alloc((size_t)N * NHEAD * 4);
  short* encT   = (short*)alloc((size_t)128 * 128 * 2);
  short* Wp     = (short*)alloc((size_t)NLAY * 131072 * 2);
  float* waSD   = (float*)alloc((size_t)NLAY * 2048 * 4);
  short* Bt512  = (short*)alloc((size_t)512 * 256 * 2);
  int*   rowptr = (int*)alloc((size_t)(N + 1) * 4);
  // cursor + degtmp adjacent -> single memset
  size_t zoff0 = off;
  int*   cursor = (int*)alloc((size_t)N * 4);
  int*   degtmp = (int*)alloc((size_t)N * 4);
  size_t zbytes = off - zoff0;
  int*   bsum   = (int*)alloc(64 * 4);
  int*   csr    = (int*)alloc((size_t)EN * 4);
  float* cntbuf = (float*)alloc(64 * 4);

  float* out_logits = (float*)d_out;
  float* out_pooled = (float*)d_out + NGRAPH * NCLS;
  float* out_preds  = (float*)d_out + NGRAPH * NCLS + NGRAPH * HIDC;

  hipMemsetAsync(d_out, 0, (size_t)out_size * 4, stream);
  hipMemsetAsync(cntbuf, 0, 64 * 4, stream);
  hipMemsetAsync(cursor, 0, zbytes, stream);

  // CSR build
  hist_kernel<<<(EN + 255) / 256, 256, 0, stream>>>(ei, degtmp, E, N);
  scan1_kernel<<<NB, 1024, 0, stream>>>(degtmp, rowptr, bsum, N);
  scan2_kernel<<<1, 64, 0, stream>>>(bsum, NB);
  scan3_kernel<<<(N + 255) / 256, 256, 0, stream>>>(rowptr, bsum, N, EN);
  scatter_kernel<<<(EN + 255) / 256, 256, 0, stream>>>(ei, rowptr, cursor, csr, E, N);

  // weight prep
  convt_kernel<<<(128 * 128 + 255) / 256, 256, 0, stream>>>(enc_W, encT, 128, 128);
  rearr_kernel<<<(NLAY * 131072 + 255) / 256, 256, 0, stream>>>(gat_W, Wp);
  {
    dim3 g(NLAY, 8);
    wa_kernel<<<g, 256, 0, stream>>>(gat_W, att_src, att_dst, waSD);
  }
  build_gru_B<<<(512 * 256 + 255) / 256, 256, 0, stream>>>(W_ih, W_hh, Bt512);

  // encoder: hb0 = bf16(relu(x @ enc_W + enc_b))
  {
    dim3 g((N + 63) / 64, 2);
    mm_bf16<<<g, 256, 0, stream>>>(x, encT, enc_b, hb0, N, HIDC, 1);
  }

  unsigned short* hbcur = hb0;
  unsigned short* hbnxt = hb1;
  for (int l = 0; l < NLAY; ++l) {
    alpha2b_kernel<<<(N + 15) / 16, 256, 0, stream>>>(
        hbcur, waSD + (size_t)l * 2048, aS, aD, N);
    gat_agg5<<<(N + 3) / 4, 256, 0, stream>>>(hbcur, rowptr, csr, aS, aD, agg, N);
    dim3 g((N + 63) / 64, 1);
    mm_bf16A<<<g, 256, 0, stream>>>(agg, Wp + (size_t)l * 131072,
                                    gat_b + (size_t)l * HIDC, hbnxt,
                                    N, HIDC, 1024, (l < NLAY - 1) ? 1 : 0);
    unsigned short* tb = hbcur; hbcur = hbnxt; hbnxt = tb;
  }

  // fused-weight GRU: S = [hb|mem] @ Bt512^T (bf16), then gates
  {
    dim3 g((N + 63) / 64, 4);
    gru_mm<<<g, 256, 0, stream>>>(hbcur, memory, Bt512, agg, N);   // agg reused as S
  }
  gru_gate2<<<((N * HIDC) + 255) / 256, 256, 0, stream>>>(agg, memory, b_ih, b_hh,
                                                          hgru, N);

  // pooling + classifier
  pool_kernel<<<(N + 127) / 128, 128, 0, stream>>>(hgru, batch, out_pooled, cntbuf, N);
  classifier_kernel<<<NGRAPH, 64, 0, stream>>>(out_pooled, cntbuf, c1W, c1b, c2W, c2b,
                                               out_logits, out_preds);
}